// Round 5
// baseline (2278.094 us; speedup 1.0000x reference)
//
#include <hip/hip_runtime.h>
#include <cmath>

constexpr int NB   = 16;      // batch
constexpr int NPTS = 10000;   // points per batch
constexpr int NBN  = NB * NPTS;   // 160000
constexpr int NS_ITERS = 18;
constexpr int COV_CHUNKS = 20;    // 500 points each
constexpr int CHUNK_PTS  = 500;
constexpr int COV_KK     = 16;    // 16*32 = 512 >= 500
constexpr unsigned NS_BLOCKS = 256;   // 16 batches x 16 tiles; <= 256 CUs

typedef _Float16 f16x8 __attribute__((ext_vector_type(8)));
typedef float  f32x4  __attribute__((ext_vector_type(4)));
typedef unsigned short ushort4v __attribute__((ext_vector_type(4)));
typedef unsigned short ushort8v __attribute__((ext_vector_type(8)));

// ---------------------------------------------------------------------------
// Layer 0: 3 -> 64, no input BN
// ---------------------------------------------------------------------------
__global__ __launch_bounds__(256) void conv0_ker(const float* __restrict__ pts,
                                                 const float* __restrict__ W,
                                                 float* __restrict__ y) {
    int g = blockIdx.x * 256 + threadIdx.x;          // 0..159999
    int b = g / NPTS;
    int n = g - b * NPTS;
    float p0 = pts[3 * (size_t)g + 0];
    float p1 = pts[3 * (size_t)g + 1];
    float p2 = pts[3 * (size_t)g + 2];
    float* yp = y + ((size_t)b * 64) * NPTS + n;
    for (int o = 0; o < 64; ++o) {
        float v = W[3 * o] * p0 + W[3 * o + 1] * p1 + W[3 * o + 2] * p2;
        yp[(size_t)o * NPTS] = v;
    }
}

// ---------------------------------------------------------------------------
// split-fp16 helpers (hi = fp16(v), lo = fp16(v - hi)): 3-MFMA product keeps
// ~2^-22 relative accuracy, effectively fp32 for this pipeline.
// ---------------------------------------------------------------------------
__device__ __forceinline__ unsigned short f2h(float f) {
    return __builtin_bit_cast(unsigned short, (_Float16)f);
}
__device__ __forceinline__ float hres(float f) {
    return f - (float)(_Float16)f;
}
// LDS XOR-swizzle on ushort index (byte bits 5-6 ^= bits 8-9), 8-us aligned
__device__ __forceinline__ int swzu(int us) {
    return us ^ (((us >> 7) & 3) << 4);
}

// ---------------------------------------------------------------------------
// MFMA conv layer: y[b, ob+o, n] = sum_c W[ob+o, c] * relu(bn(x[b, c, n]))
// Block tile: OTILE x 128 points; waves 2x2 (OTILE=128) or 1x4 (OTILE=64).
// Fused BN-stats: per-channel sum/sumsq accumulated via shfl + LDS + atomics.
// ---------------------------------------------------------------------------
template <int CIN, int COUT, int OTILE>
__global__ __launch_bounds__(256) void conv_mfma(const float* __restrict__ xin,
                                                 const float* __restrict__ ss,
                                                 const float* __restrict__ W,
                                                 float* __restrict__ y,
                                                 float* __restrict__ stats) {
    constexpr int OT = OTILE / 16;
    constexpr int WM = 4;
    constexpr int WN = (OTILE == 128) ? 4 : 2;
    constexpr int NCW = (OTILE == 128) ? 2 : 4;   // distinct col-wave groups
    __shared__ unsigned short Xp[2][8 * 512];
    __shared__ unsigned short Wp[2][OT * 512];

    const int tid  = threadIdx.x;
    const int lane = tid & 63;
    const int w    = tid >> 6;
    const int wr   = (OTILE == 128) ? (w & 1) : 0;
    const int wc   = (OTILE == 128) ? (w >> 1) : w;

    const int nb = blockIdx.x * 128;
    const int ob = blockIdx.y * OTILE;
    const int b  = blockIdx.z;

    f32x4 acc[WM][WN];
#pragma unroll
    for (int m = 0; m < WM; ++m)
#pragma unroll
        for (int n = 0; n < WN; ++n) acc[m][n] = (f32x4){0.f, 0.f, 0.f, 0.f};

    const int xn = tid & 127;
    const int th = tid >> 7;
    const bool nok = (nb + xn) < NPTS;

#pragma unroll 1
    for (int kc = 0; kc < CIN; kc += 32) {
        __syncthreads();
        // ---- stage W[ob..ob+OTILE)[kc..kc+32) as split-fp16 A panels ----
#pragma unroll
        for (int i = 0; i < OTILE / 32; ++i) {
            int l = i * 256 + tid;
            int o = l >> 3, k4 = (l & 7) << 2;
            float4 v = *(const float4*)(W + (size_t)(ob + o) * CIN + kc + k4);
            ushort4v h4, l4;
            h4[0] = f2h(v.x); l4[0] = f2h(hres(v.x));
            h4[1] = f2h(v.y); l4[1] = f2h(hres(v.y));
            h4[2] = f2h(v.z); l4[2] = f2h(hres(v.z));
            h4[3] = f2h(v.w); l4[3] = f2h(hres(v.w));
            int us = swzu((o >> 4) * 512 + ((k4 >> 3) * 16 + (o & 15)) * 8 + (k4 & 7));
            *(ushort4v*)&Wp[0][us] = h4;
            *(ushort4v*)&Wp[1][us] = l4;
        }
        // ---- stage relu(bn(x))[kc..kc+32)[nb..nb+128) as split-fp16 B panels ----
#pragma unroll
        for (int qq = 0; qq < 2; ++qq) {
            int q = th * 2 + qq;
            const float* xb = xin + ((size_t)(b * CIN + kc + q * 8)) * NPTS + nb + xn;
            float f[8];
#pragma unroll
            for (int j = 0; j < 8; ++j) {
                float v = nok ? xb[(size_t)j * NPTS] : 0.f;
                int c = kc + q * 8 + j;
                f[j] = fmaxf(fmaf(v, ss[c], ss[256 + c]), 0.f);
            }
            ushort8v h8, l8;
#pragma unroll
            for (int j = 0; j < 8; ++j) {
                h8[j] = f2h(f[j]);
                l8[j] = f2h(hres(f[j]));
            }
            int us = swzu((xn >> 4) * 512 + (q * 16 + (xn & 15)) * 8);
            *(ushort8v*)&Xp[0][us] = h8;
            *(ushort8v*)&Xp[1][us] = l8;
        }
        __syncthreads();

        f16x8 ah[WM], al[WM], bh[WN], bl[WN];
#pragma unroll
        for (int m = 0; m < WM; ++m) {
            int us = swzu((wr * WM + m) * 512 + lane * 8);
            ah[m] = *(const f16x8*)&Wp[0][us];
            al[m] = *(const f16x8*)&Wp[1][us];
        }
#pragma unroll
        for (int n = 0; n < WN; ++n) {
            int us = swzu((wc * WN + n) * 512 + lane * 8);
            bh[n] = *(const f16x8*)&Xp[0][us];
            bl[n] = *(const f16x8*)&Xp[1][us];
        }
#pragma unroll
        for (int m = 0; m < WM; ++m)
#pragma unroll
            for (int n = 0; n < WN; ++n) {
                acc[m][n] = __builtin_amdgcn_mfma_f32_16x16x32_f16(ah[m], bh[n], acc[m][n], 0, 0, 0);
                acc[m][n] = __builtin_amdgcn_mfma_f32_16x16x32_f16(ah[m], bl[n], acc[m][n], 0, 0, 0);
                acc[m][n] = __builtin_amdgcn_mfma_f32_16x16x32_f16(al[m], bh[n], acc[m][n], 0, 0, 0);
            }
    }

    // ---- epilogue: stores ----
    const int ro = (lane >> 4) * 4;
    const int co = lane & 15;
#pragma unroll
    for (int m = 0; m < WM; ++m) {
        int o = ob + wr * (WM * 16) + m * 16 + ro;
#pragma unroll
        for (int n = 0; n < WN; ++n) {
            int col = nb + wc * (WN * 16) + n * 16 + co;
            if (col < NPTS) {
                float* yp = y + ((size_t)(b * COUT + o)) * NPTS + col;
#pragma unroll
                for (int r = 0; r < 4; ++r)
                    yp[(size_t)r * NPTS] = acc[m][n][r];
            }
        }
    }

    // ---- fused BN-stats: per-channel sum / sumsq over valid columns ----
    __syncthreads();                       // all waves done reading Xp/Wp
    float* sbuf = (float*)&Xp[0][0];       // [NCW][OTILE]
    float* qbuf = sbuf + NCW * OTILE;
#pragma unroll
    for (int m = 0; m < WM; ++m)
#pragma unroll
        for (int r = 0; r < 4; ++r) {
            float s = 0.f, q = 0.f;
#pragma unroll
            for (int n = 0; n < WN; ++n) {
                int col = nb + wc * (WN * 16) + n * 16 + co;
                float v = acc[m][n][r];
                if (col < NPTS) { s += v; q = fmaf(v, v, q); }
            }
            s += __shfl_xor(s, 1); q += __shfl_xor(q, 1);
            s += __shfl_xor(s, 2); q += __shfl_xor(q, 2);
            s += __shfl_xor(s, 4); q += __shfl_xor(q, 4);
            s += __shfl_xor(s, 8); q += __shfl_xor(q, 8);
            if (co == 0) {
                int rowl = wr * (WM * 16) + m * 16 + ro + r;   // 0..OTILE-1
                sbuf[wc * OTILE + rowl] = s;
                qbuf[wc * OTILE + rowl] = q;
            }
        }
    __syncthreads();
    if (tid < OTILE) {
        float s = 0.f, q = 0.f;
#pragma unroll
        for (int j = 0; j < NCW; ++j) {
            s += sbuf[j * OTILE + tid];
            q += qbuf[j * OTILE + tid];
        }
        atomicAdd(&stats[ob + tid], s);
        atomicAdd(&stats[COUT + ob + tid], q);
    }
}

// ---------------------------------------------------------------------------
// Per-channel sum / sumsq over (batch, points)  -> stats[c], stats[C+c]
// (layer-0 output only; later layers fuse stats into conv_mfma)
// ---------------------------------------------------------------------------
__global__ void chan_stats(const float* __restrict__ y, int C, float* __restrict__ stats) {
    int c = blockIdx.x, b = blockIdx.y, t = threadIdx.x;
    const float* p = y + ((size_t)(b * C + c)) * NPTS;
    float s = 0.f, q = 0.f;
    for (int n = t; n < NPTS; n += 256) {
        float v = p[n];
        s += v;
        q = fmaf(v, v, q);
    }
    for (int off = 32; off; off >>= 1) {
        s += __shfl_down(s, off);
        q += __shfl_down(q, off);
    }
    __shared__ float ls[4], lq[4];
    if ((t & 63) == 0) { ls[t >> 6] = s; lq[t >> 6] = q; }
    __syncthreads();
    if (t == 0) {
        atomicAdd(&stats[c],     ls[0] + ls[1] + ls[2] + ls[3]);
        atomicAdd(&stats[C + c], lq[0] + lq[1] + lq[2] + lq[3]);
    }
}

__global__ void bn_finalize(const float* __restrict__ stats, const float* __restrict__ g,
                            const float* __restrict__ bi, int C, float* __restrict__ ss) {
    int c = threadIdx.x;
    if (c < C) {
        float mu  = stats[c] * (1.f / NBN);
        float var = stats[C + c] * (1.f / NBN) - mu * mu;
        float r = rsqrtf(var + 1e-5f);
        float s = g[c] * r;
        ss[c] = s;
        ss[256 + c] = bi[c] - mu * s;
    }
}

// ---------------------------------------------------------------------------
// Split-fp16 MFMA second moment: covP[chunk][b][tile] 128x128 += F F^T
// over CHUNK_PTS points.  Also accumulates per-(b,channel) relu-sums into
// fsumb (tiles 0/1 cover every channel exactly once per chunk).
// grid: (COV_CHUNKS, 3 tiles{(0,0),(1,1),(0,1)}, 16 batches) = 960 blocks.
// ---------------------------------------------------------------------------
__device__ __forceinline__ int swz8(int byteoff) {
    return byteoff ^ (((byteoff >> 8) & 3) << 5);
}

__global__ __launch_bounds__(256) void cov_mfma(const float* __restrict__ y4,
                                                const float* __restrict__ ss,
                                                float* __restrict__ covP,
                                                float* __restrict__ fsumb) {
    __shared__ unsigned short pan[2][2][4096];   // [panel][hi/lo][8 frag-tiles * 512]

    const int chunk = blockIdx.x;
    const int tile  = blockIdx.y;
    const int b     = blockIdx.z;
    const int ti = (tile == 1) ? 1 : 0;
    const int tj = (tile == 0) ? 0 : 1;
    const int npan = (tile == 2) ? 2 : 1;

    const int tid  = threadIdx.x;
    const int lane = tid & 63;
    const int w    = tid >> 6;
    const int wr   = w & 1, wc = w >> 1;

    const int n0c = chunk * CHUNK_PTS;

    f32x4 acc[4][4];
#pragma unroll
    for (int m = 0; m < 4; ++m)
#pragma unroll
        for (int n = 0; n < 4; ++n) acc[m][n] = (f32x4){0.f, 0.f, 0.f, 0.f};

    // staging assignment: 8 point-groups (4 pts) x 32 channel-bases
    const int g   = tid & 7;
    const int chb = tid >> 3;          // 0..31
    const int p4  = g * 4;             // point offset in 32-chunk
    const int q   = p4 >> 3, j0 = p4 & 7;

    float fs[4] = {0.f, 0.f, 0.f, 0.f};   // per-thread channel relu-sums (tiles 0/1)

#pragma unroll 1
    for (int kk = 0; kk < COV_KK; ++kk) {        // 16*32 = 512 >= 500
        const int nbase = n0c + kk * 32;
        __syncthreads();
        for (int p = 0; p < npan; ++p) {
            const int pcb = (p ? tj : ti) * 128;
#pragma unroll
            for (int i = 0; i < 4; ++i) {
                const int ch = chb + 32 * i;
                float4 v = make_float4(0.f, 0.f, 0.f, 0.f);
                if (kk * 32 + p4 < CHUNK_PTS) {
                    v = *(const float4*)(y4 + ((size_t)(b * 256 + pcb + ch)) * NPTS + nbase + p4);
                    float sc = ss[pcb + ch], sh = ss[256 + pcb + ch];
                    v.x = fmaxf(fmaf(v.x, sc, sh), 0.f);
                    v.y = fmaxf(fmaf(v.y, sc, sh), 0.f);
                    v.z = fmaxf(fmaf(v.z, sc, sh), 0.f);
                    v.w = fmaxf(fmaf(v.w, sc, sh), 0.f);
                }
                if (npan == 1) fs[i] += (v.x + v.y) + (v.z + v.w);
                ushort4v h4, l4;
                h4[0] = f2h(v.x); l4[0] = f2h(hres(v.x));
                h4[1] = f2h(v.y); l4[1] = f2h(hres(v.y));
                h4[2] = f2h(v.z); l4[2] = f2h(hres(v.z));
                h4[3] = f2h(v.w); l4[3] = f2h(hres(v.w));
                const int addr = (ch >> 4) * 512 + (q * 16 + (ch & 15)) * 8 + j0;
                const int sa = swz8(addr * 2) >> 1;
                *(ushort4v*)&pan[p][0][sa] = h4;
                *(ushort4v*)&pan[p][1][sa] = l4;
            }
        }
        __syncthreads();

        const unsigned short* Ah = pan[0][0];
        const unsigned short* Al = pan[0][1];
        const unsigned short* Bh = pan[npan - 1][0];
        const unsigned short* Bl = pan[npan - 1][1];

        f16x8 ah[4], al[4], bh[4], bl[4];
#pragma unroll
        for (int m = 0; m < 4; ++m) {
            int t8 = (wr * 4 + m) * 512 + lane * 8;
            int sa = swz8(t8 * 2) >> 1;
            ah[m] = *(const f16x8*)&Ah[sa];
            al[m] = *(const f16x8*)&Al[sa];
        }
#pragma unroll
        for (int n = 0; n < 4; ++n) {
            int t8 = (wc * 4 + n) * 512 + lane * 8;
            int sa = swz8(t8 * 2) >> 1;
            bh[n] = *(const f16x8*)&Bh[sa];
            bl[n] = *(const f16x8*)&Bl[sa];
        }
#pragma unroll
        for (int m = 0; m < 4; ++m)
#pragma unroll
            for (int n = 0; n < 4; ++n) {
                acc[m][n] = __builtin_amdgcn_mfma_f32_16x16x32_f16(ah[m], bh[n], acc[m][n], 0, 0, 0);
                acc[m][n] = __builtin_amdgcn_mfma_f32_16x16x32_f16(ah[m], bl[n], acc[m][n], 0, 0, 0);
                acc[m][n] = __builtin_amdgcn_mfma_f32_16x16x32_f16(al[m], bh[n], acc[m][n], 0, 0, 0);
            }
    }

    // fused per-channel relu-sum contribution (tiles 0/1 only)
    if (npan == 1) {
#pragma unroll
        for (int i = 0; i < 4; ++i) {
            float s = fs[i];
            s += __shfl_xor(s, 1);
            s += __shfl_xor(s, 2);
            s += __shfl_xor(s, 4);
            if (g == 0)
                atomicAdd(&fsumb[b * 256 + ti * 128 + chb + 32 * i], s);
        }
    }

    // epilogue: packed per-(chunk,b,tile) 128x128 partial buffer (no atomics)
    float* outp = covP + (((size_t)(chunk * NB + b) * 3 + tile) << 14);
    const int rowb = wr * 64;
    const int colb = wc * 64;
#pragma unroll
    for (int m = 0; m < 4; ++m)
#pragma unroll
        for (int n = 0; n < 4; ++n)
#pragma unroll
            for (int r = 0; r < 4; ++r) {
                int row = rowb + m * 16 + (lane >> 4) * 4 + r;
                int col = colb + n * 16 + (lane & 15);
                outp[(row << 7) + col] = acc[m][n][r];
            }
}

// ---------------------------------------------------------------------------
// cov = (sum_q covP[q])/N - m fbar^T - fbar m^T + m m^T ; mirror tile (1,0)
// covP layout: [chunk][b][tile 0:(0,0) 1:(1,1) 2:(0,1)][128][128]
// ---------------------------------------------------------------------------
__global__ void covfin_ker(const float* __restrict__ covP, const float* __restrict__ fsumb,
                           float* __restrict__ Y0, float* __restrict__ trace) {
    int r = blockIdx.x, b = blockIdx.y, c = threadIdx.x;
    float fbr = fsumb[b * 256 + r] * (1.f / NPTS);
    float fbc = fsumb[b * 256 + c] * (1.f / NPTS);
    float mr = 0.f, mc = 0.f;
    for (int q = 0; q < NB; ++q) {
        mr += fsumb[q * 256 + r];
        mc += fsumb[q * 256 + c];
    }
    mr *= (1.f / NBN);
    mc *= (1.f / NBN);
    int tile, rr, cc;
    if (r < 128 && c < 128)        { tile = 0; rr = r;       cc = c; }
    else if (r >= 128 && c >= 128) { tile = 1; rr = r - 128; cc = c - 128; }
    else if (r < 128)              { tile = 2; rr = r;       cc = c - 128; }   // (0,1)
    else                           { tile = 2; rr = c;       cc = r - 128; }   // (1,0) mirror
    size_t base = (((size_t)b * 3 + tile) << 14) + ((size_t)rr << 7) + cc;
    float m5 = 0.f;
#pragma unroll
    for (int q = 0; q < COV_CHUNKS; ++q)
        m5 += covP[(size_t)q * (NB * 3 * 16384) + base];
    float v = m5 * (1.f / NPTS) - fbr * mc - mr * fbc + mr * mc;
    Y0[((size_t)b << 16) + ((size_t)r << 8) + c] = v;
    if (c == r) atomicAdd(&trace[b], v);
}

// ---------------------------------------------------------------------------
// Newton-Schulz batched 256x256 GEMM tile body via split-fp16 MFMA.
// O = diag*I + scale*(A.B); block computes 64x64 tile, K=256 in 8 steps.
// ---------------------------------------------------------------------------
__device__ __forceinline__ void ns_body(const float* __restrict__ Ab,
                                        const float* __restrict__ Bb,
                                        float* __restrict__ Ob,
                                        float scale, float diag, int tile, int tid,
                                        unsigned short* Ap0, unsigned short* Ap1,
                                        unsigned short* Bp0, unsigned short* Bp1) {
    const int lane = tid & 63;
    const int w    = tid >> 6;
    const int wr   = w & 1, wc = w >> 1;
    const int tr = (tile >> 2) * 64, tc = (tile & 3) * 64;

    f32x4 acc[2][2];
#pragma unroll
    for (int m = 0; m < 2; ++m)
#pragma unroll
        for (int n = 0; n < 2; ++n) acc[m][n] = (f32x4){0.f, 0.f, 0.f, 0.f};

    const int fA = tid & 63;       // staged row (A) / col (B)
    const int kq = tid >> 6;       // k-subblock (== wave id)

#pragma unroll 1
    for (int kc = 0; kc < 256; kc += 32) {
        __syncthreads();
        const float* ap = Ab + (size_t)(tr + fA) * 256 + kc + kq * 8;
        float av[8];
        *(float4*)&av[0] = *(const float4*)ap;
        *(float4*)&av[4] = *(const float4*)(ap + 4);
        const float* bp = Bb + (size_t)(kc + kq * 8) * 256 + tc + fA;
        float bv[8];
#pragma unroll
        for (int j = 0; j < 8; ++j) bv[j] = bp[(size_t)j * 256];
        ushort8v ah8, al8, bh8, bl8;
#pragma unroll
        for (int j = 0; j < 8; ++j) {
            ah8[j] = f2h(av[j]); al8[j] = f2h(hres(av[j]));
            bh8[j] = f2h(bv[j]); bl8[j] = f2h(hres(bv[j]));
        }
        const int ua = (fA >> 4) * 512 + (kq * 16 + (fA & 15)) * 8;
        *(ushort8v*)&Ap0[ua] = ah8;
        *(ushort8v*)&Ap1[ua] = al8;
        *(ushort8v*)&Bp0[ua] = bh8;
        *(ushort8v*)&Bp1[ua] = bl8;
        __syncthreads();

        f16x8 a_h[2], a_l[2], b_h[2], b_l[2];
#pragma unroll
        for (int m = 0; m < 2; ++m) {
            int u = (wr * 2 + m) * 512 + lane * 8;
            a_h[m] = *(const f16x8*)&Ap0[u];
            a_l[m] = *(const f16x8*)&Ap1[u];
        }
#pragma unroll
        for (int n = 0; n < 2; ++n) {
            int u = (wc * 2 + n) * 512 + lane * 8;
            b_h[n] = *(const f16x8*)&Bp0[u];
            b_l[n] = *(const f16x8*)&Bp1[u];
        }
#pragma unroll
        for (int m = 0; m < 2; ++m)
#pragma unroll
            for (int n = 0; n < 2; ++n) {
                acc[m][n] = __builtin_amdgcn_mfma_f32_16x16x32_f16(a_h[m], b_h[n], acc[m][n], 0, 0, 0);
                acc[m][n] = __builtin_amdgcn_mfma_f32_16x16x32_f16(a_h[m], b_l[n], acc[m][n], 0, 0, 0);
                acc[m][n] = __builtin_amdgcn_mfma_f32_16x16x32_f16(a_l[m], b_h[n], acc[m][n], 0, 0, 0);
            }
    }

    const int ro = (lane >> 4) * 4, co = lane & 15;
#pragma unroll
    for (int m = 0; m < 2; ++m)
#pragma unroll
        for (int n = 0; n < 2; ++n) {
            int row = tr + wr * 32 + m * 16 + ro;
            int col = tc + wc * 32 + n * 16 + co;
#pragma unroll
            for (int r = 0; r < 4; ++r) {
                float v = scale * acc[m][n][r] + (((row + r) == col) ? diag : 0.f);
                Ob[(size_t)(row + r) * 256 + col] = v;
            }
        }
}

// ---------------------------------------------------------------------------
// Manual grid barrier: one fresh pre-zeroed counter per barrier event.
// Grid = 256 blocks on 256 CUs (4 waves + 16KB LDS each) -> co-resident.
// __threadfence (agent scope) before arrive / after release handles
// cross-XCD L2 visibility.
// ---------------------------------------------------------------------------
__device__ __forceinline__ void grid_bar(unsigned int* bar, unsigned int nb) {
    __syncthreads();
    if (threadIdx.x == 0) {
        __threadfence();
        __hip_atomic_fetch_add(bar, 1u, __ATOMIC_ACQ_REL, __HIP_MEMORY_SCOPE_AGENT);
        while (__hip_atomic_load(bar, __ATOMIC_ACQUIRE, __HIP_MEMORY_SCOPE_AGENT) < nb) {
            __builtin_amdgcn_s_sleep(8);
        }
        __threadfence();
    }
    __syncthreads();
}

// ---------------------------------------------------------------------------
// Fused Newton-Schulz: 256 blocks (16 batches x 16 tiles), 18 iters,
// manual grid barrier between phases.  Prologue does ns_init.
// ---------------------------------------------------------------------------
__global__ __launch_bounds__(256) void ns_fused(float* __restrict__ Y0, float* __restrict__ Z0,
                                                float* __restrict__ Y1, float* __restrict__ Z1,
                                                float* __restrict__ Mb,
                                                const float* __restrict__ trace,
                                                unsigned int* __restrict__ bar) {
    __shared__ unsigned short Ap[2][2048], Bp[2][2048];

    const int bid  = blockIdx.x;         // 0..255
    const int b    = bid >> 4;
    const int tile = bid & 15;
    const int t    = threadIdx.x;
    const size_t off = (size_t)b << 16;
    int bi = 0;

    // prologue: ns_init for this block's 64x64 region
    {
        float inv = 1.f / trace[b];
        int tr = (tile >> 2) * 64, tc = (tile & 3) * 64;
#pragma unroll
        for (int i = 0; i < 16; ++i) {
            int l = i * 256 + t;                       // 0..4095
            int r = tr + (l >> 6), c = tc + (l & 63);
            size_t idx = off + ((size_t)r << 8) + c;
            Y0[idx] *= inv;
            Z0[idx] = (r == c) ? 1.f : 0.f;
        }
    }
    grid_bar(&bar[bi++], NS_BLOCKS);

    float* Yc = Y0; float* Zc = Z0; float* Yn = Y1; float* Zn = Z1;
    for (int it = 0; it < NS_ITERS; ++it) {
        // M = 3I - Z.Y
        ns_body(Zc + off, Yc + off, Mb + off, -1.f, 3.f, tile, t,
                Ap[0], Ap[1], Bp[0], Bp[1]);
        grid_bar(&bar[bi++], NS_BLOCKS);
        // Yn = 0.5 Y.M ; Zn = 0.5 M.Z
        ns_body(Yc + off, Mb + off, Yn + off, 0.5f, 0.f, tile, t,
                Ap[0], Ap[1], Bp[0], Bp[1]);
        ns_body(Mb + off, Zc + off, Zn + off, 0.5f, 0.f, tile, t,
                Ap[0], Ap[1], Bp[0], Bp[1]);
        grid_bar(&bar[bi++], NS_BLOCKS);
        float* ty = Yc; Yc = Yn; Yn = ty;
        float* tz = Zc; Zc = Zn; Zn = tz;
    }
}

// ---------------------------------------------------------------------------
// FC: outpre[b,o] += sum_k sqrt(trace[b])*Yf[b,k] * Wfc[o,k]
// ---------------------------------------------------------------------------
__global__ __launch_bounds__(256) void fc_ker(const float* __restrict__ Yf,
                                              const float* __restrict__ trace,
                                              const float* __restrict__ Wfc,
                                              float* __restrict__ outpre) {
    int kc = blockIdx.x;
    int ot = blockIdx.y;
    int t = threadIdx.x;
    __shared__ float Wl[64][129];
    __shared__ float Vl[16][129];
#pragma unroll
    for (int i = 0; i < 32; ++i) {
        int l = i * 256 + t;
        int o = l >> 7, k = l & 127;
        Wl[o][k] = Wfc[(size_t)(ot * 64 + o) * 65536 + kc * 128 + k];
    }
#pragma unroll
    for (int i = 0; i < 8; ++i) {
        int l = i * 256 + t;
        int bb = l >> 7, k = l & 127;
        Vl[bb][k] = sqrtf(trace[bb]) * Yf[((size_t)bb << 16) + kc * 128 + k];
    }
    __syncthreads();
    int ol = t & 63, bg = t >> 6;
    float a0 = 0.f, a1 = 0.f, a2 = 0.f, a3 = 0.f;
    for (int k = 0; k < 128; ++k) {
        float w = Wl[ol][k];
        a0 = fmaf(w, Vl[bg * 4 + 0][k], a0);
        a1 = fmaf(w, Vl[bg * 4 + 1][k], a1);
        a2 = fmaf(w, Vl[bg * 4 + 2][k], a2);
        a3 = fmaf(w, Vl[bg * 4 + 3][k], a3);
    }
    int o = ot * 64 + ol;
    atomicAdd(&outpre[(bg * 4 + 0) * 256 + o], a0);
    atomicAdd(&outpre[(bg * 4 + 1) * 256 + o], a1);
    atomicAdd(&outpre[(bg * 4 + 2) * 256 + o], a2);
    atomicAdd(&outpre[(bg * 4 + 3) * 256 + o], a3);
}

__global__ void norm_ker(const float* __restrict__ outpre, const float* __restrict__ bfc,
                         float* __restrict__ dout) {
    int b = blockIdx.x, t = threadIdx.x;
    float v = outpre[b * 256 + t] + bfc[t];
    float q = v * v;
    for (int off = 32; off; off >>= 1) q += __shfl_xor(q, off);
    __shared__ float lq[4];
    __shared__ float snorm;
    if ((t & 63) == 0) lq[t >> 6] = q;
    __syncthreads();
    if (t == 0) snorm = fmaxf(sqrtf(lq[0] + lq[1] + lq[2] + lq[3]), 1e-12f);
    __syncthreads();
    dout[b * 256 + t] = v / snorm;
}

// ---------------------------------------------------------------------------
extern "C" void kernel_launch(void* const* d_in, const int* in_sizes, int n_in,
                              void* d_out, int out_size, void* d_ws, size_t ws_size,
                              hipStream_t stream) {
    (void)in_sizes; (void)n_in; (void)out_size; (void)ws_size;
    const float* pts = (const float*)d_in[0];
    const float* Wm[5]; const float* gm[5]; const float* bm[5];
    for (int i = 0; i < 5; ++i) {
        Wm[i] = (const float*)d_in[1 + 3 * i];
        gm[i] = (const float*)d_in[2 + 3 * i];
        bm[i] = (const float*)d_in[3 + 3 * i];
    }
    const float* Wfc = (const float*)d_in[16];
    const float* bfc = (const float*)d_in[17];

    float* ws     = (float*)d_ws;
    float* stats  = ws;                  // 2560
    float* fsumb  = ws + 2560;           // 4096
    float* trace  = ws + 6656;           // 16
    float* outpre = ws + 6672;           // 4096
    float* ss     = ws + 10768;          // 2560
    unsigned int* bar = (unsigned int*)(ws + 13400);   // 37 barrier counters
    float* R      = ws + 16384;          // 256ch fp32: 40,960,000 floats (y4)
    float* P      = R;                   // 64ch view (L0/L2 out)
    float* Q      = R + (size_t)NB * 256 * NPTS;   // 128ch: 20,480,000 floats
    // cov partials alias the (then-dead) Q region:
    // 20 chunks * 16 b * 3 tiles * 16384 = 15,728,640 floats < 20.48M
    float* covP   = Q;
    // NS buffers alias the (then-dead) R region (R dead after cov_mfma):
    float* Y0     = R;
    float* Y1     = Y0 + 1048576;
    float* Z0     = Y1 + 1048576;
    float* Z1     = Z0 + 1048576;
    float* Mb     = Z1 + 1048576;        // 5.24M floats << 40.96M of R

    hipMemsetAsync(ws, 0, 16384 * sizeof(float), stream);

    // Layer 0 (3 -> 64)
    conv0_ker<<<dim3(NBN / 256), dim3(256), 0, stream>>>(pts, Wm[0], P);
    chan_stats<<<dim3(64, NB), dim3(256), 0, stream>>>(P, 64, stats);
    bn_finalize<<<dim3(1), dim3(256), 0, stream>>>(stats, gm[0], bm[0], 64, ss);
    // Layer 1 (64 -> 64), stats fused
    conv_mfma<64, 64, 64><<<dim3(79, 1, NB), dim3(256), 0, stream>>>(P, ss, Wm[1], Q, stats + 512);
    bn_finalize<<<dim3(1), dim3(256), 0, stream>>>(stats + 512, gm[1], bm[1], 64, ss + 512);
    // Layer 2 (64 -> 64)
    conv_mfma<64, 64, 64><<<dim3(79, 1, NB), dim3(256), 0, stream>>>(Q, ss + 512, Wm[2], P, stats + 1024);
    bn_finalize<<<dim3(1), dim3(256), 0, stream>>>(stats + 1024, gm[2], bm[2], 64, ss + 1024);
    // Layer 3 (64 -> 128)
    conv_mfma<64, 128, 128><<<dim3(79, 1, NB), dim3(256), 0, stream>>>(P, ss + 1024, Wm[3], Q, stats + 1536);
    bn_finalize<<<dim3(1), dim3(256), 0, stream>>>(stats + 1536, gm[3], bm[3], 128, ss + 1536);
    // Layer 4 (128 -> 256); writes R (P is dead now)
    conv_mfma<128, 256, 128><<<dim3(79, 2, NB), dim3(256), 0, stream>>>(Q, ss + 1536, Wm[4], R, stats + 2048);
    bn_finalize<<<dim3(1), dim3(256), 0, stream>>>(stats + 2048, gm[4], bm[4], 256, ss + 2048);

    // Covariance path (fsum fused into cov_mfma; Q region hosts covP;
    // NS buffers go to R which dies after cov_mfma completes)
    cov_mfma<<<dim3(COV_CHUNKS, 3, NB), dim3(256), 0, stream>>>(R, ss + 2048, covP, fsumb);
    covfin_ker<<<dim3(256, NB), dim3(256), 0, stream>>>(covP, fsumb, Y0, trace);

    // Newton–Schulz: single fused kernel (ns_init prologue + 18 iters),
    // manual device-scope grid barriers (grid == 256 blocks -> co-resident)
    ns_fused<<<dim3(NS_BLOCKS), dim3(256), 0, stream>>>(Y0, Z0, Y1, Z1, Mb, trace, bar);

    // after 18 iterations (even), result is back in Y0
    fc_ker<<<dim3(512, 4), dim3(256), 0, stream>>>(Y0, trace, Wfc, outpre);
    norm_ker<<<dim3(NB), dim3(256), 0, stream>>>(outpre, bfc, (float*)d_out);
}

// Round 6
// 1109.125 us; speedup vs baseline: 2.0540x; 2.0540x over previous
//
#include <hip/hip_runtime.h>
#include <cmath>

constexpr int NB   = 16;      // batch
constexpr int NPTS = 10000;   // points per batch
constexpr int NBN  = NB * NPTS;   // 160000
constexpr int NS_ITERS = 18;
constexpr int COV_CHUNKS = 20;    // 500 points each
constexpr int CHUNK_PTS  = 500;
constexpr int COV_KK     = 16;    // 16*32 = 512 >= 500

typedef _Float16 f16x8 __attribute__((ext_vector_type(8)));
typedef float  f32x4  __attribute__((ext_vector_type(4)));
typedef unsigned short ushort4v __attribute__((ext_vector_type(4)));
typedef unsigned short ushort8v __attribute__((ext_vector_type(8)));

// ---------------------------------------------------------------------------
// Layer 0: 3 -> 64, no input BN
// ---------------------------------------------------------------------------
__global__ __launch_bounds__(256) void conv0_ker(const float* __restrict__ pts,
                                                 const float* __restrict__ W,
                                                 float* __restrict__ y) {
    int g = blockIdx.x * 256 + threadIdx.x;          // 0..159999
    int b = g / NPTS;
    int n = g - b * NPTS;
    float p0 = pts[3 * (size_t)g + 0];
    float p1 = pts[3 * (size_t)g + 1];
    float p2 = pts[3 * (size_t)g + 2];
    float* yp = y + ((size_t)b * 64) * NPTS + n;
    for (int o = 0; o < 64; ++o) {
        float v = W[3 * o] * p0 + W[3 * o + 1] * p1 + W[3 * o + 2] * p2;
        yp[(size_t)o * NPTS] = v;
    }
}

// ---------------------------------------------------------------------------
// split-fp16 helpers (hi = fp16(v), lo = fp16(v - hi)): 3-MFMA product keeps
// ~2^-22 relative accuracy, effectively fp32 for this pipeline.
// ---------------------------------------------------------------------------
__device__ __forceinline__ unsigned short f2h(float f) {
    return __builtin_bit_cast(unsigned short, (_Float16)f);
}
__device__ __forceinline__ float hres(float f) {
    return f - (float)(_Float16)f;
}
// LDS XOR-swizzle on ushort index (byte bits 5-6 ^= bits 8-9), 8-us aligned
__device__ __forceinline__ int swzu(int us) {
    return us ^ (((us >> 7) & 3) << 4);
}

// ---------------------------------------------------------------------------
// MFMA conv layer: y[b, ob+o, n] = sum_c W[ob+o, c] * relu(bn(x[b, c, n]))
// Block tile: OTILE x 128 points; waves 2x2 (OTILE=128) or 1x4 (OTILE=64).
// Fused BN-stats: per-channel sum/sumsq accumulated via shfl + LDS + atomics.
// ---------------------------------------------------------------------------
template <int CIN, int COUT, int OTILE>
__global__ __launch_bounds__(256) void conv_mfma(const float* __restrict__ xin,
                                                 const float* __restrict__ ss,
                                                 const float* __restrict__ W,
                                                 float* __restrict__ y,
                                                 float* __restrict__ stats) {
    constexpr int OT = OTILE / 16;
    constexpr int WM = 4;
    constexpr int WN = (OTILE == 128) ? 4 : 2;
    constexpr int NCW = (OTILE == 128) ? 2 : 4;   // distinct col-wave groups
    __shared__ unsigned short Xp[2][8 * 512];
    __shared__ unsigned short Wp[2][OT * 512];

    const int tid  = threadIdx.x;
    const int lane = tid & 63;
    const int w    = tid >> 6;
    const int wr   = (OTILE == 128) ? (w & 1) : 0;
    const int wc   = (OTILE == 128) ? (w >> 1) : w;

    const int nb = blockIdx.x * 128;
    const int ob = blockIdx.y * OTILE;
    const int b  = blockIdx.z;

    f32x4 acc[WM][WN];
#pragma unroll
    for (int m = 0; m < WM; ++m)
#pragma unroll
        for (int n = 0; n < WN; ++n) acc[m][n] = (f32x4){0.f, 0.f, 0.f, 0.f};

    const int xn = tid & 127;
    const int th = tid >> 7;
    const bool nok = (nb + xn) < NPTS;

#pragma unroll 1
    for (int kc = 0; kc < CIN; kc += 32) {
        __syncthreads();
        // ---- stage W[ob..ob+OTILE)[kc..kc+32) as split-fp16 A panels ----
#pragma unroll
        for (int i = 0; i < OTILE / 32; ++i) {
            int l = i * 256 + tid;
            int o = l >> 3, k4 = (l & 7) << 2;
            float4 v = *(const float4*)(W + (size_t)(ob + o) * CIN + kc + k4);
            ushort4v h4, l4;
            h4[0] = f2h(v.x); l4[0] = f2h(hres(v.x));
            h4[1] = f2h(v.y); l4[1] = f2h(hres(v.y));
            h4[2] = f2h(v.z); l4[2] = f2h(hres(v.z));
            h4[3] = f2h(v.w); l4[3] = f2h(hres(v.w));
            int us = swzu((o >> 4) * 512 + ((k4 >> 3) * 16 + (o & 15)) * 8 + (k4 & 7));
            *(ushort4v*)&Wp[0][us] = h4;
            *(ushort4v*)&Wp[1][us] = l4;
        }
        // ---- stage relu(bn(x))[kc..kc+32)[nb..nb+128) as split-fp16 B panels ----
#pragma unroll
        for (int qq = 0; qq < 2; ++qq) {
            int q = th * 2 + qq;
            const float* xb = xin + ((size_t)(b * CIN + kc + q * 8)) * NPTS + nb + xn;
            float f[8];
#pragma unroll
            for (int j = 0; j < 8; ++j) {
                float v = nok ? xb[(size_t)j * NPTS] : 0.f;
                int c = kc + q * 8 + j;
                f[j] = fmaxf(fmaf(v, ss[c], ss[256 + c]), 0.f);
            }
            ushort8v h8, l8;
#pragma unroll
            for (int j = 0; j < 8; ++j) {
                h8[j] = f2h(f[j]);
                l8[j] = f2h(hres(f[j]));
            }
            int us = swzu((xn >> 4) * 512 + (q * 16 + (xn & 15)) * 8);
            *(ushort8v*)&Xp[0][us] = h8;
            *(ushort8v*)&Xp[1][us] = l8;
        }
        __syncthreads();

        f16x8 ah[WM], al[WM], bh[WN], bl[WN];
#pragma unroll
        for (int m = 0; m < WM; ++m) {
            int us = swzu((wr * WM + m) * 512 + lane * 8);
            ah[m] = *(const f16x8*)&Wp[0][us];
            al[m] = *(const f16x8*)&Wp[1][us];
        }
#pragma unroll
        for (int n = 0; n < WN; ++n) {
            int us = swzu((wc * WN + n) * 512 + lane * 8);
            bh[n] = *(const f16x8*)&Xp[0][us];
            bl[n] = *(const f16x8*)&Xp[1][us];
        }
#pragma unroll
        for (int m = 0; m < WM; ++m)
#pragma unroll
            for (int n = 0; n < WN; ++n) {
                acc[m][n] = __builtin_amdgcn_mfma_f32_16x16x32_f16(ah[m], bh[n], acc[m][n], 0, 0, 0);
                acc[m][n] = __builtin_amdgcn_mfma_f32_16x16x32_f16(ah[m], bl[n], acc[m][n], 0, 0, 0);
                acc[m][n] = __builtin_amdgcn_mfma_f32_16x16x32_f16(al[m], bh[n], acc[m][n], 0, 0, 0);
            }
    }

    // ---- epilogue: stores ----
    const int ro = (lane >> 4) * 4;
    const int co = lane & 15;
#pragma unroll
    for (int m = 0; m < WM; ++m) {
        int o = ob + wr * (WM * 16) + m * 16 + ro;
#pragma unroll
        for (int n = 0; n < WN; ++n) {
            int col = nb + wc * (WN * 16) + n * 16 + co;
            if (col < NPTS) {
                float* yp = y + ((size_t)(b * COUT + o)) * NPTS + col;
#pragma unroll
                for (int r = 0; r < 4; ++r)
                    yp[(size_t)r * NPTS] = acc[m][n][r];
            }
        }
    }

    // ---- fused BN-stats: per-channel sum / sumsq over valid columns ----
    __syncthreads();                       // all waves done reading Xp/Wp
    float* sbuf = (float*)&Xp[0][0];       // [NCW][OTILE]
    float* qbuf = sbuf + NCW * OTILE;
#pragma unroll
    for (int m = 0; m < WM; ++m)
#pragma unroll
        for (int r = 0; r < 4; ++r) {
            float s = 0.f, q = 0.f;
#pragma unroll
            for (int n = 0; n < WN; ++n) {
                int col = nb + wc * (WN * 16) + n * 16 + co;
                float v = acc[m][n][r];
                if (col < NPTS) { s += v; q = fmaf(v, v, q); }
            }
            s += __shfl_xor(s, 1); q += __shfl_xor(q, 1);
            s += __shfl_xor(s, 2); q += __shfl_xor(q, 2);
            s += __shfl_xor(s, 4); q += __shfl_xor(q, 4);
            s += __shfl_xor(s, 8); q += __shfl_xor(q, 8);
            if (co == 0) {
                int rowl = wr * (WM * 16) + m * 16 + ro + r;   // 0..OTILE-1
                sbuf[wc * OTILE + rowl] = s;
                qbuf[wc * OTILE + rowl] = q;
            }
        }
    __syncthreads();
    if (tid < OTILE) {
        float s = 0.f, q = 0.f;
#pragma unroll
        for (int j = 0; j < NCW; ++j) {
            s += sbuf[j * OTILE + tid];
            q += qbuf[j * OTILE + tid];
        }
        atomicAdd(&stats[ob + tid], s);
        atomicAdd(&stats[COUT + ob + tid], q);
    }
}

// ---------------------------------------------------------------------------
// Per-channel sum / sumsq over (batch, points)  -> stats[c], stats[C+c]
// (layer-0 output only; later layers fuse stats into conv_mfma)
// ---------------------------------------------------------------------------
__global__ void chan_stats(const float* __restrict__ y, int C, float* __restrict__ stats) {
    int c = blockIdx.x, b = blockIdx.y, t = threadIdx.x;
    const float* p = y + ((size_t)(b * C + c)) * NPTS;
    float s = 0.f, q = 0.f;
    for (int n = t; n < NPTS; n += 256) {
        float v = p[n];
        s += v;
        q = fmaf(v, v, q);
    }
    for (int off = 32; off; off >>= 1) {
        s += __shfl_down(s, off);
        q += __shfl_down(q, off);
    }
    __shared__ float ls[4], lq[4];
    if ((t & 63) == 0) { ls[t >> 6] = s; lq[t >> 6] = q; }
    __syncthreads();
    if (t == 0) {
        atomicAdd(&stats[c],     ls[0] + ls[1] + ls[2] + ls[3]);
        atomicAdd(&stats[C + c], lq[0] + lq[1] + lq[2] + lq[3]);
    }
}

__global__ void bn_finalize(const float* __restrict__ stats, const float* __restrict__ g,
                            const float* __restrict__ bi, int C, float* __restrict__ ss) {
    int c = threadIdx.x;
    if (c < C) {
        float mu  = stats[c] * (1.f / NBN);
        float var = stats[C + c] * (1.f / NBN) - mu * mu;
        float r = rsqrtf(var + 1e-5f);
        float s = g[c] * r;
        ss[c] = s;
        ss[256 + c] = bi[c] - mu * s;
    }
}

// ---------------------------------------------------------------------------
// Split-fp16 MFMA second moment: covP[chunk][b][tile] 128x128 += F F^T
// over CHUNK_PTS points.  Also accumulates per-(b,channel) relu-sums into
// fsumb (tiles 0/1 cover every channel exactly once per chunk).
// grid: (COV_CHUNKS, 3 tiles{(0,0),(1,1),(0,1)}, 16 batches) = 960 blocks.
// ---------------------------------------------------------------------------
__device__ __forceinline__ int swz8(int byteoff) {
    return byteoff ^ (((byteoff >> 8) & 3) << 5);
}

__global__ __launch_bounds__(256) void cov_mfma(const float* __restrict__ y4,
                                                const float* __restrict__ ss,
                                                float* __restrict__ covP,
                                                float* __restrict__ fsumb) {
    __shared__ unsigned short pan[2][2][4096];   // [panel][hi/lo][8 frag-tiles * 512]

    const int chunk = blockIdx.x;
    const int tile  = blockIdx.y;
    const int b     = blockIdx.z;
    const int ti = (tile == 1) ? 1 : 0;
    const int tj = (tile == 0) ? 0 : 1;
    const int npan = (tile == 2) ? 2 : 1;

    const int tid  = threadIdx.x;
    const int lane = tid & 63;
    const int w    = tid >> 6;
    const int wr   = w & 1, wc = w >> 1;

    const int n0c = chunk * CHUNK_PTS;

    f32x4 acc[4][4];
#pragma unroll
    for (int m = 0; m < 4; ++m)
#pragma unroll
        for (int n = 0; n < 4; ++n) acc[m][n] = (f32x4){0.f, 0.f, 0.f, 0.f};

    // staging assignment: 8 point-groups (4 pts) x 32 channel-bases
    const int g   = tid & 7;
    const int chb = tid >> 3;          // 0..31
    const int p4  = g * 4;             // point offset in 32-chunk
    const int q   = p4 >> 3, j0 = p4 & 7;

    float fs[4] = {0.f, 0.f, 0.f, 0.f};   // per-thread channel relu-sums (tiles 0/1)

#pragma unroll 1
    for (int kk = 0; kk < COV_KK; ++kk) {        // 16*32 = 512 >= 500
        const int nbase = n0c + kk * 32;
        __syncthreads();
        for (int p = 0; p < npan; ++p) {
            const int pcb = (p ? tj : ti) * 128;
#pragma unroll
            for (int i = 0; i < 4; ++i) {
                const int ch = chb + 32 * i;
                float4 v = make_float4(0.f, 0.f, 0.f, 0.f);
                if (kk * 32 + p4 < CHUNK_PTS) {
                    v = *(const float4*)(y4 + ((size_t)(b * 256 + pcb + ch)) * NPTS + nbase + p4);
                    float sc = ss[pcb + ch], sh = ss[256 + pcb + ch];
                    v.x = fmaxf(fmaf(v.x, sc, sh), 0.f);
                    v.y = fmaxf(fmaf(v.y, sc, sh), 0.f);
                    v.z = fmaxf(fmaf(v.z, sc, sh), 0.f);
                    v.w = fmaxf(fmaf(v.w, sc, sh), 0.f);
                }
                if (npan == 1) fs[i] += (v.x + v.y) + (v.z + v.w);
                ushort4v h4, l4;
                h4[0] = f2h(v.x); l4[0] = f2h(hres(v.x));
                h4[1] = f2h(v.y); l4[1] = f2h(hres(v.y));
                h4[2] = f2h(v.z); l4[2] = f2h(hres(v.z));
                h4[3] = f2h(v.w); l4[3] = f2h(hres(v.w));
                const int addr = (ch >> 4) * 512 + (q * 16 + (ch & 15)) * 8 + j0;
                const int sa = swz8(addr * 2) >> 1;
                *(ushort4v*)&pan[p][0][sa] = h4;
                *(ushort4v*)&pan[p][1][sa] = l4;
            }
        }
        __syncthreads();

        const unsigned short* Ah = pan[0][0];
        const unsigned short* Al = pan[0][1];
        const unsigned short* Bh = pan[npan - 1][0];
        const unsigned short* Bl = pan[npan - 1][1];

        f16x8 ah[4], al[4], bh[4], bl[4];
#pragma unroll
        for (int m = 0; m < 4; ++m) {
            int t8 = (wr * 4 + m) * 512 + lane * 8;
            int sa = swz8(t8 * 2) >> 1;
            ah[m] = *(const f16x8*)&Ah[sa];
            al[m] = *(const f16x8*)&Al[sa];
        }
#pragma unroll
        for (int n = 0; n < 4; ++n) {
            int t8 = (wc * 4 + n) * 512 + lane * 8;
            int sa = swz8(t8 * 2) >> 1;
            bh[n] = *(const f16x8*)&Bh[sa];
            bl[n] = *(const f16x8*)&Bl[sa];
        }
#pragma unroll
        for (int m = 0; m < 4; ++m)
#pragma unroll
            for (int n = 0; n < 4; ++n) {
                acc[m][n] = __builtin_amdgcn_mfma_f32_16x16x32_f16(ah[m], bh[n], acc[m][n], 0, 0, 0);
                acc[m][n] = __builtin_amdgcn_mfma_f32_16x16x32_f16(ah[m], bl[n], acc[m][n], 0, 0, 0);
                acc[m][n] = __builtin_amdgcn_mfma_f32_16x16x32_f16(al[m], bh[n], acc[m][n], 0, 0, 0);
            }
    }

    // fused per-channel relu-sum contribution (tiles 0/1 only)
    if (npan == 1) {
#pragma unroll
        for (int i = 0; i < 4; ++i) {
            float s = fs[i];
            s += __shfl_xor(s, 1);
            s += __shfl_xor(s, 2);
            s += __shfl_xor(s, 4);
            if (g == 0)
                atomicAdd(&fsumb[b * 256 + ti * 128 + chb + 32 * i], s);
        }
    }

    // epilogue: packed per-(chunk,b,tile) 128x128 partial buffer (no atomics)
    float* outp = covP + (((size_t)(chunk * NB + b) * 3 + tile) << 14);
    const int rowb = wr * 64;
    const int colb = wc * 64;
#pragma unroll
    for (int m = 0; m < 4; ++m)
#pragma unroll
        for (int n = 0; n < 4; ++n)
#pragma unroll
            for (int r = 0; r < 4; ++r) {
                int row = rowb + m * 16 + (lane >> 4) * 4 + r;
                int col = colb + n * 16 + (lane & 15);
                outp[(row << 7) + col] = acc[m][n][r];
            }
}

// ---------------------------------------------------------------------------
// cov = (sum_q covP[q])/N - m fbar^T - fbar m^T + m m^T ; mirror tile (1,0)
// covP layout: [chunk][b][tile 0:(0,0) 1:(1,1) 2:(0,1)][128][128]
// ---------------------------------------------------------------------------
__global__ void covfin_ker(const float* __restrict__ covP, const float* __restrict__ fsumb,
                           float* __restrict__ Y0, float* __restrict__ trace) {
    int r = blockIdx.x, b = blockIdx.y, c = threadIdx.x;
    float fbr = fsumb[b * 256 + r] * (1.f / NPTS);
    float fbc = fsumb[b * 256 + c] * (1.f / NPTS);
    float mr = 0.f, mc = 0.f;
    for (int q = 0; q < NB; ++q) {
        mr += fsumb[q * 256 + r];
        mc += fsumb[q * 256 + c];
    }
    mr *= (1.f / NBN);
    mc *= (1.f / NBN);
    int tile, rr, cc;
    if (r < 128 && c < 128)        { tile = 0; rr = r;       cc = c; }
    else if (r >= 128 && c >= 128) { tile = 1; rr = r - 128; cc = c - 128; }
    else if (r < 128)              { tile = 2; rr = r;       cc = c - 128; }   // (0,1)
    else                           { tile = 2; rr = c;       cc = r - 128; }   // (1,0) mirror
    size_t base = (((size_t)b * 3 + tile) << 14) + ((size_t)rr << 7) + cc;
    float m5 = 0.f;
#pragma unroll
    for (int q = 0; q < COV_CHUNKS; ++q)
        m5 += covP[(size_t)q * (NB * 3 * 16384) + base];
    float v = m5 * (1.f / NPTS) - fbr * mc - mr * fbc + mr * mc;
    Y0[((size_t)b << 16) + ((size_t)r << 8) + c] = v;
    if (c == r) atomicAdd(&trace[b], v);
}

__global__ void ns_init(float* __restrict__ Y0, float* __restrict__ Z0,
                        const float* __restrict__ trace) {
    int i = blockIdx.x * 256 + threadIdx.x;   // 16*65536 total
    int b = i >> 16, rc = i & 65535;
    float inv = 1.f / trace[b];
    Y0[i] *= inv;
    Z0[i] = ((rc >> 8) == (rc & 255)) ? 1.f : 0.f;
}

// ---------------------------------------------------------------------------
// Newton-Schulz batched 256x256 GEMM tile body via split-fp16 MFMA.
// O = diag*I + scale*(A.B); block computes 64x64 tile.
// v2: B column-panel staged per 128-k half (2 sync pairs per GEMM, not 8);
// A fragments read directly from global (L2-resident matrices).
// B panel layout per half: tile ((col>>4)*4 + kb)*512 + (kq*16+(col&15))*8+j
// -- identical fragment scheme as the verified cov/conv kernels.
// ---------------------------------------------------------------------------
__device__ __forceinline__ void ns_body2(const float* __restrict__ Ab,
                                         const float* __restrict__ Bb,
                                         float* __restrict__ Ob,
                                         float scale, float diag, int tile, int tid,
                                         unsigned short* Bp0, unsigned short* Bp1) {
    const int lane = tid & 63;
    const int w    = tid >> 6;
    const int wr   = w & 1, wc = w >> 1;
    const int tr = (tile >> 2) * 64, tc = (tile & 3) * 64;

    const int fA = tid & 63;       // staged col
    const int kq = tid >> 6;       // k-octet within 32 (== wave id)

    f32x4 acc[2][2];
#pragma unroll
    for (int m = 0; m < 2; ++m)
#pragma unroll
        for (int n = 0; n < 2; ++n) acc[m][n] = (f32x4){0.f, 0.f, 0.f, 0.f};

#pragma unroll 1
    for (int half = 0; half < 2; ++half) {
        __syncthreads();               // protect panel reuse (incl. across calls)
        // ---- stage B[half*128 .. +128)[tc..tc+64) split-fp16 ----
#pragma unroll
        for (int kb = 0; kb < 4; ++kb) {
            const int k0 = half * 128 + kb * 32 + kq * 8;
            const float* bp = Bb + (size_t)k0 * 256 + tc + fA;
            float bv[8];
#pragma unroll
            for (int j = 0; j < 8; ++j) bv[j] = bp[(size_t)j * 256];
            ushort8v bh8, bl8;
#pragma unroll
            for (int j = 0; j < 8; ++j) {
                bh8[j] = f2h(bv[j]);
                bl8[j] = f2h(hres(bv[j]));
            }
            const int ua = ((fA >> 4) * 4 + kb) * 512 + (kq * 16 + (fA & 15)) * 8;
            *(ushort8v*)&Bp0[ua] = bh8;
            *(ushort8v*)&Bp1[ua] = bl8;
        }
        __syncthreads();

        // ---- compute 4 k-blocks of 32 ----
#pragma unroll
        for (int kk = 0; kk < 4; ++kk) {
            f16x8 a_h[2], a_l[2];
#pragma unroll
            for (int m = 0; m < 2; ++m) {
                const float* ap = Ab
                    + (size_t)(tr + (wr * 2 + m) * 16 + (lane & 15)) * 256
                    + half * 128 + kk * 32 + (lane >> 4) * 8;
                float av[8];
                *(float4*)&av[0] = *(const float4*)ap;
                *(float4*)&av[4] = *(const float4*)(ap + 4);
                ushort8v h8, l8;
#pragma unroll
                for (int j = 0; j < 8; ++j) {
                    h8[j] = f2h(av[j]);
                    l8[j] = f2h(hres(av[j]));
                }
                a_h[m] = __builtin_bit_cast(f16x8, h8);
                a_l[m] = __builtin_bit_cast(f16x8, l8);
            }
            f16x8 b_h[2], b_l[2];
#pragma unroll
            for (int n = 0; n < 2; ++n) {
                int u = ((wc * 2 + n) * 4 + kk) * 512 + lane * 8;
                b_h[n] = *(const f16x8*)&Bp0[u];
                b_l[n] = *(const f16x8*)&Bp1[u];
            }
#pragma unroll
            for (int m = 0; m < 2; ++m)
#pragma unroll
                for (int n = 0; n < 2; ++n) {
                    acc[m][n] = __builtin_amdgcn_mfma_f32_16x16x32_f16(a_h[m], b_h[n], acc[m][n], 0, 0, 0);
                    acc[m][n] = __builtin_amdgcn_mfma_f32_16x16x32_f16(a_h[m], b_l[n], acc[m][n], 0, 0, 0);
                    acc[m][n] = __builtin_amdgcn_mfma_f32_16x16x32_f16(a_l[m], b_h[n], acc[m][n], 0, 0, 0);
                }
        }
    }

    const int ro = (lane >> 4) * 4, co = lane & 15;
#pragma unroll
    for (int m = 0; m < 2; ++m)
#pragma unroll
        for (int n = 0; n < 2; ++n) {
            int row = tr + wr * 32 + m * 16 + ro;
            int col = tc + wc * 32 + n * 16 + co;
#pragma unroll
            for (int r = 0; r < 4; ++r) {
                float v = scale * acc[m][n][r] + (((row + r) == col) ? diag : 0.f);
                Ob[(size_t)(row + r) * 256 + col] = v;
            }
        }
}

__global__ __launch_bounds__(256) void ns_gemm(const float* __restrict__ A,
                                               const float* __restrict__ B,
                                               float* __restrict__ O,
                                               float scale, float diag) {
    __shared__ unsigned short Bp[2][8192];    // 32 KB
    size_t off = (size_t)blockIdx.y << 16;
    ns_body2(A + off, B + off, O + off, scale, diag, blockIdx.x, threadIdx.x,
             Bp[0], Bp[1]);
}

__global__ __launch_bounds__(256) void ns_gemm_pair(const float* __restrict__ Y,
                                                    const float* __restrict__ Mm,
                                                    const float* __restrict__ Z,
                                                    float* __restrict__ Yn,
                                                    float* __restrict__ Zn) {
    __shared__ unsigned short Bp[2][8192];    // 32 KB
    size_t off = (size_t)blockIdx.y << 16;
    if (blockIdx.z == 0)
        ns_body2(Y + off, Mm + off, Yn + off, 0.5f, 0.f, blockIdx.x, threadIdx.x,
                 Bp[0], Bp[1]);
    else
        ns_body2(Mm + off, Z + off, Zn + off, 0.5f, 0.f, blockIdx.x, threadIdx.x,
                 Bp[0], Bp[1]);
}

// ---------------------------------------------------------------------------
// FC: outpre[b,o] += sum_k sqrt(trace[b])*Yf[b,k] * Wfc[o,k]
// ---------------------------------------------------------------------------
__global__ __launch_bounds__(256) void fc_ker(const float* __restrict__ Yf,
                                              const float* __restrict__ trace,
                                              const float* __restrict__ Wfc,
                                              float* __restrict__ outpre) {
    int kc = blockIdx.x;
    int ot = blockIdx.y;
    int t = threadIdx.x;
    __shared__ float Wl[64][129];
    __shared__ float Vl[16][129];
#pragma unroll
    for (int i = 0; i < 32; ++i) {
        int l = i * 256 + t;
        int o = l >> 7, k = l & 127;
        Wl[o][k] = Wfc[(size_t)(ot * 64 + o) * 65536 + kc * 128 + k];
    }
#pragma unroll
    for (int i = 0; i < 8; ++i) {
        int l = i * 256 + t;
        int bb = l >> 7, k = l & 127;
        Vl[bb][k] = sqrtf(trace[bb]) * Yf[((size_t)bb << 16) + kc * 128 + k];
    }
    __syncthreads();
    int ol = t & 63, bg = t >> 6;
    float a0 = 0.f, a1 = 0.f, a2 = 0.f, a3 = 0.f;
    for (int k = 0; k < 128; ++k) {
        float w = Wl[ol][k];
        a0 = fmaf(w, Vl[bg * 4 + 0][k], a0);
        a1 = fmaf(w, Vl[bg * 4 + 1][k], a1);
        a2 = fmaf(w, Vl[bg * 4 + 2][k], a2);
        a3 = fmaf(w, Vl[bg * 4 + 3][k], a3);
    }
    int o = ot * 64 + ol;
    atomicAdd(&outpre[(bg * 4 + 0) * 256 + o], a0);
    atomicAdd(&outpre[(bg * 4 + 1) * 256 + o], a1);
    atomicAdd(&outpre[(bg * 4 + 2) * 256 + o], a2);
    atomicAdd(&outpre[(bg * 4 + 3) * 256 + o], a3);
}

__global__ void norm_ker(const float* __restrict__ outpre, const float* __restrict__ bfc,
                         float* __restrict__ dout) {
    int b = blockIdx.x, t = threadIdx.x;
    float v = outpre[b * 256 + t] + bfc[t];
    float q = v * v;
    for (int off = 32; off; off >>= 1) q += __shfl_xor(q, off);
    __shared__ float lq[4];
    __shared__ float snorm;
    if ((t & 63) == 0) lq[t >> 6] = q;
    __syncthreads();
    if (t == 0) snorm = fmaxf(sqrtf(lq[0] + lq[1] + lq[2] + lq[3]), 1e-12f);
    __syncthreads();
    dout[b * 256 + t] = v / snorm;
}

// ---------------------------------------------------------------------------
extern "C" void kernel_launch(void* const* d_in, const int* in_sizes, int n_in,
                              void* d_out, int out_size, void* d_ws, size_t ws_size,
                              hipStream_t stream) {
    (void)in_sizes; (void)n_in; (void)out_size; (void)ws_size;
    const float* pts = (const float*)d_in[0];
    const float* Wm[5]; const float* gm[5]; const float* bm[5];
    for (int i = 0; i < 5; ++i) {
        Wm[i] = (const float*)d_in[1 + 3 * i];
        gm[i] = (const float*)d_in[2 + 3 * i];
        bm[i] = (const float*)d_in[3 + 3 * i];
    }
    const float* Wfc = (const float*)d_in[16];
    const float* bfc = (const float*)d_in[17];

    float* ws     = (float*)d_ws;
    float* stats  = ws;                  // 2560
    float* fsumb  = ws + 2560;           // 4096
    float* trace  = ws + 6656;           // 16
    float* outpre = ws + 6672;           // 4096
    float* ss     = ws + 10768;          // 2560
    float* R      = ws + 16384;          // 256ch fp32: 40,960,000 floats (y4)
    float* P      = R;                   // 64ch view (L0/L2 out)
    float* Q      = R + (size_t)NB * 256 * NPTS;   // 128ch: 20,480,000 floats
    // cov partials alias the (then-dead) Q region:
    // 20 chunks * 16 b * 3 tiles * 16384 = 15,728,640 floats < 20.48M
    float* covP   = Q;
    // NS buffers alias the (then-dead) R region (R dead after cov_mfma):
    float* Y0     = R;
    float* Y1     = Y0 + 1048576;
    float* Z0     = Y1 + 1048576;
    float* Z1     = Z0 + 1048576;
    float* Mb     = Z1 + 1048576;        // 5.24M floats << 40.96M of R

    hipMemsetAsync(ws, 0, 16384 * sizeof(float), stream);

    // Layer 0 (3 -> 64)
    conv0_ker<<<dim3(NBN / 256), dim3(256), 0, stream>>>(pts, Wm[0], P);
    chan_stats<<<dim3(64, NB), dim3(256), 0, stream>>>(P, 64, stats);
    bn_finalize<<<dim3(1), dim3(256), 0, stream>>>(stats, gm[0], bm[0], 64, ss);
    // Layer 1 (64 -> 64), stats fused
    conv_mfma<64, 64, 64><<<dim3(79, 1, NB), dim3(256), 0, stream>>>(P, ss, Wm[1], Q, stats + 512);
    bn_finalize<<<dim3(1), dim3(256), 0, stream>>>(stats + 512, gm[1], bm[1], 64, ss + 512);
    // Layer 2 (64 -> 64)
    conv_mfma<64, 64, 64><<<dim3(79, 1, NB), dim3(256), 0, stream>>>(Q, ss + 512, Wm[2], P, stats + 1024);
    bn_finalize<<<dim3(1), dim3(256), 0, stream>>>(stats + 1024, gm[2], bm[2], 64, ss + 1024);
    // Layer 3 (64 -> 128)
    conv_mfma<64, 128, 128><<<dim3(79, 1, NB), dim3(256), 0, stream>>>(P, ss + 1024, Wm[3], Q, stats + 1536);
    bn_finalize<<<dim3(1), dim3(256), 0, stream>>>(stats + 1536, gm[3], bm[3], 128, ss + 1536);
    // Layer 4 (128 -> 256); writes R (P is dead now)
    conv_mfma<128, 256, 128><<<dim3(79, 2, NB), dim3(256), 0, stream>>>(Q, ss + 1536, Wm[4], R, stats + 2048);
    bn_finalize<<<dim3(1), dim3(256), 0, stream>>>(stats + 2048, gm[4], bm[4], 256, ss + 2048);

    // Covariance path (fsum fused into cov_mfma; Q region hosts covP;
    // NS buffers go to R which dies after cov_mfma completes)
    cov_mfma<<<dim3(COV_CHUNKS, 3, NB), dim3(256), 0, stream>>>(R, ss + 2048, covP, fsumb);
    covfin_ker<<<dim3(256, NB), dim3(256), 0, stream>>>(covP, fsumb, Y0, trace);
    ns_init<<<dim3(4096), dim3(256), 0, stream>>>(Y0, Z0, trace);

    // Newton–Schulz iterations (split-fp16 MFMA, single-staged B panels)
    float* Yc = Y0; float* Zc = Z0; float* Yn = Y1; float* Zn = Z1;
    for (int it = 0; it < NS_ITERS; ++it) {
        ns_gemm<<<dim3(16, NB), dim3(256), 0, stream>>>(Zc, Yc, Mb, -1.f, 3.f);
        ns_gemm_pair<<<dim3(16, NB, 2), dim3(256), 0, stream>>>(Yc, Mb, Zc, Yn, Zn);
        float* ty = Yc; Yc = Yn; Yn = ty;
        float* tz = Zc; Zc = Zn; Zn = tz;
    }

    fc_ker<<<dim3(512, 4), dim3(256), 0, stream>>>(Yc, trace, Wfc, outpre);
    norm_ker<<<dim3(NB), dim3(256), 0, stream>>>(outpre, bfc, (float*)d_out);
}

// Round 8
// 1014.304 us; speedup vs baseline: 2.2460x; 1.0935x over previous
//
#include <hip/hip_runtime.h>
#include <cmath>

constexpr int NB   = 16;      // batch
constexpr int NPTS = 10000;   // points per batch
constexpr int NBN  = NB * NPTS;   // 160000
constexpr int NS_ITERS = 18;
constexpr int COV_CHUNKS = 20;    // 500 points each
constexpr int CHUNK_PTS  = 500;
constexpr int COV_KK     = 16;    // 16*32 = 512 >= 500

typedef _Float16 f16x8 __attribute__((ext_vector_type(8)));
typedef float  f32x4  __attribute__((ext_vector_type(4)));
typedef unsigned short ushort4v __attribute__((ext_vector_type(4)));
typedef unsigned short ushort8v __attribute__((ext_vector_type(8)));

// ---------------------------------------------------------------------------
// Layer 0: 3 -> 64, no input BN
// ---------------------------------------------------------------------------
__global__ __launch_bounds__(256) void conv0_ker(const float* __restrict__ pts,
                                                 const float* __restrict__ W,
                                                 float* __restrict__ y) {
    int g = blockIdx.x * 256 + threadIdx.x;          // 0..159999
    int b = g / NPTS;
    int n = g - b * NPTS;
    float p0 = pts[3 * (size_t)g + 0];
    float p1 = pts[3 * (size_t)g + 1];
    float p2 = pts[3 * (size_t)g + 2];
    float* yp = y + ((size_t)b * 64) * NPTS + n;
    for (int o = 0; o < 64; ++o) {
        float v = W[3 * o] * p0 + W[3 * o + 1] * p1 + W[3 * o + 2] * p2;
        yp[(size_t)o * NPTS] = v;
    }
}

// ---------------------------------------------------------------------------
// split-fp16 helpers (hi = fp16(v), lo = fp16(v - hi)): 3-MFMA product keeps
// ~2^-22 relative accuracy, effectively fp32 for this pipeline.
// ---------------------------------------------------------------------------
__device__ __forceinline__ unsigned short f2h(float f) {
    return __builtin_bit_cast(unsigned short, (_Float16)f);
}
__device__ __forceinline__ float hres(float f) {
    return f - (float)(_Float16)f;
}
// LDS XOR-swizzles (involutions, applied on both write & read)
__device__ __forceinline__ int swzu(int us) {        // conv panels
    return us ^ (((us >> 7) & 3) << 4);
}
__device__ __forceinline__ int swz8(int byteoff) {   // cov panels
    return byteoff ^ (((byteoff >> 8) & 3) << 5);
}

// ---------------------------------------------------------------------------
// MFMA conv layer: y[b, ob+o, n] = sum_c W[ob+o, c] * relu(bn(x[b, c, n]))
// Block tile: OTILE x 128 points; waves 2x2 (OTILE=128) or 1x4 (OTILE=64).
// Fused BN-stats: per-channel sum/sumsq accumulated via shfl + LDS + atomics.
// ---------------------------------------------------------------------------
template <int CIN, int COUT, int OTILE>
__global__ __launch_bounds__(256) void conv_mfma(const float* __restrict__ xin,
                                                 const float* __restrict__ ss,
                                                 const float* __restrict__ W,
                                                 float* __restrict__ y,
                                                 float* __restrict__ stats) {
    constexpr int OT = OTILE / 16;
    constexpr int WM = 4;
    constexpr int WN = (OTILE == 128) ? 4 : 2;
    constexpr int NCW = (OTILE == 128) ? 2 : 4;   // distinct col-wave groups
    __shared__ unsigned short Xp[2][8 * 512];
    __shared__ unsigned short Wp[2][OT * 512];

    const int tid  = threadIdx.x;
    const int lane = tid & 63;
    const int w    = tid >> 6;
    const int wr   = (OTILE == 128) ? (w & 1) : 0;
    const int wc   = (OTILE == 128) ? (w >> 1) : w;

    const int nb = blockIdx.x * 128;
    const int ob = blockIdx.y * OTILE;
    const int b  = blockIdx.z;

    f32x4 acc[WM][WN];
#pragma unroll
    for (int m = 0; m < WM; ++m)
#pragma unroll
        for (int n = 0; n < WN; ++n) acc[m][n] = (f32x4){0.f, 0.f, 0.f, 0.f};

    const int xn = tid & 127;
    const int th = tid >> 7;
    const bool nok = (nb + xn) < NPTS;

#pragma unroll 1
    for (int kc = 0; kc < CIN; kc += 32) {
        __syncthreads();
        // ---- stage W[ob..ob+OTILE)[kc..kc+32) as split-fp16 A panels ----
#pragma unroll
        for (int i = 0; i < OTILE / 32; ++i) {
            int l = i * 256 + tid;
            int o = l >> 3, k4 = (l & 7) << 2;
            float4 v = *(const float4*)(W + (size_t)(ob + o) * CIN + kc + k4);
            ushort4v h4, l4;
            h4[0] = f2h(v.x); l4[0] = f2h(hres(v.x));
            h4[1] = f2h(v.y); l4[1] = f2h(hres(v.y));
            h4[2] = f2h(v.z); l4[2] = f2h(hres(v.z));
            h4[3] = f2h(v.w); l4[3] = f2h(hres(v.w));
            int us = swzu((o >> 4) * 512 + ((k4 >> 3) * 16 + (o & 15)) * 8 + (k4 & 7));
            *(ushort4v*)&Wp[0][us] = h4;
            *(ushort4v*)&Wp[1][us] = l4;
        }
        // ---- stage relu(bn(x))[kc..kc+32)[nb..nb+128) as split-fp16 B panels ----
#pragma unroll
        for (int qq = 0; qq < 2; ++qq) {
            int q = th * 2 + qq;
            const float* xb = xin + ((size_t)(b * CIN + kc + q * 8)) * NPTS + nb + xn;
            float f[8];
#pragma unroll
            for (int j = 0; j < 8; ++j) {
                float v = nok ? xb[(size_t)j * NPTS] : 0.f;
                int c = kc + q * 8 + j;
                f[j] = fmaxf(fmaf(v, ss[c], ss[256 + c]), 0.f);
            }
            ushort8v h8, l8;
#pragma unroll
            for (int j = 0; j < 8; ++j) {
                h8[j] = f2h(f[j]);
                l8[j] = f2h(hres(f[j]));
            }
            int us = swzu((xn >> 4) * 512 + (q * 16 + (xn & 15)) * 8);
            *(ushort8v*)&Xp[0][us] = h8;
            *(ushort8v*)&Xp[1][us] = l8;
        }
        __syncthreads();

        f16x8 ah[WM], al[WM], bh[WN], bl[WN];
#pragma unroll
        for (int m = 0; m < WM; ++m) {
            int us = swzu((wr * WM + m) * 512 + lane * 8);
            ah[m] = *(const f16x8*)&Wp[0][us];
            al[m] = *(const f16x8*)&Wp[1][us];
        }
#pragma unroll
        for (int n = 0; n < WN; ++n) {
            int us = swzu((wc * WN + n) * 512 + lane * 8);
            bh[n] = *(const f16x8*)&Xp[0][us];
            bl[n] = *(const f16x8*)&Xp[1][us];
        }
#pragma unroll
        for (int m = 0; m < WM; ++m)
#pragma unroll
            for (int n = 0; n < WN; ++n) {
                acc[m][n] = __builtin_amdgcn_mfma_f32_16x16x32_f16(ah[m], bh[n], acc[m][n], 0, 0, 0);
                acc[m][n] = __builtin_amdgcn_mfma_f32_16x16x32_f16(ah[m], bl[n], acc[m][n], 0, 0, 0);
                acc[m][n] = __builtin_amdgcn_mfma_f32_16x16x32_f16(al[m], bh[n], acc[m][n], 0, 0, 0);
            }
    }

    // ---- epilogue: stores ----
    const int ro = (lane >> 4) * 4;
    const int co = lane & 15;
#pragma unroll
    for (int m = 0; m < WM; ++m) {
        int o = ob + wr * (WM * 16) + m * 16 + ro;
#pragma unroll
        for (int n = 0; n < WN; ++n) {
            int col = nb + wc * (WN * 16) + n * 16 + co;
            if (col < NPTS) {
                float* yp = y + ((size_t)(b * COUT + o)) * NPTS + col;
#pragma unroll
                for (int r = 0; r < 4; ++r)
                    yp[(size_t)r * NPTS] = acc[m][n][r];
            }
        }
    }

    // ---- fused BN-stats: per-channel sum / sumsq over valid columns ----
    __syncthreads();                       // all waves done reading Xp/Wp
    float* sbuf = (float*)&Xp[0][0];       // [NCW][OTILE]
    float* qbuf = sbuf + NCW * OTILE;
#pragma unroll
    for (int m = 0; m < WM; ++m)
#pragma unroll
        for (int r = 0; r < 4; ++r) {
            float s = 0.f, q = 0.f;
#pragma unroll
            for (int n = 0; n < WN; ++n) {
                int col = nb + wc * (WN * 16) + n * 16 + co;
                float v = acc[m][n][r];
                if (col < NPTS) { s += v; q = fmaf(v, v, q); }
            }
            s += __shfl_xor(s, 1); q += __shfl_xor(q, 1);
            s += __shfl_xor(s, 2); q += __shfl_xor(q, 2);
            s += __shfl_xor(s, 4); q += __shfl_xor(q, 4);
            s += __shfl_xor(s, 8); q += __shfl_xor(q, 8);
            if (co == 0) {
                int rowl = wr * (WM * 16) + m * 16 + ro + r;   // 0..OTILE-1
                sbuf[wc * OTILE + rowl] = s;
                qbuf[wc * OTILE + rowl] = q;
            }
        }
    __syncthreads();
    if (tid < OTILE) {
        float s = 0.f, q = 0.f;
#pragma unroll
        for (int j = 0; j < NCW; ++j) {
            s += sbuf[j * OTILE + tid];
            q += qbuf[j * OTILE + tid];
        }
        atomicAdd(&stats[ob + tid], s);
        atomicAdd(&stats[COUT + ob + tid], q);
    }
}

// ---------------------------------------------------------------------------
// Per-channel sum / sumsq over (batch, points)  -> stats[c], stats[C+c]
// (layer-0 output only; later layers fuse stats into conv_mfma)
// ---------------------------------------------------------------------------
__global__ void chan_stats(const float* __restrict__ y, int C, float* __restrict__ stats) {
    int c = blockIdx.x, b = blockIdx.y, t = threadIdx.x;
    const float* p = y + ((size_t)(b * C + c)) * NPTS;
    float s = 0.f, q = 0.f;
    for (int n = t; n < NPTS; n += 256) {
        float v = p[n];
        s += v;
        q = fmaf(v, v, q);
    }
    for (int off = 32; off; off >>= 1) {
        s += __shfl_down(s, off);
        q += __shfl_down(q, off);
    }
    __shared__ float ls[4], lq[4];
    if ((t & 63) == 0) { ls[t >> 6] = s; lq[t >> 6] = q; }
    __syncthreads();
    if (t == 0) {
        atomicAdd(&stats[c],     ls[0] + ls[1] + ls[2] + ls[3]);
        atomicAdd(&stats[C + c], lq[0] + lq[1] + lq[2] + lq[3]);
    }
}

__global__ void bn_finalize(const float* __restrict__ stats, const float* __restrict__ g,
                            const float* __restrict__ bi, int C, float* __restrict__ ss) {
    int c = threadIdx.x;
    if (c < C) {
        float mu  = stats[c] * (1.f / NBN);
        float var = stats[C + c] * (1.f / NBN) - mu * mu;
        float r = rsqrtf(var + 1e-5f);
        float s = g[c] * r;
        ss[c] = s;
        ss[256 + c] = bi[c] - mu * s;
    }
}

// ---------------------------------------------------------------------------
// Split-fp16 MFMA second moment, software-pipelined (register prefetch + raw
// s_barrier without vmcnt drain).  covP[chunk][b][tile] 128x128 += F F^T.
// NPAN=1: tiles (0,0)/(1,1), fused fsum; NPAN=2: tile (0,1).
// ---------------------------------------------------------------------------
template <int NPAN>
__device__ __forceinline__ void cov_issue(const float* __restrict__ y4, int b,
                                          int ti, int tj, int chb, int p4,
                                          int n0c, int kk, float4 (&cur)[NPAN][4]) {
    const int nbase = n0c + kk * 32;
#pragma unroll
    for (int p = 0; p < NPAN; ++p) {
        const int pcb = (p ? tj : ti) * 128;
#pragma unroll
        for (int i = 0; i < 4; ++i) {
            const int ch = chb + 32 * i;
            float4 v = make_float4(0.f, 0.f, 0.f, 0.f);
            if (kk * 32 + p4 < CHUNK_PTS)
                v = *(const float4*)(y4 + ((size_t)(b * 256 + pcb + ch)) * NPTS + nbase + p4);
            cur[p][i] = v;
        }
    }
}

template <int NPAN>
__global__ __launch_bounds__(256) void cov_mfma(const float* __restrict__ y4,
                                                const float* __restrict__ ss,
                                                float* __restrict__ covP,
                                                float* __restrict__ fsumb) {
    __shared__ unsigned short pan[NPAN][2][4096];

    const int chunk = blockIdx.x;
    const int tile  = (NPAN == 2) ? 2 : (int)blockIdx.y;
    const int b     = blockIdx.z;
    const int ti = (tile == 1) ? 1 : 0;
    const int tj = (tile == 0) ? 0 : 1;

    const int tid  = threadIdx.x;
    const int lane = tid & 63;
    const int w    = tid >> 6;
    const int wr   = w & 1, wc = w >> 1;
    const int n0c  = chunk * CHUNK_PTS;

    f32x4 acc[4][4];
#pragma unroll
    for (int m = 0; m < 4; ++m)
#pragma unroll
        for (int n = 0; n < 4; ++n) acc[m][n] = (f32x4){0.f, 0.f, 0.f, 0.f};

    // staging assignment: 8 point-groups (4 pts) x 32 channel-bases
    const int g   = tid & 7;
    const int chb = tid >> 3;          // 0..31
    const int p4  = g * 4;             // point offset in 32-chunk
    const int q   = p4 >> 3, j0 = p4 & 7;

    float fs[4] = {0.f, 0.f, 0.f, 0.f};
    float4 cur[NPAN][4];

    cov_issue<NPAN>(y4, b, ti, tj, chb, p4, n0c, 0, cur);

#pragma unroll 1
    for (int kk = 0; kk < COV_KK; ++kk) {
        __builtin_amdgcn_sched_barrier(0);
        __builtin_amdgcn_s_barrier();          // LDS safe to overwrite
        __builtin_amdgcn_sched_barrier(0);

        const bool ok = (kk * 32 + p4 < CHUNK_PTS);
#pragma unroll
        for (int p = 0; p < NPAN; ++p) {
            const int pcb = (p ? tj : ti) * 128;
#pragma unroll
            for (int i = 0; i < 4; ++i) {
                const int ch = chb + 32 * i;
                float4 v = cur[p][i];
                if (ok) {
                    float sc = ss[pcb + ch], sh = ss[256 + pcb + ch];
                    v.x = fmaxf(fmaf(v.x, sc, sh), 0.f);
                    v.y = fmaxf(fmaf(v.y, sc, sh), 0.f);
                    v.z = fmaxf(fmaf(v.z, sc, sh), 0.f);
                    v.w = fmaxf(fmaf(v.w, sc, sh), 0.f);
                } else {
                    v = make_float4(0.f, 0.f, 0.f, 0.f);
                }
                if (NPAN == 1) fs[i] += (v.x + v.y) + (v.z + v.w);
                ushort4v h4, l4;
                h4[0] = f2h(v.x); l4[0] = f2h(hres(v.x));
                h4[1] = f2h(v.y); l4[1] = f2h(hres(v.y));
                h4[2] = f2h(v.z); l4[2] = f2h(hres(v.z));
                h4[3] = f2h(v.w); l4[3] = f2h(hres(v.w));
                const int addr = (ch >> 4) * 512 + (q * 16 + (ch & 15)) * 8 + j0;
                const int sa = swz8(addr * 2) >> 1;
                *(ushort4v*)&pan[p][0][sa] = h4;
                *(ushort4v*)&pan[p][1][sa] = l4;
            }
        }
        if (kk + 1 < COV_KK)
            cov_issue<NPAN>(y4, b, ti, tj, chb, p4, n0c, kk + 1, cur);  // prefetch

        asm volatile("s_waitcnt lgkmcnt(0)" ::: "memory");  // ds_writes visible
        __builtin_amdgcn_s_barrier();                       // NO vmcnt drain
        __builtin_amdgcn_sched_barrier(0);

        const unsigned short* Ah = pan[0][0];
        const unsigned short* Al = pan[0][1];
        const unsigned short* Bh = pan[NPAN - 1][0];
        const unsigned short* Bl = pan[NPAN - 1][1];

        f16x8 ah[4], al[4], bh[4], bl[4];
#pragma unroll
        for (int m = 0; m < 4; ++m) {
            int t8 = (wr * 4 + m) * 512 + lane * 8;
            int sa = swz8(t8 * 2) >> 1;
            ah[m] = *(const f16x8*)&Ah[sa];
            al[m] = *(const f16x8*)&Al[sa];
        }
#pragma unroll
        for (int n = 0; n < 4; ++n) {
            int t8 = (wc * 4 + n) * 512 + lane * 8;
            int sa = swz8(t8 * 2) >> 1;
            bh[n] = *(const f16x8*)&Bh[sa];
            bl[n] = *(const f16x8*)&Bl[sa];
        }
#pragma unroll
        for (int m = 0; m < 4; ++m)
#pragma unroll
            for (int n = 0; n < 4; ++n) {
                acc[m][n] = __builtin_amdgcn_mfma_f32_16x16x32_f16(ah[m], bh[n], acc[m][n], 0, 0, 0);
                acc[m][n] = __builtin_amdgcn_mfma_f32_16x16x32_f16(ah[m], bl[n], acc[m][n], 0, 0, 0);
                acc[m][n] = __builtin_amdgcn_mfma_f32_16x16x32_f16(al[m], bh[n], acc[m][n], 0, 0, 0);
            }
    }

    // fused per-channel relu-sum contribution (tiles 0/1 only)
    if (NPAN == 1) {
#pragma unroll
        for (int i = 0; i < 4; ++i) {
            float s = fs[i];
            s += __shfl_xor(s, 1);
            s += __shfl_xor(s, 2);
            s += __shfl_xor(s, 4);
            if (g == 0)
                atomicAdd(&fsumb[b * 256 + ti * 128 + chb + 32 * i], s);
        }
    }

    // epilogue: packed per-(chunk,b,tile) 128x128 partial buffer (no atomics)
    float* outp = covP + (((size_t)(chunk * NB + b) * 3 + tile) << 14);
    const int rowb = wr * 64;
    const int colb = wc * 64;
#pragma unroll
    for (int m = 0; m < 4; ++m)
#pragma unroll
        for (int n = 0; n < 4; ++n)
#pragma unroll
            for (int r = 0; r < 4; ++r) {
                int row = rowb + m * 16 + (lane >> 4) * 4 + r;
                int col = colb + n * 16 + (lane & 15);
                outp[(row << 7) + col] = acc[m][n][r];
            }
}

// ---------------------------------------------------------------------------
// cov = (sum_q covP[q])/N - m fbar^T - fbar m^T + m m^T ; mirror tile (1,0)
// covP layout: [chunk][b][tile 0:(0,0) 1:(1,1) 2:(0,1)][128][128]
// ---------------------------------------------------------------------------
__global__ void covfin_ker(const float* __restrict__ covP, const float* __restrict__ fsumb,
                           float* __restrict__ Y0, float* __restrict__ trace) {
    int r = blockIdx.x, b = blockIdx.y, c = threadIdx.x;
    float fbr = fsumb[b * 256 + r] * (1.f / NPTS);
    float fbc = fsumb[b * 256 + c] * (1.f / NPTS);
    float mr = 0.f, mc = 0.f;
    for (int q = 0; q < NB; ++q) {
        mr += fsumb[q * 256 + r];
        mc += fsumb[q * 256 + c];
    }
    mr *= (1.f / NBN);
    mc *= (1.f / NBN);
    int tile, rr, cc;
    if (r < 128 && c < 128)        { tile = 0; rr = r;       cc = c; }
    else if (r >= 128 && c >= 128) { tile = 1; rr = r - 128; cc = c - 128; }
    else if (r < 128)              { tile = 2; rr = r;       cc = c - 128; }   // (0,1)
    else                           { tile = 2; rr = c;       cc = r - 128; }   // (1,0) mirror
    size_t base = (((size_t)b * 3 + tile) << 14) + ((size_t)rr << 7) + cc;
    float m5 = 0.f;
#pragma unroll
    for (int q = 0; q < COV_CHUNKS; ++q)
        m5 += covP[(size_t)q * (NB * 3 * 16384) + base];
    float v = m5 * (1.f / NPTS) - fbr * mc - mr * fbc + mr * mc;
    Y0[((size_t)b << 16) + ((size_t)r << 8) + c] = v;
    if (c == r) atomicAdd(&trace[b], v);
}

__global__ void ns_init(float* __restrict__ Y0, float* __restrict__ Z0,
                        const float* __restrict__ trace) {
    int i = blockIdx.x * 256 + threadIdx.x;   // 16*65536 total
    int b = i >> 16, rc = i & 65535;
    float inv = 1.f / trace[b];
    Y0[i] *= inv;
    Z0[i] = ((rc >> 8) == (rc & 255)) ? 1.f : 0.f;
}

// ---------------------------------------------------------------------------
// Newton-Schulz batched 256x256 GEMM via split-fp16 MFMA (R3-proven body).
// O = diag*I + scale*(A.B); block computes 64x64 tile, K=256 in 8 steps.
// Staging layout (per panel, 64 f x 32 k): (f>>4)*512 + (kq*16+(f&15))*8 + j.
// kq == wave id -> staging writes are bank-conflict-free; frag reads linear.
// NOTE: stable coupled iteration — do NOT commute M.Z -> Z.M or read
// operands transposed-via-symmetry (Higham: commutativity-assuming NS
// variants are numerically unstable; R7 NaN'd exactly this way).
// ---------------------------------------------------------------------------
__device__ __forceinline__ void ns_body(const float* __restrict__ Ab,
                                        const float* __restrict__ Bb,
                                        float* __restrict__ Ob,
                                        float scale, float diag, int tile, int tid,
                                        unsigned short* Ap0, unsigned short* Ap1,
                                        unsigned short* Bp0, unsigned short* Bp1) {
    const int lane = tid & 63;
    const int w    = tid >> 6;
    const int wr   = w & 1, wc = w >> 1;
    const int tr = (tile >> 2) * 64, tc = (tile & 3) * 64;

    f32x4 acc[2][2];
#pragma unroll
    for (int m = 0; m < 2; ++m)
#pragma unroll
        for (int n = 0; n < 2; ++n) acc[m][n] = (f32x4){0.f, 0.f, 0.f, 0.f};

    const int fA = tid & 63;       // staged row (A) / col (B)
    const int kq = tid >> 6;       // k-subblock (== wave id)

#pragma unroll 1
    for (int kc = 0; kc < 256; kc += 32) {
        __syncthreads();
        const float* ap = Ab + (size_t)(tr + fA) * 256 + kc + kq * 8;
        float av[8];
        *(float4*)&av[0] = *(const float4*)ap;
        *(float4*)&av[4] = *(const float4*)(ap + 4);
        const float* bp = Bb + (size_t)(kc + kq * 8) * 256 + tc + fA;
        float bv[8];
#pragma unroll
        for (int j = 0; j < 8; ++j) bv[j] = bp[(size_t)j * 256];
        ushort8v ah8, al8, bh8, bl8;
#pragma unroll
        for (int j = 0; j < 8; ++j) {
            ah8[j] = f2h(av[j]); al8[j] = f2h(hres(av[j]));
            bh8[j] = f2h(bv[j]); bl8[j] = f2h(hres(bv[j]));
        }
        const int ua = (fA >> 4) * 512 + (kq * 16 + (fA & 15)) * 8;
        *(ushort8v*)&Ap0[ua] = ah8;
        *(ushort8v*)&Ap1[ua] = al8;
        *(ushort8v*)&Bp0[ua] = bh8;
        *(ushort8v*)&Bp1[ua] = bl8;
        __syncthreads();

        f16x8 a_h[2], a_l[2], b_h[2], b_l[2];
#pragma unroll
        for (int m = 0; m < 2; ++m) {
            int u = (wr * 2 + m) * 512 + lane * 8;
            a_h[m] = *(const f16x8*)&Ap0[u];
            a_l[m] = *(const f16x8*)&Ap1[u];
        }
#pragma unroll
        for (int n = 0; n < 2; ++n) {
            int u = (wc * 2 + n) * 512 + lane * 8;
            b_h[n] = *(const f16x8*)&Bp0[u];
            b_l[n] = *(const f16x8*)&Bp1[u];
        }
#pragma unroll
        for (int m = 0; m < 2; ++m)
#pragma unroll
            for (int n = 0; n < 2; ++n) {
                acc[m][n] = __builtin_amdgcn_mfma_f32_16x16x32_f16(a_h[m], b_h[n], acc[m][n], 0, 0, 0);
                acc[m][n] = __builtin_amdgcn_mfma_f32_16x16x32_f16(a_h[m], b_l[n], acc[m][n], 0, 0, 0);
                acc[m][n] = __builtin_amdgcn_mfma_f32_16x16x32_f16(a_l[m], b_h[n], acc[m][n], 0, 0, 0);
            }
    }

    const int ro = (lane >> 4) * 4, co = lane & 15;
#pragma unroll
    for (int m = 0; m < 2; ++m)
#pragma unroll
        for (int n = 0; n < 2; ++n) {
            int row = tr + wr * 32 + m * 16 + ro;
            int col = tc + wc * 32 + n * 16 + co;
#pragma unroll
            for (int r = 0; r < 4; ++r) {
                float v = scale * acc[m][n][r] + (((row + r) == col) ? diag : 0.f);
                Ob[(size_t)(row + r) * 256 + col] = v;
            }
        }
}

__global__ __launch_bounds__(256) void ns_gemm(const float* __restrict__ A,
                                               const float* __restrict__ B,
                                               float* __restrict__ O,
                                               float scale, float diag) {
    __shared__ unsigned short Ap[2][2048], Bp[2][2048];
    size_t off = (size_t)blockIdx.y << 16;
    ns_body(A + off, B + off, O + off, scale, diag, blockIdx.x, threadIdx.x,
            Ap[0], Ap[1], Bp[0], Bp[1]);
}

__global__ __launch_bounds__(256) void ns_gemm_pair(const float* __restrict__ Y,
                                                    const float* __restrict__ Mm,
                                                    const float* __restrict__ Z,
                                                    float* __restrict__ Yn,
                                                    float* __restrict__ Zn) {
    __shared__ unsigned short Ap[2][2048], Bp[2][2048];
    size_t off = (size_t)blockIdx.y << 16;
    if (blockIdx.z == 0)
        ns_body(Y + off, Mm + off, Yn + off, 0.5f, 0.f, blockIdx.x, threadIdx.x,
                Ap[0], Ap[1], Bp[0], Bp[1]);
    else
        ns_body(Mm + off, Z + off, Zn + off, 0.5f, 0.f, blockIdx.x, threadIdx.x,
                Ap[0], Ap[1], Bp[0], Bp[1]);
}

// ---------------------------------------------------------------------------
// FC: outpre[b,o] += sum_k sqrt(trace[b])*Yf[b,k] * Wfc[o,k]
// ---------------------------------------------------------------------------
__global__ __launch_bounds__(256) void fc_ker(const float* __restrict__ Yf,
                                              const float* __restrict__ trace,
                                              const float* __restrict__ Wfc,
                                              float* __restrict__ outpre) {
    int kc = blockIdx.x;
    int ot = blockIdx.y;
    int t = threadIdx.x;
    __shared__ float Wl[64][129];
    __shared__ float Vl[16][129];
#pragma unroll
    for (int i = 0; i < 32; ++i) {
        int l = i * 256 + t;
        int o = l >> 7, k = l & 127;
        Wl[o][k] = Wfc[(size_t)(ot * 64 + o) * 65536 + kc * 128 + k];
    }
#pragma unroll
    for (int i = 0; i < 8; ++i) {
        int l = i * 256 + t;
        int bb = l >> 7, k = l & 127;
        Vl[bb][k] = sqrtf(trace[bb]) * Yf[((size_t)bb << 16) + kc * 128 + k];
    }
    __syncthreads();
    int ol = t & 63, bg = t >> 6;
    float a0 = 0.f, a1 = 0.f, a2 = 0.f, a3 = 0.f;
    for (int k = 0; k < 128; ++k) {
        float w = Wl[ol][k];
        a0 = fmaf(w, Vl[bg * 4 + 0][k], a0);
        a1 = fmaf(w, Vl[bg * 4 + 1][k], a1);
        a2 = fmaf(w, Vl[bg * 4 + 2][k], a2);
        a3 = fmaf(w, Vl[bg * 4 + 3][k], a3);
    }
    int o = ot * 64 + ol;
    atomicAdd(&outpre[(bg * 4 + 0) * 256 + o], a0);
    atomicAdd(&outpre[(bg * 4 + 1) * 256 + o], a1);
    atomicAdd(&outpre[(bg * 4 + 2) * 256 + o], a2);
    atomicAdd(&outpre[(bg * 4 + 3) * 256 + o], a3);
}

__global__ void norm_ker(const float* __restrict__ outpre, const float* __restrict__ bfc,
                         float* __restrict__ dout) {
    int b = blockIdx.x, t = threadIdx.x;
    float v = outpre[b * 256 + t] + bfc[t];
    float q = v * v;
    for (int off = 32; off; off >>= 1) q += __shfl_xor(q, off);
    __shared__ float lq[4];
    __shared__ float snorm;
    if ((t & 63) == 0) lq[t >> 6] = q;
    __syncthreads();
    if (t == 0) snorm = fmaxf(sqrtf(lq[0] + lq[1] + lq[2] + lq[3]), 1e-12f);
    __syncthreads();
    dout[b * 256 + t] = v / snorm;
}

// ---------------------------------------------------------------------------
extern "C" void kernel_launch(void* const* d_in, const int* in_sizes, int n_in,
                              void* d_out, int out_size, void* d_ws, size_t ws_size,
                              hipStream_t stream) {
    (void)in_sizes; (void)n_in; (void)out_size; (void)ws_size;
    const float* pts = (const float*)d_in[0];
    const float* Wm[5]; const float* gm[5]; const float* bm[5];
    for (int i = 0; i < 5; ++i) {
        Wm[i] = (const float*)d_in[1 + 3 * i];
        gm[i] = (const float*)d_in[2 + 3 * i];
        bm[i] = (const float*)d_in[3 + 3 * i];
    }
    const float* Wfc = (const float*)d_in[16];
    const float* bfc = (const float*)d_in[17];

    float* ws     = (float*)d_ws;
    float* stats  = ws;                  // 2560
    float* fsumb  = ws + 2560;           // 4096
    float* trace  = ws + 6656;           // 16
    float* outpre = ws + 6672;           // 4096
    float* ss     = ws + 10768;          // 2560
    float* R      = ws + 16384;          // 256ch fp32: 40,960,000 floats (y4)
    float* P      = R;                   // 64ch view (L0/L2 out)
    float* Q      = R + (size_t)NB * 256 * NPTS;   // 128ch: 20,480,000 floats
    // cov partials alias the (then-dead) Q region:
    // 20 chunks * 16 b * 3 tiles * 16384 = 15,728,640 floats < 20.48M
    float* covP   = Q;
    // NS buffers alias the (then-dead) R region (R dead after cov_mfma):
    float* Y0     = R;
    float* Y1     = Y0 + 1048576;
    float* Z0     = Y1 + 1048576;
    float* Z1     = Z0 + 1048576;
    float* Mb     = Z1 + 1048576;        // 5.24M floats << 40.96M of R

    hipMemsetAsync(ws, 0, 16384 * sizeof(float), stream);

    // Layer 0 (3 -> 64)
    conv0_ker<<<dim3(NBN / 256), dim3(256), 0, stream>>>(pts, Wm[0], P);
    chan_stats<<<dim3(64, NB), dim3(256), 0, stream>>>(P, 64, stats);
    bn_finalize<<<dim3(1), dim3(256), 0, stream>>>(stats, gm[0], bm[0], 64, ss);
    // Layer 1 (64 -> 64), stats fused
    conv_mfma<64, 64, 64><<<dim3(79, 1, NB), dim3(256), 0, stream>>>(P, ss, Wm[1], Q, stats + 512);
    bn_finalize<<<dim3(1), dim3(256), 0, stream>>>(stats + 512, gm[1], bm[1], 64, ss + 512);
    // Layer 2 (64 -> 64)
    conv_mfma<64, 64, 64><<<dim3(79, 1, NB), dim3(256), 0, stream>>>(Q, ss + 512, Wm[2], P, stats + 1024);
    bn_finalize<<<dim3(1), dim3(256), 0, stream>>>(stats + 1024, gm[2], bm[2], 64, ss + 1024);
    // Layer 3 (64 -> 128)
    conv_mfma<64, 128, 128><<<dim3(79, 1, NB), dim3(256), 0, stream>>>(P, ss + 1024, Wm[3], Q, stats + 1536);
    bn_finalize<<<dim3(1), dim3(256), 0, stream>>>(stats + 1536, gm[3], bm[3], 128, ss + 1536);
    // Layer 4 (128 -> 256); writes R (P is dead now)
    conv_mfma<128, 256, 128><<<dim3(79, 2, NB), dim3(256), 0, stream>>>(Q, ss + 1536, Wm[4], R, stats + 2048);
    bn_finalize<<<dim3(1), dim3(256), 0, stream>>>(stats + 2048, gm[4], bm[4], 256, ss + 2048);

    // Covariance path (fsum fused into cov_mfma tiles 0/1; pipelined)
    cov_mfma<1><<<dim3(COV_CHUNKS, 2, NB), dim3(256), 0, stream>>>(R, ss + 2048, covP, fsumb);
    cov_mfma<2><<<dim3(COV_CHUNKS, 1, NB), dim3(256), 0, stream>>>(R, ss + 2048, covP, fsumb);
    covfin_ker<<<dim3(256, NB), dim3(256), 0, stream>>>(covP, fsumb, Y0, trace);
    ns_init<<<dim3(4096), dim3(256), 0, stream>>>(Y0, Z0, trace);

    // Newton–Schulz iterations (stable coupled form, R3-proven body)
    float* Yc = Y0; float* Zc = Z0; float* Yn = Y1; float* Zn = Z1;
    for (int it = 0; it < NS_ITERS; ++it) {
        ns_gemm<<<dim3(16, NB), dim3(256), 0, stream>>>(Zc, Yc, Mb, -1.f, 3.f);
        ns_gemm_pair<<<dim3(16, NB, 2), dim3(256), 0, stream>>>(Yc, Mb, Zc, Yn, Zn);
        float* ty = Yc; Yc = Yn; Yn = ty;
        float* tz = Zc; Zc = Zn; Zn = tz;
    }

    fc_ker<<<dim3(512, 4), dim3(256), 0, stream>>>(Yc, trace, Wfc, outpre);
    norm_ker<<<dim3(NB), dim3(256), 0, stream>>>(outpre, bfc, (float*)d_out);
}

// Round 9
// 949.349 us; speedup vs baseline: 2.3996x; 1.0684x over previous
//
#include <hip/hip_runtime.h>
#include <cmath>

constexpr int NB   = 16;      // batch
constexpr int NPTS = 10000;   // points per batch
constexpr int NBN  = NB * NPTS;   // 160000
constexpr int NS_ITERS = 18;
constexpr int COV_CHUNKS = 20;    // 500 points each
constexpr int CHUNK_PTS  = 500;
constexpr int COV_KK     = 16;    // 16*32 = 512 >= 500

typedef _Float16 f16x8 __attribute__((ext_vector_type(8)));
typedef float  f32x4  __attribute__((ext_vector_type(4)));
typedef unsigned short ushort4v __attribute__((ext_vector_type(4)));
typedef unsigned short ushort8v __attribute__((ext_vector_type(8)));

// ---------------------------------------------------------------------------
// Layer 0: 3 -> 64, no input BN
// ---------------------------------------------------------------------------
__global__ __launch_bounds__(256) void conv0_ker(const float* __restrict__ pts,
                                                 const float* __restrict__ W,
                                                 float* __restrict__ y) {
    int g = blockIdx.x * 256 + threadIdx.x;          // 0..159999
    int b = g / NPTS;
    int n = g - b * NPTS;
    float p0 = pts[3 * (size_t)g + 0];
    float p1 = pts[3 * (size_t)g + 1];
    float p2 = pts[3 * (size_t)g + 2];
    float* yp = y + ((size_t)b * 64) * NPTS + n;
    for (int o = 0; o < 64; ++o) {
        float v = W[3 * o] * p0 + W[3 * o + 1] * p1 + W[3 * o + 2] * p2;
        yp[(size_t)o * NPTS] = v;
    }
}

// ---------------------------------------------------------------------------
// split-fp16 helpers (hi = fp16(v), lo = fp16(v - hi)): 3-MFMA product keeps
// ~2^-22 relative accuracy, effectively fp32 for this pipeline.
// ---------------------------------------------------------------------------
__device__ __forceinline__ unsigned short f2h(float f) {
    return __builtin_bit_cast(unsigned short, (_Float16)f);
}
__device__ __forceinline__ float hres(float f) {
    return f - (float)(_Float16)f;
}
// LDS XOR-swizzles (involutions, applied on both write & read)
__device__ __forceinline__ int swzu(int us) {        // conv panels
    return us ^ (((us >> 7) & 3) << 4);
}
__device__ __forceinline__ int swz8(int byteoff) {   // cov/ns panels
    return byteoff ^ (((byteoff >> 8) & 3) << 5);
}

// ---------------------------------------------------------------------------
// MFMA conv layer: y[b, ob+o, n] = sum_c W[ob+o, c] * relu(bn(x[b, c, n]))
// Block tile: OTILE x 128 points; waves 2x2 (OTILE=128) or 1x4 (OTILE=64).
// Fused BN-stats epilogue; X-operand software pipeline (register prefetch +
// raw s_barrier without vmcnt drain — mirror of the verified cov pattern).
// ---------------------------------------------------------------------------
template <int CIN, int COUT, int OTILE>
__global__ __launch_bounds__(256) void conv_mfma(const float* __restrict__ xin,
                                                 const float* __restrict__ ss,
                                                 const float* __restrict__ W,
                                                 float* __restrict__ y,
                                                 float* __restrict__ stats) {
    constexpr int OT = OTILE / 16;
    constexpr int WM = 4;
    constexpr int WN = (OTILE == 128) ? 4 : 2;
    constexpr int NCW = (OTILE == 128) ? 2 : 4;   // distinct col-wave groups
    __shared__ unsigned short Xp[2][8 * 512];
    __shared__ unsigned short Wp[2][OT * 512];

    const int tid  = threadIdx.x;
    const int lane = tid & 63;
    const int w    = tid >> 6;
    const int wr   = (OTILE == 128) ? (w & 1) : 0;
    const int wc   = (OTILE == 128) ? (w >> 1) : w;

    const int nb = blockIdx.x * 128;
    const int ob = blockIdx.y * OTILE;
    const int b  = blockIdx.z;

    f32x4 acc[WM][WN];
#pragma unroll
    for (int m = 0; m < WM; ++m)
#pragma unroll
        for (int n = 0; n < WN; ++n) acc[m][n] = (f32x4){0.f, 0.f, 0.f, 0.f};

    const int xn = tid & 127;
    const int th = tid >> 7;
    const bool nok = (nb + xn) < NPTS;

    float xv[2][8];
    // issue X loads for kc = 0
    {
        const float* xb0 = xin + ((size_t)(b * CIN)) * NPTS + nb + xn;
#pragma unroll
        for (int qq = 0; qq < 2; ++qq) {
            int q = th * 2 + qq;
#pragma unroll
            for (int j = 0; j < 8; ++j)
                xv[qq][j] = nok ? xb0[(size_t)(q * 8 + j) * NPTS] : 0.f;
        }
    }

#pragma unroll 1
    for (int kc = 0; kc < CIN; kc += 32) {
        __builtin_amdgcn_sched_barrier(0);
        __builtin_amdgcn_s_barrier();          // LDS safe to overwrite
        __builtin_amdgcn_sched_barrier(0);
        // ---- stage W[ob..ob+OTILE)[kc..kc+32) as split-fp16 A panels ----
#pragma unroll
        for (int i = 0; i < OTILE / 32; ++i) {
            int l = i * 256 + tid;
            int o = l >> 3, k4 = (l & 7) << 2;
            float4 v = *(const float4*)(W + (size_t)(ob + o) * CIN + kc + k4);
            ushort4v h4, l4;
            h4[0] = f2h(v.x); l4[0] = f2h(hres(v.x));
            h4[1] = f2h(v.y); l4[1] = f2h(hres(v.y));
            h4[2] = f2h(v.z); l4[2] = f2h(hres(v.z));
            h4[3] = f2h(v.w); l4[3] = f2h(hres(v.w));
            int us = swzu((o >> 4) * 512 + ((k4 >> 3) * 16 + (o & 15)) * 8 + (k4 & 7));
            *(ushort4v*)&Wp[0][us] = h4;
            *(ushort4v*)&Wp[1][us] = l4;
        }
        // ---- stage relu(bn(x)) from prefetched registers ----
#pragma unroll
        for (int qq = 0; qq < 2; ++qq) {
            int q = th * 2 + qq;
            float f[8];
#pragma unroll
            for (int j = 0; j < 8; ++j) {
                int c = kc + q * 8 + j;
                f[j] = fmaxf(fmaf(xv[qq][j], ss[c], ss[256 + c]), 0.f);
            }
            ushort8v h8, l8;
#pragma unroll
            for (int j = 0; j < 8; ++j) {
                h8[j] = f2h(f[j]);
                l8[j] = f2h(hres(f[j]));
            }
            int us = swzu((xn >> 4) * 512 + (q * 16 + (xn & 15)) * 8);
            *(ushort8v*)&Xp[0][us] = h8;
            *(ushort8v*)&Xp[1][us] = l8;
        }
        // ---- prefetch next X k-slab (stays in flight across the barrier) ----
        if (kc + 32 < CIN) {
            const float* xb0 = xin + ((size_t)(b * CIN + kc + 32)) * NPTS + nb + xn;
#pragma unroll
            for (int qq = 0; qq < 2; ++qq) {
                int q = th * 2 + qq;
#pragma unroll
                for (int j = 0; j < 8; ++j)
                    xv[qq][j] = nok ? xb0[(size_t)(q * 8 + j) * NPTS] : 0.f;
            }
        }
        asm volatile("s_waitcnt lgkmcnt(0)" ::: "memory");  // ds_writes visible
        __builtin_amdgcn_s_barrier();                       // NO vmcnt drain
        __builtin_amdgcn_sched_barrier(0);

        f16x8 ah[WM], al[WM], bh[WN], bl[WN];
#pragma unroll
        for (int m = 0; m < WM; ++m) {
            int us = swzu((wr * WM + m) * 512 + lane * 8);
            ah[m] = *(const f16x8*)&Wp[0][us];
            al[m] = *(const f16x8*)&Wp[1][us];
        }
#pragma unroll
        for (int n = 0; n < WN; ++n) {
            int us = swzu((wc * WN + n) * 512 + lane * 8);
            bh[n] = *(const f16x8*)&Xp[0][us];
            bl[n] = *(const f16x8*)&Xp[1][us];
        }
#pragma unroll
        for (int m = 0; m < WM; ++m)
#pragma unroll
            for (int n = 0; n < WN; ++n) {
                acc[m][n] = __builtin_amdgcn_mfma_f32_16x16x32_f16(ah[m], bh[n], acc[m][n], 0, 0, 0);
                acc[m][n] = __builtin_amdgcn_mfma_f32_16x16x32_f16(ah[m], bl[n], acc[m][n], 0, 0, 0);
                acc[m][n] = __builtin_amdgcn_mfma_f32_16x16x32_f16(al[m], bh[n], acc[m][n], 0, 0, 0);
            }
    }

    // ---- epilogue: stores ----
    const int ro = (lane >> 4) * 4;
    const int co = lane & 15;
#pragma unroll
    for (int m = 0; m < WM; ++m) {
        int o = ob + wr * (WM * 16) + m * 16 + ro;
#pragma unroll
        for (int n = 0; n < WN; ++n) {
            int col = nb + wc * (WN * 16) + n * 16 + co;
            if (col < NPTS) {
                float* yp = y + ((size_t)(b * COUT + o)) * NPTS + col;
#pragma unroll
                for (int r = 0; r < 4; ++r)
                    yp[(size_t)r * NPTS] = acc[m][n][r];
            }
        }
    }

    // ---- fused BN-stats: per-channel sum / sumsq over valid columns ----
    __syncthreads();                       // all waves done reading Xp/Wp
    float* sbuf = (float*)&Xp[0][0];       // [NCW][OTILE]
    float* qbuf = sbuf + NCW * OTILE;
#pragma unroll
    for (int m = 0; m < WM; ++m)
#pragma unroll
        for (int r = 0; r < 4; ++r) {
            float s = 0.f, q = 0.f;
#pragma unroll
            for (int n = 0; n < WN; ++n) {
                int col = nb + wc * (WN * 16) + n * 16 + co;
                float v = acc[m][n][r];
                if (col < NPTS) { s += v; q = fmaf(v, v, q); }
            }
            s += __shfl_xor(s, 1); q += __shfl_xor(q, 1);
            s += __shfl_xor(s, 2); q += __shfl_xor(q, 2);
            s += __shfl_xor(s, 4); q += __shfl_xor(q, 4);
            s += __shfl_xor(s, 8); q += __shfl_xor(q, 8);
            if (co == 0) {
                int rowl = wr * (WM * 16) + m * 16 + ro + r;   // 0..OTILE-1
                sbuf[wc * OTILE + rowl] = s;
                qbuf[wc * OTILE + rowl] = q;
            }
        }
    __syncthreads();
    if (tid < OTILE) {
        float s = 0.f, q = 0.f;
#pragma unroll
        for (int j = 0; j < NCW; ++j) {
            s += sbuf[j * OTILE + tid];
            q += qbuf[j * OTILE + tid];
        }
        atomicAdd(&stats[ob + tid], s);
        atomicAdd(&stats[COUT + ob + tid], q);
    }
}

// ---------------------------------------------------------------------------
// Per-channel sum / sumsq over (batch, points)  -> stats[c], stats[C+c]
// (layer-0 output only; later layers fuse stats into conv_mfma)
// ---------------------------------------------------------------------------
__global__ void chan_stats(const float* __restrict__ y, int C, float* __restrict__ stats) {
    int c = blockIdx.x, b = blockIdx.y, t = threadIdx.x;
    const float* p = y + ((size_t)(b * C + c)) * NPTS;
    float s = 0.f, q = 0.f;
    for (int n = t; n < NPTS; n += 256) {
        float v = p[n];
        s += v;
        q = fmaf(v, v, q);
    }
    for (int off = 32; off; off >>= 1) {
        s += __shfl_down(s, off);
        q += __shfl_down(q, off);
    }
    __shared__ float ls[4], lq[4];
    if ((t & 63) == 0) { ls[t >> 6] = s; lq[t >> 6] = q; }
    __syncthreads();
    if (t == 0) {
        atomicAdd(&stats[c],     ls[0] + ls[1] + ls[2] + ls[3]);
        atomicAdd(&stats[C + c], lq[0] + lq[1] + lq[2] + lq[3]);
    }
}

__global__ void bn_finalize(const float* __restrict__ stats, const float* __restrict__ g,
                            const float* __restrict__ bi, int C, float* __restrict__ ss) {
    int c = threadIdx.x;
    if (c < C) {
        float mu  = stats[c] * (1.f / NBN);
        float var = stats[C + c] * (1.f / NBN) - mu * mu;
        float r = rsqrtf(var + 1e-5f);
        float s = g[c] * r;
        ss[c] = s;
        ss[256 + c] = bi[c] - mu * s;
    }
}

// ---------------------------------------------------------------------------
// Split-fp16 MFMA second moment, software-pipelined (register prefetch + raw
// s_barrier without vmcnt drain).  covP[chunk][b][tile] 128x128 += F F^T.
// NPAN=1: tiles (0,0)/(1,1), fused fsum; NPAN=2: tile (0,1).
// ---------------------------------------------------------------------------
template <int NPAN>
__device__ __forceinline__ void cov_issue(const float* __restrict__ y4, int b,
                                          int ti, int tj, int chb, int p4,
                                          int n0c, int kk, float4 (&cur)[NPAN][4]) {
    const int nbase = n0c + kk * 32;
#pragma unroll
    for (int p = 0; p < NPAN; ++p) {
        const int pcb = (p ? tj : ti) * 128;
#pragma unroll
        for (int i = 0; i < 4; ++i) {
            const int ch = chb + 32 * i;
            float4 v = make_float4(0.f, 0.f, 0.f, 0.f);
            if (kk * 32 + p4 < CHUNK_PTS)
                v = *(const float4*)(y4 + ((size_t)(b * 256 + pcb + ch)) * NPTS + nbase + p4);
            cur[p][i] = v;
        }
    }
}

template <int NPAN>
__global__ __launch_bounds__(256) void cov_mfma(const float* __restrict__ y4,
                                                const float* __restrict__ ss,
                                                float* __restrict__ covP,
                                                float* __restrict__ fsumb) {
    __shared__ unsigned short pan[NPAN][2][4096];

    const int chunk = blockIdx.x;
    const int tile  = (NPAN == 2) ? 2 : (int)blockIdx.y;
    const int b     = blockIdx.z;
    const int ti = (tile == 1) ? 1 : 0;
    const int tj = (tile == 0) ? 0 : 1;

    const int tid  = threadIdx.x;
    const int lane = tid & 63;
    const int w    = tid >> 6;
    const int wr   = w & 1, wc = w >> 1;
    const int n0c  = chunk * CHUNK_PTS;

    f32x4 acc[4][4];
#pragma unroll
    for (int m = 0; m < 4; ++m)
#pragma unroll
        for (int n = 0; n < 4; ++n) acc[m][n] = (f32x4){0.f, 0.f, 0.f, 0.f};

    // staging assignment: 8 point-groups (4 pts) x 32 channel-bases
    const int g   = tid & 7;
    const int chb = tid >> 3;          // 0..31
    const int p4  = g * 4;             // point offset in 32-chunk
    const int q   = p4 >> 3, j0 = p4 & 7;

    float fs[4] = {0.f, 0.f, 0.f, 0.f};
    float4 cur[NPAN][4];

    cov_issue<NPAN>(y4, b, ti, tj, chb, p4, n0c, 0, cur);

#pragma unroll 1
    for (int kk = 0; kk < COV_KK; ++kk) {
        __builtin_amdgcn_sched_barrier(0);
        __builtin_amdgcn_s_barrier();          // LDS safe to overwrite
        __builtin_amdgcn_sched_barrier(0);

        const bool ok = (kk * 32 + p4 < CHUNK_PTS);
#pragma unroll
        for (int p = 0; p < NPAN; ++p) {
            const int pcb = (p ? tj : ti) * 128;
#pragma unroll
            for (int i = 0; i < 4; ++i) {
                const int ch = chb + 32 * i;
                float4 v = cur[p][i];
                if (ok) {
                    float sc = ss[pcb + ch], sh = ss[256 + pcb + ch];
                    v.x = fmaxf(fmaf(v.x, sc, sh), 0.f);
                    v.y = fmaxf(fmaf(v.y, sc, sh), 0.f);
                    v.z = fmaxf(fmaf(v.z, sc, sh), 0.f);
                    v.w = fmaxf(fmaf(v.w, sc, sh), 0.f);
                } else {
                    v = make_float4(0.f, 0.f, 0.f, 0.f);
                }
                if (NPAN == 1) fs[i] += (v.x + v.y) + (v.z + v.w);
                ushort4v h4, l4;
                h4[0] = f2h(v.x); l4[0] = f2h(hres(v.x));
                h4[1] = f2h(v.y); l4[1] = f2h(hres(v.y));
                h4[2] = f2h(v.z); l4[2] = f2h(hres(v.z));
                h4[3] = f2h(v.w); l4[3] = f2h(hres(v.w));
                const int addr = (ch >> 4) * 512 + (q * 16 + (ch & 15)) * 8 + j0;
                const int sa = swz8(addr * 2) >> 1;
                *(ushort4v*)&pan[p][0][sa] = h4;
                *(ushort4v*)&pan[p][1][sa] = l4;
            }
        }
        if (kk + 1 < COV_KK)
            cov_issue<NPAN>(y4, b, ti, tj, chb, p4, n0c, kk + 1, cur);  // prefetch

        asm volatile("s_waitcnt lgkmcnt(0)" ::: "memory");  // ds_writes visible
        __builtin_amdgcn_s_barrier();                       // NO vmcnt drain
        __builtin_amdgcn_sched_barrier(0);

        const unsigned short* Ah = pan[0][0];
        const unsigned short* Al = pan[0][1];
        const unsigned short* Bh = pan[NPAN - 1][0];
        const unsigned short* Bl = pan[NPAN - 1][1];

        f16x8 ah[4], al[4], bh[4], bl[4];
#pragma unroll
        for (int m = 0; m < 4; ++m) {
            int t8 = (wr * 4 + m) * 512 + lane * 8;
            int sa = swz8(t8 * 2) >> 1;
            ah[m] = *(const f16x8*)&Ah[sa];
            al[m] = *(const f16x8*)&Al[sa];
        }
#pragma unroll
        for (int n = 0; n < 4; ++n) {
            int t8 = (wc * 4 + n) * 512 + lane * 8;
            int sa = swz8(t8 * 2) >> 1;
            bh[n] = *(const f16x8*)&Bh[sa];
            bl[n] = *(const f16x8*)&Bl[sa];
        }
#pragma unroll
        for (int m = 0; m < 4; ++m)
#pragma unroll
            for (int n = 0; n < 4; ++n) {
                acc[m][n] = __builtin_amdgcn_mfma_f32_16x16x32_f16(ah[m], bh[n], acc[m][n], 0, 0, 0);
                acc[m][n] = __builtin_amdgcn_mfma_f32_16x16x32_f16(ah[m], bl[n], acc[m][n], 0, 0, 0);
                acc[m][n] = __builtin_amdgcn_mfma_f32_16x16x32_f16(al[m], bh[n], acc[m][n], 0, 0, 0);
            }
    }

    // fused per-channel relu-sum contribution (tiles 0/1 only)
    if (NPAN == 1) {
#pragma unroll
        for (int i = 0; i < 4; ++i) {
            float s = fs[i];
            s += __shfl_xor(s, 1);
            s += __shfl_xor(s, 2);
            s += __shfl_xor(s, 4);
            if (g == 0)
                atomicAdd(&fsumb[b * 256 + ti * 128 + chb + 32 * i], s);
        }
    }

    // epilogue: packed per-(chunk,b,tile) 128x128 partial buffer (no atomics)
    float* outp = covP + (((size_t)(chunk * NB + b) * 3 + tile) << 14);
    const int rowb = wr * 64;
    const int colb = wc * 64;
#pragma unroll
    for (int m = 0; m < 4; ++m)
#pragma unroll
        for (int n = 0; n < 4; ++n)
#pragma unroll
            for (int r = 0; r < 4; ++r) {
                int row = rowb + m * 16 + (lane >> 4) * 4 + r;
                int col = colb + n * 16 + (lane & 15);
                outp[(row << 7) + col] = acc[m][n][r];
            }
}

// ---------------------------------------------------------------------------
// cov = (sum_q covP[q])/N - m fbar^T - fbar m^T + m m^T ; mirror tile (1,0)
// covP layout: [chunk][b][tile 0:(0,0) 1:(1,1) 2:(0,1)][128][128]
// ---------------------------------------------------------------------------
__global__ void covfin_ker(const float* __restrict__ covP, const float* __restrict__ fsumb,
                           float* __restrict__ Y0, float* __restrict__ trace) {
    int r = blockIdx.x, b = blockIdx.y, c = threadIdx.x;
    float fbr = fsumb[b * 256 + r] * (1.f / NPTS);
    float fbc = fsumb[b * 256 + c] * (1.f / NPTS);
    float mr = 0.f, mc = 0.f;
    for (int q = 0; q < NB; ++q) {
        mr += fsumb[q * 256 + r];
        mc += fsumb[q * 256 + c];
    }
    mr *= (1.f / NBN);
    mc *= (1.f / NBN);
    int tile, rr, cc;
    if (r < 128 && c < 128)        { tile = 0; rr = r;       cc = c; }
    else if (r >= 128 && c >= 128) { tile = 1; rr = r - 128; cc = c - 128; }
    else if (r < 128)              { tile = 2; rr = r;       cc = c - 128; }   // (0,1)
    else                           { tile = 2; rr = c;       cc = r - 128; }   // (1,0) mirror
    size_t base = (((size_t)b * 3 + tile) << 14) + ((size_t)rr << 7) + cc;
    float m5 = 0.f;
#pragma unroll
    for (int q = 0; q < COV_CHUNKS; ++q)
        m5 += covP[(size_t)q * (NB * 3 * 16384) + base];
    float v = m5 * (1.f / NPTS) - fbr * mc - mr * fbc + mr * mc;
    Y0[((size_t)b << 16) + ((size_t)r << 8) + c] = v;
    if (c == r) atomicAdd(&trace[b], v);
}

__global__ void ns_init(float* __restrict__ Y0, float* __restrict__ Z0,
                        const float* __restrict__ trace) {
    int i = blockIdx.x * 256 + threadIdx.x;   // 16*65536 total
    int b = i >> 16, rc = i & 65535;
    float inv = 1.f / trace[b];
    Y0[i] *= inv;
    Z0[i] = ((rc >> 8) == (rc & 255)) ? 1.f : 0.f;
}

// ---------------------------------------------------------------------------
// Newton-Schulz batched 256x256 GEMM via split-fp16 MFMA, 8-wave body.
// O = diag*I + scale*(A.B); block = 64x64 tile, 512 threads (8 waves:
// wave = 16 rows x 32 cols), K staged 64-wide -> 4 stages, 8 barriers.
// A staging: thread (r2=tid>>3, kq8=tid&7) loads A[tr+r2][kc+kq8*8..+8]
//   (8 lanes per row -> coalesced 256B row segments).
// B staging: thread (colB=tid&63, kB=tid>>6) loads B[kc+kB*8+j][tc+colB]
//   (64-col coalesced rows, 8 per thread).
// Panel layout (verified fragment family): tile = (f>>4)*2 + (koct>>2),
//   offset ((koct&3)*16 + (f&15))*8 + j ; swz8 on byte offsets.
// NOTE: stable coupled iteration — do NOT commute M.Z -> Z.M or read
// operands transposed-via-symmetry (Higham; R7 NaN'd exactly this way).
// ---------------------------------------------------------------------------
__device__ __forceinline__ void ns_body8(const float* __restrict__ Ab,
                                         const float* __restrict__ Bb,
                                         float* __restrict__ Ob,
                                         float scale, float diag, int tile, int tid,
                                         unsigned short* Ap0, unsigned short* Ap1,
                                         unsigned short* Bp0, unsigned short* Bp1) {
    const int lane = tid & 63;
    const int w    = tid >> 6;          // 0..7
    const int wr   = w & 3;             // 16-row frag group
    const int wc   = w >> 2;            // 32-col group
    const int tr = (tile >> 2) * 64, tc = (tile & 3) * 64;

    f32x4 acc[2];
    acc[0] = (f32x4){0.f, 0.f, 0.f, 0.f};
    acc[1] = (f32x4){0.f, 0.f, 0.f, 0.f};

    const int r2   = tid >> 3;          // A row 0..63
    const int kq8  = tid & 7;           // A k-octet 0..7
    const int colB = tid & 63;          // B col 0..63
    const int kB   = tid >> 6;          // B k-octet 0..7

#pragma unroll 1
    for (int kc = 0; kc < 256; kc += 64) {
        __syncthreads();
        // ---- stage A[tr..tr+64)[kc..kc+64) ----
        {
            const float* ap = Ab + (size_t)(tr + r2) * 256 + kc + kq8 * 8;
            float av[8];
            *(float4*)&av[0] = *(const float4*)ap;
            *(float4*)&av[4] = *(const float4*)(ap + 4);
            ushort8v h8, l8;
#pragma unroll
            for (int j = 0; j < 8; ++j) { h8[j] = f2h(av[j]); l8[j] = f2h(hres(av[j])); }
            const int ua = ((r2 >> 4) * 2 + (kq8 >> 2)) * 512 + ((kq8 & 3) * 16 + (r2 & 15)) * 8;
            const int sa = swz8(ua * 2) >> 1;
            *(ushort8v*)&Ap0[sa] = h8;
            *(ushort8v*)&Ap1[sa] = l8;
        }
        // ---- stage B[kc..kc+64)[tc..tc+64) ----
        {
            const float* bp = Bb + (size_t)(kc + kB * 8) * 256 + tc + colB;
            float bv[8];
#pragma unroll
            for (int j = 0; j < 8; ++j) bv[j] = bp[(size_t)j * 256];
            ushort8v h8, l8;
#pragma unroll
            for (int j = 0; j < 8; ++j) { h8[j] = f2h(bv[j]); l8[j] = f2h(hres(bv[j])); }
            const int ub = ((colB >> 4) * 2 + (kB >> 2)) * 512 + ((kB & 3) * 16 + (colB & 15)) * 8;
            const int sb = swz8(ub * 2) >> 1;
            *(ushort8v*)&Bp0[sb] = h8;
            *(ushort8v*)&Bp1[sb] = l8;
        }
        __syncthreads();

#pragma unroll
        for (int kk = 0; kk < 2; ++kk) {
            const int ua = swz8(((wr * 2 + kk) * 512 + lane * 8) * 2) >> 1;
            f16x8 a_h = *(const f16x8*)&Ap0[ua];
            f16x8 a_l = *(const f16x8*)&Ap1[ua];
#pragma unroll
            for (int n = 0; n < 2; ++n) {
                const int ub = swz8((((wc * 2 + n) * 2 + kk) * 512 + lane * 8) * 2) >> 1;
                f16x8 b_h = *(const f16x8*)&Bp0[ub];
                f16x8 b_l = *(const f16x8*)&Bp1[ub];
                acc[n] = __builtin_amdgcn_mfma_f32_16x16x32_f16(a_h, b_h, acc[n], 0, 0, 0);
                acc[n] = __builtin_amdgcn_mfma_f32_16x16x32_f16(a_h, b_l, acc[n], 0, 0, 0);
                acc[n] = __builtin_amdgcn_mfma_f32_16x16x32_f16(a_l, b_h, acc[n], 0, 0, 0);
            }
        }
    }

    const int ro = (lane >> 4) * 4, co = lane & 15;
#pragma unroll
    for (int n = 0; n < 2; ++n) {
        int row = tr + wr * 16 + ro;
        int col = tc + wc * 32 + n * 16 + co;
#pragma unroll
        for (int r = 0; r < 4; ++r) {
            float v = scale * acc[n][r] + (((row + r) == col) ? diag : 0.f);
            Ob[(size_t)(row + r) * 256 + col] = v;
        }
    }
}

__global__ __launch_bounds__(512) void ns_gemm(const float* __restrict__ A,
                                               const float* __restrict__ B,
                                               float* __restrict__ O,
                                               float scale, float diag) {
    __shared__ unsigned short Ap[2][4096], Bp[2][4096];
    size_t off = (size_t)blockIdx.y << 16;
    ns_body8(A + off, B + off, O + off, scale, diag, blockIdx.x, threadIdx.x,
             Ap[0], Ap[1], Bp[0], Bp[1]);
}

__global__ __launch_bounds__(512) void ns_gemm_pair(const float* __restrict__ Y,
                                                    const float* __restrict__ Mm,
                                                    const float* __restrict__ Z,
                                                    float* __restrict__ Yn,
                                                    float* __restrict__ Zn) {
    __shared__ unsigned short Ap[2][4096], Bp[2][4096];
    size_t off = (size_t)blockIdx.y << 16;
    if (blockIdx.z == 0)
        ns_body8(Y + off, Mm + off, Yn + off, 0.5f, 0.f, blockIdx.x, threadIdx.x,
                 Ap[0], Ap[1], Bp[0], Bp[1]);
    else
        ns_body8(Mm + off, Z + off, Zn + off, 0.5f, 0.f, blockIdx.x, threadIdx.x,
                 Ap[0], Ap[1], Bp[0], Bp[1]);
}

// ---------------------------------------------------------------------------
// FC: outpre[b,o] += sum_k sqrt(trace[b])*Yf[b,k] * Wfc[o,k]
// ---------------------------------------------------------------------------
__global__ __launch_bounds__(256) void fc_ker(const float* __restrict__ Yf,
                                              const float* __restrict__ trace,
                                              const float* __restrict__ Wfc,
                                              float* __restrict__ outpre) {
    int kc = blockIdx.x;
    int ot = blockIdx.y;
    int t = threadIdx.x;
    __shared__ float Wl[64][129];
    __shared__ float Vl[16][129];
#pragma unroll
    for (int i = 0; i < 32; ++i) {
        int l = i * 256 + t;
        int o = l >> 7, k = l & 127;
        Wl[o][k] = Wfc[(size_t)(ot * 64 + o) * 65536 + kc * 128 + k];
    }
#pragma unroll
    for (int i = 0; i < 8; ++i) {
        int l = i * 256 + t;
        int bb = l >> 7, k = l & 127;
        Vl[bb][k] = sqrtf(trace[bb]) * Yf[((size_t)bb << 16) + kc * 128 + k];
    }
    __syncthreads();
    int ol = t & 63, bg = t >> 6;
    float a0 = 0.f, a1 = 0.f, a2 = 0.f, a3 = 0.f;
    for (int k = 0; k < 128; ++k) {
        float w = Wl[ol][k];
        a0 = fmaf(w, Vl[bg * 4 + 0][k], a0);
        a1 = fmaf(w, Vl[bg * 4 + 1][k], a1);
        a2 = fmaf(w, Vl[bg * 4 + 2][k], a2);
        a3 = fmaf(w, Vl[bg * 4 + 3][k], a3);
    }
    int o = ot * 64 + ol;
    atomicAdd(&outpre[(bg * 4 + 0) * 256 + o], a0);
    atomicAdd(&outpre[(bg * 4 + 1) * 256 + o], a1);
    atomicAdd(&outpre[(bg * 4 + 2) * 256 + o], a2);
    atomicAdd(&outpre[(bg * 4 + 3) * 256 + o], a3);
}

__global__ void norm_ker(const float* __restrict__ outpre, const float* __restrict__ bfc,
                         float* __restrict__ dout) {
    int b = blockIdx.x, t = threadIdx.x;
    float v = outpre[b * 256 + t] + bfc[t];
    float q = v * v;
    for (int off = 32; off; off >>= 1) q += __shfl_xor(q, off);
    __shared__ float lq[4];
    __shared__ float snorm;
    if ((t & 63) == 0) lq[t >> 6] = q;
    __syncthreads();
    if (t == 0) snorm = fmaxf(sqrtf(lq[0] + lq[1] + lq[2] + lq[3]), 1e-12f);
    __syncthreads();
    dout[b * 256 + t] = v / snorm;
}

// ---------------------------------------------------------------------------
extern "C" void kernel_launch(void* const* d_in, const int* in_sizes, int n_in,
                              void* d_out, int out_size, void* d_ws, size_t ws_size,
                              hipStream_t stream) {
    (void)in_sizes; (void)n_in; (void)out_size; (void)ws_size;
    const float* pts = (const float*)d_in[0];
    const float* Wm[5]; const float* gm[5]; const float* bm[5];
    for (int i = 0; i < 5; ++i) {
        Wm[i] = (const float*)d_in[1 + 3 * i];
        gm[i] = (const float*)d_in[2 + 3 * i];
        bm[i] = (const float*)d_in[3 + 3 * i];
    }
    const float* Wfc = (const float*)d_in[16];
    const float* bfc = (const float*)d_in[17];

    float* ws     = (float*)d_ws;
    float* stats  = ws;                  // 2560
    float* fsumb  = ws + 2560;           // 4096
    float* trace  = ws + 6656;           // 16
    float* outpre = ws + 6672;           // 4096
    float* ss     = ws + 10768;          // 2560
    float* R      = ws + 16384;          // 256ch fp32: 40,960,000 floats (y4)
    float* P      = R;                   // 64ch view (L0/L2 out)
    float* Q      = R + (size_t)NB * 256 * NPTS;   // 128ch: 20,480,000 floats
    // cov partials alias the (then-dead) Q region:
    // 20 chunks * 16 b * 3 tiles * 16384 = 15,728,640 floats < 20.48M
    float* covP   = Q;
    // NS buffers alias the (then-dead) R region (R dead after cov_mfma):
    float* Y0     = R;
    float* Y1     = Y0 + 1048576;
    float* Z0     = Y1 + 1048576;
    float* Z1     = Z0 + 1048576;
    float* Mb     = Z1 + 1048576;        // 5.24M floats << 40.96M of R

    hipMemsetAsync(ws, 0, 16384 * sizeof(float), stream);

    // Layer 0 (3 -> 64)
    conv0_ker<<<dim3(NBN / 256), dim3(256), 0, stream>>>(pts, Wm[0], P);
    chan_stats<<<dim3(64, NB), dim3(256), 0, stream>>>(P, 64, stats);
    bn_finalize<<<dim3(1), dim3(256), 0, stream>>>(stats, gm[0], bm[0], 64, ss);
    // Layer 1 (64 -> 64), stats fused
    conv_mfma<64, 64, 64><<<dim3(79, 1, NB), dim3(256), 0, stream>>>(P, ss, Wm[1], Q, stats + 512);
    bn_finalize<<<dim3(1), dim3(256), 0, stream>>>(stats + 512, gm[1], bm[1], 64, ss + 512);
    // Layer 2 (64 -> 64)
    conv_mfma<64, 64, 64><<<dim3(79, 1, NB), dim3(256), 0, stream>>>(Q, ss + 512, Wm[2], P, stats + 1024);
    bn_finalize<<<dim3(1), dim3(256), 0, stream>>>(stats + 1024, gm[2], bm[2], 64, ss + 1024);
    // Layer 3 (64 -> 128)
    conv_mfma<64, 128, 128><<<dim3(79, 1, NB), dim3(256), 0, stream>>>(P, ss + 1024, Wm[3], Q, stats + 1536);
    bn_finalize<<<dim3(1), dim3(256), 0, stream>>>(stats + 1536, gm[3], bm[3], 128, ss + 1536);
    // Layer 4 (128 -> 256); writes R (P is dead now)
    conv_mfma<128, 256, 128><<<dim3(79, 2, NB), dim3(256), 0, stream>>>(Q, ss + 1536, Wm[4], R, stats + 2048);
    bn_finalize<<<dim3(1), dim3(256), 0, stream>>>(stats + 2048, gm[4], bm[4], 256, ss + 2048);

    // Covariance path (fsum fused into cov_mfma tiles 0/1; pipelined)
    cov_mfma<1><<<dim3(COV_CHUNKS, 2, NB), dim3(256), 0, stream>>>(R, ss + 2048, covP, fsumb);
    cov_mfma<2><<<dim3(COV_CHUNKS, 1, NB), dim3(256), 0, stream>>>(R, ss + 2048, covP, fsumb);
    covfin_ker<<<dim3(256, NB), dim3(256), 0, stream>>>(covP, fsumb, Y0, trace);
    ns_init<<<dim3(4096), dim3(256), 0, stream>>>(Y0, Z0, trace);

    // Newton–Schulz iterations (stable coupled form, 8-wave bodies)
    float* Yc = Y0; float* Zc = Z0; float* Yn = Y1; float* Zn = Z1;
    for (int it = 0; it < NS_ITERS; ++it) {
        ns_gemm<<<dim3(16, NB), dim3(512), 0, stream>>>(Zc, Yc, Mb, -1.f, 3.f);
        ns_gemm_pair<<<dim3(16, NB, 2), dim3(512), 0, stream>>>(Yc, Mb, Zc, Yn, Zn);
        float* ty = Yc; Yc = Yn; Yn = ty;
        float* tz = Zc; Zc = Zn; Zn = tz;
    }

    fc_ker<<<dim3(512, 4), dim3(256), 0, stream>>>(Yc, trace, Wfc, outpre);
    norm_ker<<<dim3(NB), dim3(256), 0, stream>>>(outpre, bfc, (float*)d_out);
}

// Round 10
// 844.931 us; speedup vs baseline: 2.6962x; 1.1236x over previous
//
#include <hip/hip_runtime.h>
#include <cmath>

constexpr int NB   = 16;      // batch
constexpr int NPTS = 10000;   // points per batch
constexpr int NBN  = NB * NPTS;   // 160000
constexpr int NS_ITERS = 18;
constexpr int COV_CHUNKS = 20;    // 500 points each
constexpr int CHUNK_PTS  = 500;
constexpr int COV_KK     = 16;    // 16*32 = 512 >= 500

typedef _Float16 f16x8 __attribute__((ext_vector_type(8)));
typedef float  f32x4  __attribute__((ext_vector_type(4)));
typedef unsigned short ushort4v __attribute__((ext_vector_type(4)));
typedef unsigned short ushort8v __attribute__((ext_vector_type(8)));

// ---------------------------------------------------------------------------
// Layer 0: 3 -> 64, no input BN
// ---------------------------------------------------------------------------
__global__ __launch_bounds__(256) void conv0_ker(const float* __restrict__ pts,
                                                 const float* __restrict__ W,
                                                 float* __restrict__ y) {
    int g = blockIdx.x * 256 + threadIdx.x;          // 0..159999
    int b = g / NPTS;
    int n = g - b * NPTS;
    float p0 = pts[3 * (size_t)g + 0];
    float p1 = pts[3 * (size_t)g + 1];
    float p2 = pts[3 * (size_t)g + 2];
    float* yp = y + ((size_t)b * 64) * NPTS + n;
    for (int o = 0; o < 64; ++o) {
        float v = W[3 * o] * p0 + W[3 * o + 1] * p1 + W[3 * o + 2] * p2;
        yp[(size_t)o * NPTS] = v;
    }
}

// ---------------------------------------------------------------------------
// split-fp16 helpers (hi = fp16(v), lo = fp16(v - hi)): 3-MFMA product keeps
// ~2^-22 relative accuracy, effectively fp32 for this pipeline.
// ---------------------------------------------------------------------------
__device__ __forceinline__ unsigned short f2h(float f) {
    return __builtin_bit_cast(unsigned short, (_Float16)f);
}
__device__ __forceinline__ float hres(float f) {
    return f - (float)(_Float16)f;
}
// LDS XOR-swizzles (involutions, applied on both write & read)
__device__ __forceinline__ int swzu(int us) {        // conv panels
    return us ^ (((us >> 7) & 3) << 4);
}
__device__ __forceinline__ int swz8(int byteoff) {   // cov/ns panels
    return byteoff ^ (((byteoff >> 8) & 3) << 5);
}

// ---------------------------------------------------------------------------
// MFMA conv layer: y[b, ob+o, n] = sum_c W[ob+o, c] * relu(bn(x[b, c, n]))
// Block tile: OTILE x 128 points; waves 2x2 (OTILE=128) or 1x4 (OTILE=64).
// Fused BN-stats epilogue.  (R9 lesson: do NOT hand-pipeline the X loads —
// explicit prefetch + sched_barrier pinning regressed 101 -> 114 us; the
// compiler schedules the strided scalar loads better itself.)
// ---------------------------------------------------------------------------
template <int CIN, int COUT, int OTILE>
__global__ __launch_bounds__(256) void conv_mfma(const float* __restrict__ xin,
                                                 const float* __restrict__ ss,
                                                 const float* __restrict__ W,
                                                 float* __restrict__ y,
                                                 float* __restrict__ stats) {
    constexpr int OT = OTILE / 16;
    constexpr int WM = 4;
    constexpr int WN = (OTILE == 128) ? 4 : 2;
    constexpr int NCW = (OTILE == 128) ? 2 : 4;   // distinct col-wave groups
    __shared__ unsigned short Xp[2][8 * 512];
    __shared__ unsigned short Wp[2][OT * 512];

    const int tid  = threadIdx.x;
    const int lane = tid & 63;
    const int w    = tid >> 6;
    const int wr   = (OTILE == 128) ? (w & 1) : 0;
    const int wc   = (OTILE == 128) ? (w >> 1) : w;

    const int nb = blockIdx.x * 128;
    const int ob = blockIdx.y * OTILE;
    const int b  = blockIdx.z;

    f32x4 acc[WM][WN];
#pragma unroll
    for (int m = 0; m < WM; ++m)
#pragma unroll
        for (int n = 0; n < WN; ++n) acc[m][n] = (f32x4){0.f, 0.f, 0.f, 0.f};

    const int xn = tid & 127;
    const int th = tid >> 7;
    const bool nok = (nb + xn) < NPTS;

#pragma unroll 1
    for (int kc = 0; kc < CIN; kc += 32) {
        __syncthreads();
        // ---- stage W[ob..ob+OTILE)[kc..kc+32) as split-fp16 A panels ----
#pragma unroll
        for (int i = 0; i < OTILE / 32; ++i) {
            int l = i * 256 + tid;
            int o = l >> 3, k4 = (l & 7) << 2;
            float4 v = *(const float4*)(W + (size_t)(ob + o) * CIN + kc + k4);
            ushort4v h4, l4;
            h4[0] = f2h(v.x); l4[0] = f2h(hres(v.x));
            h4[1] = f2h(v.y); l4[1] = f2h(hres(v.y));
            h4[2] = f2h(v.z); l4[2] = f2h(hres(v.z));
            h4[3] = f2h(v.w); l4[3] = f2h(hres(v.w));
            int us = swzu((o >> 4) * 512 + ((k4 >> 3) * 16 + (o & 15)) * 8 + (k4 & 7));
            *(ushort4v*)&Wp[0][us] = h4;
            *(ushort4v*)&Wp[1][us] = l4;
        }
        // ---- stage relu(bn(x))[kc..kc+32)[nb..nb+128) as split-fp16 B panels ----
#pragma unroll
        for (int qq = 0; qq < 2; ++qq) {
            int q = th * 2 + qq;
            const float* xb = xin + ((size_t)(b * CIN + kc + q * 8)) * NPTS + nb + xn;
            float f[8];
#pragma unroll
            for (int j = 0; j < 8; ++j) {
                float v = nok ? xb[(size_t)j * NPTS] : 0.f;
                int c = kc + q * 8 + j;
                f[j] = fmaxf(fmaf(v, ss[c], ss[256 + c]), 0.f);
            }
            ushort8v h8, l8;
#pragma unroll
            for (int j = 0; j < 8; ++j) {
                h8[j] = f2h(f[j]);
                l8[j] = f2h(hres(f[j]));
            }
            int us = swzu((xn >> 4) * 512 + (q * 16 + (xn & 15)) * 8);
            *(ushort8v*)&Xp[0][us] = h8;
            *(ushort8v*)&Xp[1][us] = l8;
        }
        __syncthreads();

        f16x8 ah[WM], al[WM], bh[WN], bl[WN];
#pragma unroll
        for (int m = 0; m < WM; ++m) {
            int us = swzu((wr * WM + m) * 512 + lane * 8);
            ah[m] = *(const f16x8*)&Wp[0][us];
            al[m] = *(const f16x8*)&Wp[1][us];
        }
#pragma unroll
        for (int n = 0; n < WN; ++n) {
            int us = swzu((wc * WN + n) * 512 + lane * 8);
            bh[n] = *(const f16x8*)&Xp[0][us];
            bl[n] = *(const f16x8*)&Xp[1][us];
        }
#pragma unroll
        for (int m = 0; m < WM; ++m)
#pragma unroll
            for (int n = 0; n < WN; ++n) {
                acc[m][n] = __builtin_amdgcn_mfma_f32_16x16x32_f16(ah[m], bh[n], acc[m][n], 0, 0, 0);
                acc[m][n] = __builtin_amdgcn_mfma_f32_16x16x32_f16(ah[m], bl[n], acc[m][n], 0, 0, 0);
                acc[m][n] = __builtin_amdgcn_mfma_f32_16x16x32_f16(al[m], bh[n], acc[m][n], 0, 0, 0);
            }
    }

    // ---- epilogue: stores ----
    const int ro = (lane >> 4) * 4;
    const int co = lane & 15;
#pragma unroll
    for (int m = 0; m < WM; ++m) {
        int o = ob + wr * (WM * 16) + m * 16 + ro;
#pragma unroll
        for (int n = 0; n < WN; ++n) {
            int col = nb + wc * (WN * 16) + n * 16 + co;
            if (col < NPTS) {
                float* yp = y + ((size_t)(b * COUT + o)) * NPTS + col;
#pragma unroll
                for (int r = 0; r < 4; ++r)
                    yp[(size_t)r * NPTS] = acc[m][n][r];
            }
        }
    }

    // ---- fused BN-stats: per-channel sum / sumsq over valid columns ----
    __syncthreads();                       // all waves done reading Xp/Wp
    float* sbuf = (float*)&Xp[0][0];       // [NCW][OTILE]
    float* qbuf = sbuf + NCW * OTILE;
#pragma unroll
    for (int m = 0; m < WM; ++m)
#pragma unroll
        for (int r = 0; r < 4; ++r) {
            float s = 0.f, q = 0.f;
#pragma unroll
            for (int n = 0; n < WN; ++n) {
                int col = nb + wc * (WN * 16) + n * 16 + co;
                float v = acc[m][n][r];
                if (col < NPTS) { s += v; q = fmaf(v, v, q); }
            }
            s += __shfl_xor(s, 1); q += __shfl_xor(q, 1);
            s += __shfl_xor(s, 2); q += __shfl_xor(q, 2);
            s += __shfl_xor(s, 4); q += __shfl_xor(q, 4);
            s += __shfl_xor(s, 8); q += __shfl_xor(q, 8);
            if (co == 0) {
                int rowl = wr * (WM * 16) + m * 16 + ro + r;   // 0..OTILE-1
                sbuf[wc * OTILE + rowl] = s;
                qbuf[wc * OTILE + rowl] = q;
            }
        }
    __syncthreads();
    if (tid < OTILE) {
        float s = 0.f, q = 0.f;
#pragma unroll
        for (int j = 0; j < NCW; ++j) {
            s += sbuf[j * OTILE + tid];
            q += qbuf[j * OTILE + tid];
        }
        atomicAdd(&stats[ob + tid], s);
        atomicAdd(&stats[COUT + ob + tid], q);
    }
}

// ---------------------------------------------------------------------------
// Per-channel sum / sumsq over (batch, points)  -> stats[c], stats[C+c]
// (layer-0 output only; later layers fuse stats into conv_mfma)
// ---------------------------------------------------------------------------
__global__ void chan_stats(const float* __restrict__ y, int C, float* __restrict__ stats) {
    int c = blockIdx.x, b = blockIdx.y, t = threadIdx.x;
    const float* p = y + ((size_t)(b * C + c)) * NPTS;
    float s = 0.f, q = 0.f;
    for (int n = t; n < NPTS; n += 256) {
        float v = p[n];
        s += v;
        q = fmaf(v, v, q);
    }
    for (int off = 32; off; off >>= 1) {
        s += __shfl_down(s, off);
        q += __shfl_down(q, off);
    }
    __shared__ float ls[4], lq[4];
    if ((t & 63) == 0) { ls[t >> 6] = s; lq[t >> 6] = q; }
    __syncthreads();
    if (t == 0) {
        atomicAdd(&stats[c],     ls[0] + ls[1] + ls[2] + ls[3]);
        atomicAdd(&stats[C + c], lq[0] + lq[1] + lq[2] + lq[3]);
    }
}

__global__ void bn_finalize(const float* __restrict__ stats, const float* __restrict__ g,
                            const float* __restrict__ bi, int C, float* __restrict__ ss) {
    int c = threadIdx.x;
    if (c < C) {
        float mu  = stats[c] * (1.f / NBN);
        float var = stats[C + c] * (1.f / NBN) - mu * mu;
        float r = rsqrtf(var + 1e-5f);
        float s = g[c] * r;
        ss[c] = s;
        ss[256 + c] = bi[c] - mu * s;
    }
}

// ---------------------------------------------------------------------------
// Split-fp16 MFMA second moment, software-pipelined (register prefetch + raw
// s_barrier without vmcnt drain).  covP[chunk][b][tile] 128x128 += F F^T.
// NPAN=1: tiles (0,0)/(1,1), fused fsum; NPAN=2: tile (0,1).
// ---------------------------------------------------------------------------
template <int NPAN>
__device__ __forceinline__ void cov_issue(const float* __restrict__ y4, int b,
                                          int ti, int tj, int chb, int p4,
                                          int n0c, int kk, float4 (&cur)[NPAN][4]) {
    const int nbase = n0c + kk * 32;
#pragma unroll
    for (int p = 0; p < NPAN; ++p) {
        const int pcb = (p ? tj : ti) * 128;
#pragma unroll
        for (int i = 0; i < 4; ++i) {
            const int ch = chb + 32 * i;
            float4 v = make_float4(0.f, 0.f, 0.f, 0.f);
            if (kk * 32 + p4 < CHUNK_PTS)
                v = *(const float4*)(y4 + ((size_t)(b * 256 + pcb + ch)) * NPTS + nbase + p4);
            cur[p][i] = v;
        }
    }
}

template <int NPAN>
__global__ __launch_bounds__(256) void cov_mfma(const float* __restrict__ y4,
                                                const float* __restrict__ ss,
                                                float* __restrict__ covP,
                                                float* __restrict__ fsumb) {
    __shared__ unsigned short pan[NPAN][2][4096];

    const int chunk = blockIdx.x;
    const int tile  = (NPAN == 2) ? 2 : (int)blockIdx.y;
    const int b     = blockIdx.z;
    const int ti = (tile == 1) ? 1 : 0;
    const int tj = (tile == 0) ? 0 : 1;

    const int tid  = threadIdx.x;
    const int lane = tid & 63;
    const int w    = tid >> 6;
    const int wr   = w & 1, wc = w >> 1;
    const int n0c  = chunk * CHUNK_PTS;

    f32x4 acc[4][4];
#pragma unroll
    for (int m = 0; m < 4; ++m)
#pragma unroll
        for (int n = 0; n < 4; ++n) acc[m][n] = (f32x4){0.f, 0.f, 0.f, 0.f};

    // staging assignment: 8 point-groups (4 pts) x 32 channel-bases
    const int g   = tid & 7;
    const int chb = tid >> 3;          // 0..31
    const int p4  = g * 4;             // point offset in 32-chunk
    const int q   = p4 >> 3, j0 = p4 & 7;

    float fs[4] = {0.f, 0.f, 0.f, 0.f};
    float4 cur[NPAN][4];

    cov_issue<NPAN>(y4, b, ti, tj, chb, p4, n0c, 0, cur);

#pragma unroll 1
    for (int kk = 0; kk < COV_KK; ++kk) {
        __builtin_amdgcn_sched_barrier(0);
        __builtin_amdgcn_s_barrier();          // LDS safe to overwrite
        __builtin_amdgcn_sched_barrier(0);

        const bool ok = (kk * 32 + p4 < CHUNK_PTS);
#pragma unroll
        for (int p = 0; p < NPAN; ++p) {
            const int pcb = (p ? tj : ti) * 128;
#pragma unroll
            for (int i = 0; i < 4; ++i) {
                const int ch = chb + 32 * i;
                float4 v = cur[p][i];
                if (ok) {
                    float sc = ss[pcb + ch], sh = ss[256 + pcb + ch];
                    v.x = fmaxf(fmaf(v.x, sc, sh), 0.f);
                    v.y = fmaxf(fmaf(v.y, sc, sh), 0.f);
                    v.z = fmaxf(fmaf(v.z, sc, sh), 0.f);
                    v.w = fmaxf(fmaf(v.w, sc, sh), 0.f);
                } else {
                    v = make_float4(0.f, 0.f, 0.f, 0.f);
                }
                if (NPAN == 1) fs[i] += (v.x + v.y) + (v.z + v.w);
                ushort4v h4, l4;
                h4[0] = f2h(v.x); l4[0] = f2h(hres(v.x));
                h4[1] = f2h(v.y); l4[1] = f2h(hres(v.y));
                h4[2] = f2h(v.z); l4[2] = f2h(hres(v.z));
                h4[3] = f2h(v.w); l4[3] = f2h(hres(v.w));
                const int addr = (ch >> 4) * 512 + (q * 16 + (ch & 15)) * 8 + j0;
                const int sa = swz8(addr * 2) >> 1;
                *(ushort4v*)&pan[p][0][sa] = h4;
                *(ushort4v*)&pan[p][1][sa] = l4;
            }
        }
        if (kk + 1 < COV_KK)
            cov_issue<NPAN>(y4, b, ti, tj, chb, p4, n0c, kk + 1, cur);  // prefetch

        asm volatile("s_waitcnt lgkmcnt(0)" ::: "memory");  // ds_writes visible
        __builtin_amdgcn_s_barrier();                       // NO vmcnt drain
        __builtin_amdgcn_sched_barrier(0);

        const unsigned short* Ah = pan[0][0];
        const unsigned short* Al = pan[0][1];
        const unsigned short* Bh = pan[NPAN - 1][0];
        const unsigned short* Bl = pan[NPAN - 1][1];

        f16x8 ah[4], al[4], bh[4], bl[4];
#pragma unroll
        for (int m = 0; m < 4; ++m) {
            int t8 = (wr * 4 + m) * 512 + lane * 8;
            int sa = swz8(t8 * 2) >> 1;
            ah[m] = *(const f16x8*)&Ah[sa];
            al[m] = *(const f16x8*)&Al[sa];
        }
#pragma unroll
        for (int n = 0; n < 4; ++n) {
            int t8 = (wc * 4 + n) * 512 + lane * 8;
            int sa = swz8(t8 * 2) >> 1;
            bh[n] = *(const f16x8*)&Bh[sa];
            bl[n] = *(const f16x8*)&Bl[sa];
        }
#pragma unroll
        for (int m = 0; m < 4; ++m)
#pragma unroll
            for (int n = 0; n < 4; ++n) {
                acc[m][n] = __builtin_amdgcn_mfma_f32_16x16x32_f16(ah[m], bh[n], acc[m][n], 0, 0, 0);
                acc[m][n] = __builtin_amdgcn_mfma_f32_16x16x32_f16(ah[m], bl[n], acc[m][n], 0, 0, 0);
                acc[m][n] = __builtin_amdgcn_mfma_f32_16x16x32_f16(al[m], bh[n], acc[m][n], 0, 0, 0);
            }
    }

    // fused per-channel relu-sum contribution (tiles 0/1 only)
    if (NPAN == 1) {
#pragma unroll
        for (int i = 0; i < 4; ++i) {
            float s = fs[i];
            s += __shfl_xor(s, 1);
            s += __shfl_xor(s, 2);
            s += __shfl_xor(s, 4);
            if (g == 0)
                atomicAdd(&fsumb[b * 256 + ti * 128 + chb + 32 * i], s);
        }
    }

    // epilogue: packed per-(chunk,b,tile) 128x128 partial buffer (no atomics)
    float* outp = covP + (((size_t)(chunk * NB + b) * 3 + tile) << 14);
    const int rowb = wr * 64;
    const int colb = wc * 64;
#pragma unroll
    for (int m = 0; m < 4; ++m)
#pragma unroll
        for (int n = 0; n < 4; ++n)
#pragma unroll
            for (int r = 0; r < 4; ++r) {
                int row = rowb + m * 16 + (lane >> 4) * 4 + r;
                int col = colb + n * 16 + (lane & 15);
                outp[(row << 7) + col] = acc[m][n][r];
            }
}

// ---------------------------------------------------------------------------
// cov = (sum_q covP[q])/N - m fbar^T - fbar m^T + m m^T ; mirror tile (1,0)
// covP layout: [chunk][b][tile 0:(0,0) 1:(1,1) 2:(0,1)][128][128]
// ---------------------------------------------------------------------------
__global__ void covfin_ker(const float* __restrict__ covP, const float* __restrict__ fsumb,
                           float* __restrict__ Y0, float* __restrict__ trace) {
    int r = blockIdx.x, b = blockIdx.y, c = threadIdx.x;
    float fbr = fsumb[b * 256 + r] * (1.f / NPTS);
    float fbc = fsumb[b * 256 + c] * (1.f / NPTS);
    float mr = 0.f, mc = 0.f;
    for (int q = 0; q < NB; ++q) {
        mr += fsumb[q * 256 + r];
        mc += fsumb[q * 256 + c];
    }
    mr *= (1.f / NBN);
    mc *= (1.f / NBN);
    int tile, rr, cc;
    if (r < 128 && c < 128)        { tile = 0; rr = r;       cc = c; }
    else if (r >= 128 && c >= 128) { tile = 1; rr = r - 128; cc = c - 128; }
    else if (r < 128)              { tile = 2; rr = r;       cc = c - 128; }   // (0,1)
    else                           { tile = 2; rr = c;       cc = r - 128; }   // (1,0) mirror
    size_t base = (((size_t)b * 3 + tile) << 14) + ((size_t)rr << 7) + cc;
    float m5 = 0.f;
#pragma unroll
    for (int q = 0; q < COV_CHUNKS; ++q)
        m5 += covP[(size_t)q * (NB * 3 * 16384) + base];
    float v = m5 * (1.f / NPTS) - fbr * mc - mr * fbc + mr * mc;
    Y0[((size_t)b << 16) + ((size_t)r << 8) + c] = v;
    if (c == r) atomicAdd(&trace[b], v);
}

__global__ void ns_init(float* __restrict__ Y0, float* __restrict__ Z0,
                        const float* __restrict__ trace) {
    int i = blockIdx.x * 256 + threadIdx.x;   // 16*65536 total
    int b = i >> 16, rc = i & 65535;
    float inv = 1.f / trace[b];
    Y0[i] *= inv;
    Z0[i] = ((rc >> 8) == (rc & 255)) ? 1.f : 0.f;
}

// ---------------------------------------------------------------------------
// Newton-Schulz batched 256x256 GEMM via split-fp16 MFMA, 8-wave body.
// O = diag*I + scale*(A.B); block = 64x64 tile, 512 threads (8 waves:
// wave = 16 rows x 32 cols), K staged 64-wide -> 4 stages, 8 barriers.
// XCD-aware block swizzle: batches {2x, 2x+1} pinned to XCD x (id & 7)
// consistently across ALL NS dispatches, so Y/Z/M stay resident in that
// XCD's 4 MB L2 (per-batch working set 1.25 MB, 2 batches = 2.5 MB).
// NOTE: stable coupled iteration — do NOT commute M.Z -> Z.M or read
// operands transposed-via-symmetry (Higham; R7 NaN'd exactly this way).
// ---------------------------------------------------------------------------
__device__ __forceinline__ void ns_body8(const float* __restrict__ Ab,
                                         const float* __restrict__ Bb,
                                         float* __restrict__ Ob,
                                         float scale, float diag, int tile, int tid,
                                         unsigned short* Ap0, unsigned short* Ap1,
                                         unsigned short* Bp0, unsigned short* Bp1) {
    const int lane = tid & 63;
    const int w    = tid >> 6;          // 0..7
    const int wr   = w & 3;             // 16-row frag group
    const int wc   = w >> 2;            // 32-col group
    const int tr = (tile >> 2) * 64, tc = (tile & 3) * 64;

    f32x4 acc[2];
    acc[0] = (f32x4){0.f, 0.f, 0.f, 0.f};
    acc[1] = (f32x4){0.f, 0.f, 0.f, 0.f};

    const int r2   = tid >> 3;          // A row 0..63
    const int kq8  = tid & 7;           // A k-octet 0..7
    const int colB = tid & 63;          // B col 0..63
    const int kB   = tid >> 6;          // B k-octet 0..7

#pragma unroll 1
    for (int kc = 0; kc < 256; kc += 64) {
        __syncthreads();
        // ---- stage A[tr..tr+64)[kc..kc+64) ----
        {
            const float* ap = Ab + (size_t)(tr + r2) * 256 + kc + kq8 * 8;
            float av[8];
            *(float4*)&av[0] = *(const float4*)ap;
            *(float4*)&av[4] = *(const float4*)(ap + 4);
            ushort8v h8, l8;
#pragma unroll
            for (int j = 0; j < 8; ++j) { h8[j] = f2h(av[j]); l8[j] = f2h(hres(av[j])); }
            const int ua = ((r2 >> 4) * 2 + (kq8 >> 2)) * 512 + ((kq8 & 3) * 16 + (r2 & 15)) * 8;
            const int sa = swz8(ua * 2) >> 1;
            *(ushort8v*)&Ap0[sa] = h8;
            *(ushort8v*)&Ap1[sa] = l8;
        }
        // ---- stage B[kc..kc+64)[tc..tc+64) ----
        {
            const float* bp = Bb + (size_t)(kc + kB * 8) * 256 + tc + colB;
            float bv[8];
#pragma unroll
            for (int j = 0; j < 8; ++j) bv[j] = bp[(size_t)j * 256];
            ushort8v h8, l8;
#pragma unroll
            for (int j = 0; j < 8; ++j) { h8[j] = f2h(bv[j]); l8[j] = f2h(hres(bv[j])); }
            const int ub = ((colB >> 4) * 2 + (kB >> 2)) * 512 + ((kB & 3) * 16 + (colB & 15)) * 8;
            const int sb = swz8(ub * 2) >> 1;
            *(ushort8v*)&Bp0[sb] = h8;
            *(ushort8v*)&Bp1[sb] = l8;
        }
        __syncthreads();

#pragma unroll
        for (int kk = 0; kk < 2; ++kk) {
            const int ua = swz8(((wr * 2 + kk) * 512 + lane * 8) * 2) >> 1;
            f16x8 a_h = *(const f16x8*)&Ap0[ua];
            f16x8 a_l = *(const f16x8*)&Ap1[ua];
#pragma unroll
            for (int n = 0; n < 2; ++n) {
                const int ub = swz8((((wc * 2 + n) * 2 + kk) * 512 + lane * 8) * 2) >> 1;
                f16x8 b_h = *(const f16x8*)&Bp0[ub];
                f16x8 b_l = *(const f16x8*)&Bp1[ub];
                acc[n] = __builtin_amdgcn_mfma_f32_16x16x32_f16(a_h, b_h, acc[n], 0, 0, 0);
                acc[n] = __builtin_amdgcn_mfma_f32_16x16x32_f16(a_h, b_l, acc[n], 0, 0, 0);
                acc[n] = __builtin_amdgcn_mfma_f32_16x16x32_f16(a_l, b_h, acc[n], 0, 0, 0);
            }
        }
    }

    const int ro = (lane >> 4) * 4, co = lane & 15;
#pragma unroll
    for (int n = 0; n < 2; ++n) {
        int row = tr + wr * 16 + ro;
        int col = tc + wc * 32 + n * 16 + co;
#pragma unroll
        for (int r = 0; r < 4; ++r) {
            float v = scale * acc[n][r] + (((row + r) == col) ? diag : 0.f);
            Ob[(size_t)(row + r) * 256 + col] = v;
        }
    }
}

// grid: 256 blocks 1D.  xcd = id&7; k = id>>3 (0..31);
// b = 2*xcd + (k>>4); tile = k&15  -> each batch's 16 tiles on one XCD.
__global__ __launch_bounds__(512) void ns_gemm(const float* __restrict__ A,
                                               const float* __restrict__ B,
                                               float* __restrict__ O,
                                               float scale, float diag) {
    __shared__ unsigned short Ap[2][4096], Bp[2][4096];
    const int id  = blockIdx.x;
    const int xcd = id & 7;
    const int k   = id >> 3;
    const int b   = 2 * xcd + (k >> 4);
    const int tile = k & 15;
    size_t off = (size_t)b << 16;
    ns_body8(A + off, B + off, O + off, scale, diag, tile, threadIdx.x,
             Ap[0], Ap[1], Bp[0], Bp[1]);
}

// grid: 512 blocks 1D.  xcd = id&7; k = id>>3 (0..63); z = k>>5;
// rem = k&31; b = 2*xcd + (rem>>4); tile = rem&15.
__global__ __launch_bounds__(512) void ns_gemm_pair(const float* __restrict__ Y,
                                                    const float* __restrict__ Mm,
                                                    const float* __restrict__ Z,
                                                    float* __restrict__ Yn,
                                                    float* __restrict__ Zn) {
    __shared__ unsigned short Ap[2][4096], Bp[2][4096];
    const int id  = blockIdx.x;
    const int xcd = id & 7;
    const int k   = id >> 3;
    const int z   = k >> 5;
    const int rem = k & 31;
    const int b   = 2 * xcd + (rem >> 4);
    const int tile = rem & 15;
    size_t off = (size_t)b << 16;
    if (z == 0)
        ns_body8(Y + off, Mm + off, Yn + off, 0.5f, 0.f, tile, threadIdx.x,
                 Ap[0], Ap[1], Bp[0], Bp[1]);
    else
        ns_body8(Mm + off, Z + off, Zn + off, 0.5f, 0.f, tile, threadIdx.x,
                 Ap[0], Ap[1], Bp[0], Bp[1]);
}

// ---------------------------------------------------------------------------
// FC: outpre[b,o] += sum_k sqrt(trace[b])*Yf[b,k] * Wfc[o,k]
// ---------------------------------------------------------------------------
__global__ __launch_bounds__(256) void fc_ker(const float* __restrict__ Yf,
                                              const float* __restrict__ trace,
                                              const float* __restrict__ Wfc,
                                              float* __restrict__ outpre) {
    int kc = blockIdx.x;
    int ot = blockIdx.y;
    int t = threadIdx.x;
    __shared__ float Wl[64][129];
    __shared__ float Vl[16][129];
#pragma unroll
    for (int i = 0; i < 32; ++i) {
        int l = i * 256 + t;
        int o = l >> 7, k = l & 127;
        Wl[o][k] = Wfc[(size_t)(ot * 64 + o) * 65536 + kc * 128 + k];
    }
#pragma unroll
    for (int i = 0; i < 8; ++i) {
        int l = i * 256 + t;
        int bb = l >> 7, k = l & 127;
        Vl[bb][k] = sqrtf(trace[bb]) * Yf[((size_t)bb << 16) + kc * 128 + k];
    }
    __syncthreads();
    int ol = t & 63, bg = t >> 6;
    float a0 = 0.f, a1 = 0.f, a2 = 0.f, a3 = 0.f;
    for (int k = 0; k < 128; ++k) {
        float w = Wl[ol][k];
        a0 = fmaf(w, Vl[bg * 4 + 0][k], a0);
        a1 = fmaf(w, Vl[bg * 4 + 1][k], a1);
        a2 = fmaf(w, Vl[bg * 4 + 2][k], a2);
        a3 = fmaf(w, Vl[bg * 4 + 3][k], a3);
    }
    int o = ot * 64 + ol;
    atomicAdd(&outpre[(bg * 4 + 0) * 256 + o], a0);
    atomicAdd(&outpre[(bg * 4 + 1) * 256 + o], a1);
    atomicAdd(&outpre[(bg * 4 + 2) * 256 + o], a2);
    atomicAdd(&outpre[(bg * 4 + 3) * 256 + o], a3);
}

__global__ void norm_ker(const float* __restrict__ outpre, const float* __restrict__ bfc,
                         float* __restrict__ dout) {
    int b = blockIdx.x, t = threadIdx.x;
    float v = outpre[b * 256 + t] + bfc[t];
    float q = v * v;
    for (int off = 32; off; off >>= 1) q += __shfl_xor(q, off);
    __shared__ float lq[4];
    __shared__ float snorm;
    if ((t & 63) == 0) lq[t >> 6] = q;
    __syncthreads();
    if (t == 0) snorm = fmaxf(sqrtf(lq[0] + lq[1] + lq[2] + lq[3]), 1e-12f);
    __syncthreads();
    dout[b * 256 + t] = v / snorm;
}

// ---------------------------------------------------------------------------
extern "C" void kernel_launch(void* const* d_in, const int* in_sizes, int n_in,
                              void* d_out, int out_size, void* d_ws, size_t ws_size,
                              hipStream_t stream) {
    (void)in_sizes; (void)n_in; (void)out_size; (void)ws_size;
    const float* pts = (const float*)d_in[0];
    const float* Wm[5]; const float* gm[5]; const float* bm[5];
    for (int i = 0; i < 5; ++i) {
        Wm[i] = (const float*)d_in[1 + 3 * i];
        gm[i] = (const float*)d_in[2 + 3 * i];
        bm[i] = (const float*)d_in[3 + 3 * i];
    }
    const float* Wfc = (const float*)d_in[16];
    const float* bfc = (const float*)d_in[17];

    float* ws     = (float*)d_ws;
    float* stats  = ws;                  // 2560
    float* fsumb  = ws + 2560;           // 4096
    float* trace  = ws + 6656;           // 16
    float* outpre = ws + 6672;           // 4096
    float* ss     = ws + 10768;          // 2560
    float* R      = ws + 16384;          // 256ch fp32: 40,960,000 floats (y4)
    float* P      = R;                   // 64ch view (L0/L2 out)
    float* Q      = R + (size_t)NB * 256 * NPTS;   // 128ch: 20,480,000 floats
    // cov partials alias the (then-dead) Q region:
    // 20 chunks * 16 b * 3 tiles * 16384 = 15,728,640 floats < 20.48M
    float* covP   = Q;
    // NS buffers alias the (then-dead) R region (R dead after cov_mfma):
    float* Y0     = R;
    float* Y1     = Y0 + 1048576;
    float* Z0     = Y1 + 1048576;
    float* Z1     = Z0 + 1048576;
    float* Mb     = Z1 + 1048576;        // 5.24M floats << 40.96M of R

    hipMemsetAsync(ws, 0, 16384 * sizeof(float), stream);

    // Layer 0 (3 -> 64)
    conv0_ker<<<dim3(NBN / 256), dim3(256), 0, stream>>>(pts, Wm[0], P);
    chan_stats<<<dim3(64, NB), dim3(256), 0, stream>>>(P, 64, stats);
    bn_finalize<<<dim3(1), dim3(256), 0, stream>>>(stats, gm[0], bm[0], 64, ss);
    // Layer 1 (64 -> 64), stats fused
    conv_mfma<64, 64, 64><<<dim3(79, 1, NB), dim3(256), 0, stream>>>(P, ss, Wm[1], Q, stats + 512);
    bn_finalize<<<dim3(1), dim3(256), 0, stream>>>(stats + 512, gm[1], bm[1], 64, ss + 512);
    // Layer 2 (64 -> 64)
    conv_mfma<64, 64, 64><<<dim3(79, 1, NB), dim3(256), 0, stream>>>(Q, ss + 512, Wm[2], P, stats + 1024);
    bn_finalize<<<dim3(1), dim3(256), 0, stream>>>(stats + 1024, gm[2], bm[2], 64, ss + 1024);
    // Layer 3 (64 -> 128)
    conv_mfma<64, 128, 128><<<dim3(79, 1, NB), dim3(256), 0, stream>>>(P, ss + 1024, Wm[3], Q, stats + 1536);
    bn_finalize<<<dim3(1), dim3(256), 0, stream>>>(stats + 1536, gm[3], bm[3], 128, ss + 1536);
    // Layer 4 (128 -> 256); writes R (P is dead now)
    conv_mfma<128, 256, 128><<<dim3(79, 2, NB), dim3(256), 0, stream>>>(Q, ss + 1536, Wm[4], R, stats + 2048);
    bn_finalize<<<dim3(1), dim3(256), 0, stream>>>(stats + 2048, gm[4], bm[4], 256, ss + 2048);

    // Covariance path (fsum fused into cov_mfma tiles 0/1; pipelined)
    cov_mfma<1><<<dim3(COV_CHUNKS, 2, NB), dim3(256), 0, stream>>>(R, ss + 2048, covP, fsumb);
    cov_mfma<2><<<dim3(COV_CHUNKS, 1, NB), dim3(256), 0, stream>>>(R, ss + 2048, covP, fsumb);
    covfin_ker<<<dim3(256, NB), dim3(256), 0, stream>>>(covP, fsumb, Y0, trace);
    ns_init<<<dim3(4096), dim3(256), 0, stream>>>(Y0, Z0, trace);

    // Newton–Schulz iterations (stable coupled form, 8-wave bodies,
    // XCD-pinned batches for L2 residency)
    float* Yc = Y0; float* Zc = Z0; float* Yn = Y1; float* Zn = Z1;
    for (int it = 0; it < NS_ITERS; ++it) {
        ns_gemm<<<dim3(256), dim3(512), 0, stream>>>(Zc, Yc, Mb, -1.f, 3.f);
        ns_gemm_pair<<<dim3(512), dim3(512), 0, stream>>>(Yc, Mb, Zc, Yn, Zn);
        float* ty = Yc; Yc = Yn; Yn = ty;
        float* tz = Zc; Zc = Zn; Zn = tz;
    }

    fc_ker<<<dim3(512, 4), dim3(256), 0, stream>>>(Yc, trace, Wfc, outpre);
    norm_ker<<<dim3(NB), dim3(256), 0, stream>>>(outpre, bfc, (float*)d_out);
}

// Round 11
// 843.707 us; speedup vs baseline: 2.7001x; 1.0015x over previous
//
#include <hip/hip_runtime.h>
#include <cmath>

constexpr int NB   = 16;      // batch
constexpr int NPTS = 10000;   // points per batch
constexpr int NBN  = NB * NPTS;   // 160000
constexpr int NS_ITERS = 18;
constexpr int COV_CHUNKS = 20;    // 500 points each
constexpr int CHUNK_PTS  = 500;
constexpr int COV_KK     = 16;    // 16*32 = 512 >= 500

typedef _Float16 f16x8 __attribute__((ext_vector_type(8)));
typedef float  f32x4  __attribute__((ext_vector_type(4)));
typedef unsigned short ushort4v __attribute__((ext_vector_type(4)));
typedef unsigned short ushort8v __attribute__((ext_vector_type(8)));

// ---------------------------------------------------------------------------
// Layer 0: 3 -> 64, no input BN
// ---------------------------------------------------------------------------
__global__ __launch_bounds__(256) void conv0_ker(const float* __restrict__ pts,
                                                 const float* __restrict__ W,
                                                 float* __restrict__ y) {
    int g = blockIdx.x * 256 + threadIdx.x;          // 0..159999
    int b = g / NPTS;
    int n = g - b * NPTS;
    float p0 = pts[3 * (size_t)g + 0];
    float p1 = pts[3 * (size_t)g + 1];
    float p2 = pts[3 * (size_t)g + 2];
    float* yp = y + ((size_t)b * 64) * NPTS + n;
    for (int o = 0; o < 64; ++o) {
        float v = W[3 * o] * p0 + W[3 * o + 1] * p1 + W[3 * o + 2] * p2;
        yp[(size_t)o * NPTS] = v;
    }
}

// ---------------------------------------------------------------------------
// split-fp16 helpers (hi = fp16(v), lo = fp16(v - hi)): 3-MFMA product keeps
// ~2^-22 relative accuracy, effectively fp32 for this pipeline.
// ---------------------------------------------------------------------------
__device__ __forceinline__ unsigned short f2h(float f) {
    return __builtin_bit_cast(unsigned short, (_Float16)f);
}
__device__ __forceinline__ float hres(float f) {
    return f - (float)(_Float16)f;
}
// LDS XOR-swizzles (involutions, applied on both write & read)
__device__ __forceinline__ int swzu(int us) {        // conv panels
    return us ^ (((us >> 7) & 3) << 4);
}
__device__ __forceinline__ int swz8(int byteoff) {   // cov/ns panels
    return byteoff ^ (((byteoff >> 8) & 3) << 5);
}

// ---------------------------------------------------------------------------
// MFMA conv layer: y[b, ob+o, n] = sum_c W[ob+o, c] * relu(bn(x[b, c, n]))
// Block tile: OTILE x 128 points; waves 2x2 (OTILE=128) or 1x4 (OTILE=64).
// Fused BN-stats epilogue.  (R9 lesson: do NOT hand-pipeline the X loads.)
// ---------------------------------------------------------------------------
template <int CIN, int COUT, int OTILE>
__global__ __launch_bounds__(256) void conv_mfma(const float* __restrict__ xin,
                                                 const float* __restrict__ ss,
                                                 const float* __restrict__ W,
                                                 float* __restrict__ y,
                                                 float* __restrict__ stats) {
    constexpr int OT = OTILE / 16;
    constexpr int WM = 4;
    constexpr int WN = (OTILE == 128) ? 4 : 2;
    constexpr int NCW = (OTILE == 128) ? 2 : 4;   // distinct col-wave groups
    __shared__ unsigned short Xp[2][8 * 512];
    __shared__ unsigned short Wp[2][OT * 512];

    const int tid  = threadIdx.x;
    const int lane = tid & 63;
    const int w    = tid >> 6;
    const int wr   = (OTILE == 128) ? (w & 1) : 0;
    const int wc   = (OTILE == 128) ? (w >> 1) : w;

    const int nb = blockIdx.x * 128;
    const int ob = blockIdx.y * OTILE;
    const int b  = blockIdx.z;

    f32x4 acc[WM][WN];
#pragma unroll
    for (int m = 0; m < WM; ++m)
#pragma unroll
        for (int n = 0; n < WN; ++n) acc[m][n] = (f32x4){0.f, 0.f, 0.f, 0.f};

    const int xn = tid & 127;
    const int th = tid >> 7;
    const bool nok = (nb + xn) < NPTS;

#pragma unroll 1
    for (int kc = 0; kc < CIN; kc += 32) {
        __syncthreads();
        // ---- stage W[ob..ob+OTILE)[kc..kc+32) as split-fp16 A panels ----
#pragma unroll
        for (int i = 0; i < OTILE / 32; ++i) {
            int l = i * 256 + tid;
            int o = l >> 3, k4 = (l & 7) << 2;
            float4 v = *(const float4*)(W + (size_t)(ob + o) * CIN + kc + k4);
            ushort4v h4, l4;
            h4[0] = f2h(v.x); l4[0] = f2h(hres(v.x));
            h4[1] = f2h(v.y); l4[1] = f2h(hres(v.y));
            h4[2] = f2h(v.z); l4[2] = f2h(hres(v.z));
            h4[3] = f2h(v.w); l4[3] = f2h(hres(v.w));
            int us = swzu((o >> 4) * 512 + ((k4 >> 3) * 16 + (o & 15)) * 8 + (k4 & 7));
            *(ushort4v*)&Wp[0][us] = h4;
            *(ushort4v*)&Wp[1][us] = l4;
        }
        // ---- stage relu(bn(x))[kc..kc+32)[nb..nb+128) as split-fp16 B panels ----
#pragma unroll
        for (int qq = 0; qq < 2; ++qq) {
            int q = th * 2 + qq;
            const float* xb = xin + ((size_t)(b * CIN + kc + q * 8)) * NPTS + nb + xn;
            float f[8];
#pragma unroll
            for (int j = 0; j < 8; ++j) {
                float v = nok ? xb[(size_t)j * NPTS] : 0.f;
                int c = kc + q * 8 + j;
                f[j] = fmaxf(fmaf(v, ss[c], ss[256 + c]), 0.f);
            }
            ushort8v h8, l8;
#pragma unroll
            for (int j = 0; j < 8; ++j) {
                h8[j] = f2h(f[j]);
                l8[j] = f2h(hres(f[j]));
            }
            int us = swzu((xn >> 4) * 512 + (q * 16 + (xn & 15)) * 8);
            *(ushort8v*)&Xp[0][us] = h8;
            *(ushort8v*)&Xp[1][us] = l8;
        }
        __syncthreads();

        f16x8 ah[WM], al[WM], bh[WN], bl[WN];
#pragma unroll
        for (int m = 0; m < WM; ++m) {
            int us = swzu((wr * WM + m) * 512 + lane * 8);
            ah[m] = *(const f16x8*)&Wp[0][us];
            al[m] = *(const f16x8*)&Wp[1][us];
        }
#pragma unroll
        for (int n = 0; n < WN; ++n) {
            int us = swzu((wc * WN + n) * 512 + lane * 8);
            bh[n] = *(const f16x8*)&Xp[0][us];
            bl[n] = *(const f16x8*)&Xp[1][us];
        }
#pragma unroll
        for (int m = 0; m < WM; ++m)
#pragma unroll
            for (int n = 0; n < WN; ++n) {
                acc[m][n] = __builtin_amdgcn_mfma_f32_16x16x32_f16(ah[m], bh[n], acc[m][n], 0, 0, 0);
                acc[m][n] = __builtin_amdgcn_mfma_f32_16x16x32_f16(ah[m], bl[n], acc[m][n], 0, 0, 0);
                acc[m][n] = __builtin_amdgcn_mfma_f32_16x16x32_f16(al[m], bh[n], acc[m][n], 0, 0, 0);
            }
    }

    // ---- epilogue: stores ----
    const int ro = (lane >> 4) * 4;
    const int co = lane & 15;
#pragma unroll
    for (int m = 0; m < WM; ++m) {
        int o = ob + wr * (WM * 16) + m * 16 + ro;
#pragma unroll
        for (int n = 0; n < WN; ++n) {
            int col = nb + wc * (WN * 16) + n * 16 + co;
            if (col < NPTS) {
                float* yp = y + ((size_t)(b * COUT + o)) * NPTS + col;
#pragma unroll
                for (int r = 0; r < 4; ++r)
                    yp[(size_t)r * NPTS] = acc[m][n][r];
            }
        }
    }

    // ---- fused BN-stats: per-channel sum / sumsq over valid columns ----
    __syncthreads();                       // all waves done reading Xp/Wp
    float* sbuf = (float*)&Xp[0][0];       // [NCW][OTILE]
    float* qbuf = sbuf + NCW * OTILE;
#pragma unroll
    for (int m = 0; m < WM; ++m)
#pragma unroll
        for (int r = 0; r < 4; ++r) {
            float s = 0.f, q = 0.f;
#pragma unroll
            for (int n = 0; n < WN; ++n) {
                int col = nb + wc * (WN * 16) + n * 16 + co;
                float v = acc[m][n][r];
                if (col < NPTS) { s += v; q = fmaf(v, v, q); }
            }
            s += __shfl_xor(s, 1); q += __shfl_xor(q, 1);
            s += __shfl_xor(s, 2); q += __shfl_xor(q, 2);
            s += __shfl_xor(s, 4); q += __shfl_xor(q, 4);
            s += __shfl_xor(s, 8); q += __shfl_xor(q, 8);
            if (co == 0) {
                int rowl = wr * (WM * 16) + m * 16 + ro + r;   // 0..OTILE-1
                sbuf[wc * OTILE + rowl] = s;
                qbuf[wc * OTILE + rowl] = q;
            }
        }
    __syncthreads();
    if (tid < OTILE) {
        float s = 0.f, q = 0.f;
#pragma unroll
        for (int j = 0; j < NCW; ++j) {
            s += sbuf[j * OTILE + tid];
            q += qbuf[j * OTILE + tid];
        }
        atomicAdd(&stats[ob + tid], s);
        atomicAdd(&stats[COUT + ob + tid], q);
    }
}

// ---------------------------------------------------------------------------
// Per-channel sum / sumsq over (batch, points)  -> stats[c], stats[C+c]
// (layer-0 output only; later layers fuse stats into conv_mfma)
// ---------------------------------------------------------------------------
__global__ void chan_stats(const float* __restrict__ y, int C, float* __restrict__ stats) {
    int c = blockIdx.x, b = blockIdx.y, t = threadIdx.x;
    const float* p = y + ((size_t)(b * C + c)) * NPTS;
    float s = 0.f, q = 0.f;
    for (int n = t; n < NPTS; n += 256) {
        float v = p[n];
        s += v;
        q = fmaf(v, v, q);
    }
    for (int off = 32; off; off >>= 1) {
        s += __shfl_down(s, off);
        q += __shfl_down(q, off);
    }
    __shared__ float ls[4], lq[4];
    if ((t & 63) == 0) { ls[t >> 6] = s; lq[t >> 6] = q; }
    __syncthreads();
    if (t == 0) {
        atomicAdd(&stats[c],     ls[0] + ls[1] + ls[2] + ls[3]);
        atomicAdd(&stats[C + c], lq[0] + lq[1] + lq[2] + lq[3]);
    }
}

__global__ void bn_finalize(const float* __restrict__ stats, const float* __restrict__ g,
                            const float* __restrict__ bi, int C, float* __restrict__ ss) {
    int c = threadIdx.x;
    if (c < C) {
        float mu  = stats[c] * (1.f / NBN);
        float var = stats[C + c] * (1.f / NBN) - mu * mu;
        float r = rsqrtf(var + 1e-5f);
        float s = g[c] * r;
        ss[c] = s;
        ss[256 + c] = bi[c] - mu * s;
    }
}

// ---------------------------------------------------------------------------
// Split-fp16 MFMA second moment, software-pipelined (register prefetch + raw
// s_barrier without vmcnt drain).  covP[chunk][b][tile] 128x128 += F F^T.
// NPAN=1: tiles (0,0)/(1,1), fused fsum; NPAN=2: tile (0,1).
// Single merged dispatch (960 blocks 1D): the 3 tiles of each (chunk,b)
// trio get consecutive ids with equal id&7 -> same XCD (round-robin
// heuristic, perf-only) so tile (0,1)'s reads prime L2 for tiles 0/1.
// ---------------------------------------------------------------------------
template <int NPAN>
__device__ __forceinline__ void cov_issue(const float* __restrict__ y4, int b,
                                          int ti, int tj, int chb, int p4,
                                          int n0c, int kk, float4 (&cur)[NPAN][4]) {
    const int nbase = n0c + kk * 32;
#pragma unroll
    for (int p = 0; p < NPAN; ++p) {
        const int pcb = (p ? tj : ti) * 128;
#pragma unroll
        for (int i = 0; i < 4; ++i) {
            const int ch = chb + 32 * i;
            float4 v = make_float4(0.f, 0.f, 0.f, 0.f);
            if (kk * 32 + p4 < CHUNK_PTS)
                v = *(const float4*)(y4 + ((size_t)(b * 256 + pcb + ch)) * NPTS + nbase + p4);
            cur[p][i] = v;
        }
    }
}

template <int NPAN>
__device__ __forceinline__ void cov_body(const float* __restrict__ y4,
                                         const float* __restrict__ ss,
                                         float* __restrict__ covP,
                                         float* __restrict__ fsumb,
                                         int chunk, int tile, int b, int tid,
                                         unsigned short (*pan)[2][4096]) {
    const int ti = (tile == 1) ? 1 : 0;
    const int tj = (tile == 0) ? 0 : 1;

    const int lane = tid & 63;
    const int w    = tid >> 6;
    const int wr   = w & 1, wc = w >> 1;
    const int n0c  = chunk * CHUNK_PTS;

    f32x4 acc[4][4];
#pragma unroll
    for (int m = 0; m < 4; ++m)
#pragma unroll
        for (int n = 0; n < 4; ++n) acc[m][n] = (f32x4){0.f, 0.f, 0.f, 0.f};

    // staging assignment: 8 point-groups (4 pts) x 32 channel-bases
    const int g   = tid & 7;
    const int chb = tid >> 3;          // 0..31
    const int p4  = g * 4;             // point offset in 32-chunk
    const int q   = p4 >> 3, j0 = p4 & 7;

    float fs[4] = {0.f, 0.f, 0.f, 0.f};
    float4 cur[NPAN][4];

    cov_issue<NPAN>(y4, b, ti, tj, chb, p4, n0c, 0, cur);

#pragma unroll 1
    for (int kk = 0; kk < COV_KK; ++kk) {
        __builtin_amdgcn_sched_barrier(0);
        __builtin_amdgcn_s_barrier();          // LDS safe to overwrite
        __builtin_amdgcn_sched_barrier(0);

        const bool ok = (kk * 32 + p4 < CHUNK_PTS);
#pragma unroll
        for (int p = 0; p < NPAN; ++p) {
            const int pcb = (p ? tj : ti) * 128;
#pragma unroll
            for (int i = 0; i < 4; ++i) {
                const int ch = chb + 32 * i;
                float4 v = cur[p][i];
                if (ok) {
                    float sc = ss[pcb + ch], sh = ss[256 + pcb + ch];
                    v.x = fmaxf(fmaf(v.x, sc, sh), 0.f);
                    v.y = fmaxf(fmaf(v.y, sc, sh), 0.f);
                    v.z = fmaxf(fmaf(v.z, sc, sh), 0.f);
                    v.w = fmaxf(fmaf(v.w, sc, sh), 0.f);
                } else {
                    v = make_float4(0.f, 0.f, 0.f, 0.f);
                }
                if (NPAN == 1) fs[i] += (v.x + v.y) + (v.z + v.w);
                ushort4v h4, l4;
                h4[0] = f2h(v.x); l4[0] = f2h(hres(v.x));
                h4[1] = f2h(v.y); l4[1] = f2h(hres(v.y));
                h4[2] = f2h(v.z); l4[2] = f2h(hres(v.z));
                h4[3] = f2h(v.w); l4[3] = f2h(hres(v.w));
                const int addr = (ch >> 4) * 512 + (q * 16 + (ch & 15)) * 8 + j0;
                const int sa = swz8(addr * 2) >> 1;
                *(ushort4v*)&pan[p][0][sa] = h4;
                *(ushort4v*)&pan[p][1][sa] = l4;
            }
        }
        if (kk + 1 < COV_KK)
            cov_issue<NPAN>(y4, b, ti, tj, chb, p4, n0c, kk + 1, cur);  // prefetch

        asm volatile("s_waitcnt lgkmcnt(0)" ::: "memory");  // ds_writes visible
        __builtin_amdgcn_s_barrier();                       // NO vmcnt drain
        __builtin_amdgcn_sched_barrier(0);

        const unsigned short* Ah = pan[0][0];
        const unsigned short* Al = pan[0][1];
        const unsigned short* Bh = pan[NPAN - 1][0];
        const unsigned short* Bl = pan[NPAN - 1][1];

        f16x8 ah[4], al[4], bh[4], bl[4];
#pragma unroll
        for (int m = 0; m < 4; ++m) {
            int t8 = (wr * 4 + m) * 512 + lane * 8;
            int sa = swz8(t8 * 2) >> 1;
            ah[m] = *(const f16x8*)&Ah[sa];
            al[m] = *(const f16x8*)&Al[sa];
        }
#pragma unroll
        for (int n = 0; n < 4; ++n) {
            int t8 = (wc * 4 + n) * 512 + lane * 8;
            int sa = swz8(t8 * 2) >> 1;
            bh[n] = *(const f16x8*)&Bh[sa];
            bl[n] = *(const f16x8*)&Bl[sa];
        }
#pragma unroll
        for (int m = 0; m < 4; ++m)
#pragma unroll
            for (int n = 0; n < 4; ++n) {
                acc[m][n] = __builtin_amdgcn_mfma_f32_16x16x32_f16(ah[m], bh[n], acc[m][n], 0, 0, 0);
                acc[m][n] = __builtin_amdgcn_mfma_f32_16x16x32_f16(ah[m], bl[n], acc[m][n], 0, 0, 0);
                acc[m][n] = __builtin_amdgcn_mfma_f32_16x16x32_f16(al[m], bh[n], acc[m][n], 0, 0, 0);
            }
    }

    // fused per-channel relu-sum contribution (tiles 0/1 only)
    if (NPAN == 1) {
#pragma unroll
        for (int i = 0; i < 4; ++i) {
            float s = fs[i];
            s += __shfl_xor(s, 1);
            s += __shfl_xor(s, 2);
            s += __shfl_xor(s, 4);
            if (g == 0)
                atomicAdd(&fsumb[b * 256 + ti * 128 + chb + 32 * i], s);
        }
    }

    // epilogue: packed per-(chunk,b,tile) 128x128 partial buffer (no atomics)
    float* outp = covP + (((size_t)(chunk * NB + b) * 3 + tile) << 14);
    const int rowb = wr * 64;
    const int colb = wc * 64;
#pragma unroll
    for (int m = 0; m < 4; ++m)
#pragma unroll
        for (int n = 0; n < 4; ++n)
#pragma unroll
            for (int r = 0; r < 4; ++r) {
                int row = rowb + m * 16 + (lane >> 4) * 4 + r;
                int col = colb + n * 16 + (lane & 15);
                outp[(row << 7) + col] = acc[m][n][r];
            }
}

// grid: 960 blocks 1D; id&7 = xcd slot, j = id>>3 (0..119);
// tile order within trio: (0,1) first, then (0,0), (1,1).
__global__ __launch_bounds__(256) void cov_all(const float* __restrict__ y4,
                                               const float* __restrict__ ss,
                                               float* __restrict__ covP,
                                               float* __restrict__ fsumb) {
    __shared__ unsigned short pan[2][2][4096];
    const int id  = blockIdx.x;
    const int xcd = id & 7;
    const int j   = id >> 3;          // 0..119
    const int t3  = j % 3;
    const int tile = (t3 == 0) ? 2 : (t3 - 1);
    const int g0  = xcd * 40 + j / 3; // 0..319
    const int chunk = g0 >> 4;
    const int b     = g0 & 15;
    if (tile == 2)
        cov_body<2>(y4, ss, covP, fsumb, chunk, 2, b, threadIdx.x, pan);
    else
        cov_body<1>(y4, ss, covP, fsumb, chunk, tile, b, threadIdx.x, pan);
}

// ---------------------------------------------------------------------------
// cov = (sum_q covP[q])/N - m fbar^T - fbar m^T + m m^T ; mirror tile (1,0)
// covP layout: [chunk][b][tile 0:(0,0) 1:(1,1) 2:(0,1)][128][128]
// ---------------------------------------------------------------------------
__global__ void covfin_ker(const float* __restrict__ covP, const float* __restrict__ fsumb,
                           float* __restrict__ Y0, float* __restrict__ trace) {
    int r = blockIdx.x, b = blockIdx.y, c = threadIdx.x;
    float fbr = fsumb[b * 256 + r] * (1.f / NPTS);
    float fbc = fsumb[b * 256 + c] * (1.f / NPTS);
    float mr = 0.f, mc = 0.f;
    for (int q = 0; q < NB; ++q) {
        mr += fsumb[q * 256 + r];
        mc += fsumb[q * 256 + c];
    }
    mr *= (1.f / NBN);
    mc *= (1.f / NBN);
    int tile, rr, cc;
    if (r < 128 && c < 128)        { tile = 0; rr = r;       cc = c; }
    else if (r >= 128 && c >= 128) { tile = 1; rr = r - 128; cc = c - 128; }
    else if (r < 128)              { tile = 2; rr = r;       cc = c - 128; }   // (0,1)
    else                           { tile = 2; rr = c;       cc = r - 128; }   // (1,0) mirror
    size_t base = (((size_t)b * 3 + tile) << 14) + ((size_t)rr << 7) + cc;
    float m5 = 0.f;
#pragma unroll
    for (int q = 0; q < COV_CHUNKS; ++q)
        m5 += covP[(size_t)q * (NB * 3 * 16384) + base];
    float v = m5 * (1.f / NPTS) - fbr * mc - mr * fbc + mr * mc;
    Y0[((size_t)b << 16) + ((size_t)r << 8) + c] = v;
    if (c == r) atomicAdd(&trace[b], v);
}

__global__ void ns_init(float* __restrict__ Y0, float* __restrict__ Z0,
                        const float* __restrict__ trace) {
    int i = blockIdx.x * 256 + threadIdx.x;   // 16*65536 total
    int b = i >> 16, rc = i & 65535;
    float inv = 1.f / trace[b];
    Y0[i] *= inv;
    Z0[i] = ((rc >> 8) == (rc & 255)) ? 1.f : 0.f;
}

// ---------------------------------------------------------------------------
// Newton-Schulz batched 256x256 GEMM via split-fp16 MFMA, 8-wave body.
// O = diag*I + scale*(A.B); block = 64x64 tile, 512 threads (8 waves:
// wave = 16 rows x 32 cols), K staged 128-wide -> 2 stages, 4 barriers.
// A staging: thread (r2=tid>>3, kq8=tid&7) loads octets kq8 and kq8+8.
// B staging: thread (colB=tid&63, kB=tid>>6) loads octets kB and kB+8.
// Panel layout: tile = (f>>4)*4 + (koct>>2); off ((koct&3)*16+(f&15))*8+j;
// swz8 on byte offsets (same verified family; K-accumulation order is
// unchanged vs the K=64 version -> bitwise-identical results).
// XCD-aware block swizzle: batches {2x, 2x+1} pinned to slot x (id & 7)
// consistently across ALL NS dispatches for L2 residency.
// NOTE: stable coupled iteration — do NOT commute M.Z -> Z.M or read
// operands transposed-via-symmetry (Higham; R7 NaN'd exactly this way).
// ---------------------------------------------------------------------------
__device__ __forceinline__ void ns_body8(const float* __restrict__ Ab,
                                         const float* __restrict__ Bb,
                                         float* __restrict__ Ob,
                                         float scale, float diag, int tile, int tid,
                                         unsigned short* Ap0, unsigned short* Ap1,
                                         unsigned short* Bp0, unsigned short* Bp1) {
    const int lane = tid & 63;
    const int w    = tid >> 6;          // 0..7
    const int wr   = w & 3;             // 16-row frag group
    const int wc   = w >> 2;            // 32-col group
    const int tr = (tile >> 2) * 64, tc = (tile & 3) * 64;

    f32x4 acc[2];
    acc[0] = (f32x4){0.f, 0.f, 0.f, 0.f};
    acc[1] = (f32x4){0.f, 0.f, 0.f, 0.f};

    const int r2   = tid >> 3;          // A row 0..63
    const int kq8  = tid & 7;           // A base k-octet
    const int colB = tid & 63;          // B col 0..63
    const int kB   = tid >> 6;          // B base k-octet 0..7

#pragma unroll 1
    for (int kc = 0; kc < 256; kc += 128) {
        __syncthreads();
        // ---- stage A[tr..tr+64)[kc..kc+128) ----
#pragma unroll
        for (int kb = 0; kb < 2; ++kb) {
            const int koct = kq8 + kb * 8;      // 0..15
            const float* ap = Ab + (size_t)(tr + r2) * 256 + kc + koct * 8;
            float av[8];
            *(float4*)&av[0] = *(const float4*)ap;
            *(float4*)&av[4] = *(const float4*)(ap + 4);
            ushort8v h8, l8;
#pragma unroll
            for (int j = 0; j < 8; ++j) { h8[j] = f2h(av[j]); l8[j] = f2h(hres(av[j])); }
            const int ua = ((r2 >> 4) * 4 + (koct >> 2)) * 512 + ((koct & 3) * 16 + (r2 & 15)) * 8;
            const int sa = swz8(ua * 2) >> 1;
            *(ushort8v*)&Ap0[sa] = h8;
            *(ushort8v*)&Ap1[sa] = l8;
        }
        // ---- stage B[kc..kc+128)[tc..tc+64) ----
#pragma unroll
        for (int kb = 0; kb < 2; ++kb) {
            const int koct = kB + kb * 8;       // 0..15
            const float* bp = Bb + (size_t)(kc + koct * 8) * 256 + tc + colB;
            float bv[8];
#pragma unroll
            for (int j = 0; j < 8; ++j) bv[j] = bp[(size_t)j * 256];
            ushort8v h8, l8;
#pragma unroll
            for (int j = 0; j < 8; ++j) { h8[j] = f2h(bv[j]); l8[j] = f2h(hres(bv[j])); }
            const int ub = ((colB >> 4) * 4 + (koct >> 2)) * 512 + ((koct & 3) * 16 + (colB & 15)) * 8;
            const int sb = swz8(ub * 2) >> 1;
            *(ushort8v*)&Bp0[sb] = h8;
            *(ushort8v*)&Bp1[sb] = l8;
        }
        __syncthreads();

#pragma unroll
        for (int kk = 0; kk < 4; ++kk) {
            const int ua = swz8(((wr * 4 + kk) * 512 + lane * 8) * 2) >> 1;
            f16x8 a_h = *(const f16x8*)&Ap0[ua];
            f16x8 a_l = *(const f16x8*)&Ap1[ua];
#pragma unroll
            for (int n = 0; n < 2; ++n) {
                const int ub = swz8((((wc * 2 + n) * 4 + kk) * 512 + lane * 8) * 2) >> 1;
                f16x8 b_h = *(const f16x8*)&Bp0[ub];
                f16x8 b_l = *(const f16x8*)&Bp1[ub];
                acc[n] = __builtin_amdgcn_mfma_f32_16x16x32_f16(a_h, b_h, acc[n], 0, 0, 0);
                acc[n] = __builtin_amdgcn_mfma_f32_16x16x32_f16(a_h, b_l, acc[n], 0, 0, 0);
                acc[n] = __builtin_amdgcn_mfma_f32_16x16x32_f16(a_l, b_h, acc[n], 0, 0, 0);
            }
        }
    }

    const int ro = (lane >> 4) * 4, co = lane & 15;
#pragma unroll
    for (int n = 0; n < 2; ++n) {
        int row = tr + wr * 16 + ro;
        int col = tc + wc * 32 + n * 16 + co;
#pragma unroll
        for (int r = 0; r < 4; ++r) {
            float v = scale * acc[n][r] + (((row + r) == col) ? diag : 0.f);
            Ob[(size_t)(row + r) * 256 + col] = v;
        }
    }
}

// grid: 256 blocks 1D.  xcd = id&7; k = id>>3 (0..31);
// b = 2*xcd + (k>>4); tile = k&15  -> each batch's 16 tiles on one XCD.
__global__ __launch_bounds__(512) void ns_gemm(const float* __restrict__ A,
                                               const float* __restrict__ B,
                                               float* __restrict__ O,
                                               float scale, float diag) {
    __shared__ unsigned short Ap[2][8192], Bp[2][8192];
    const int id  = blockIdx.x;
    const int xcd = id & 7;
    const int k   = id >> 3;
    const int b   = 2 * xcd + (k >> 4);
    const int tile = k & 15;
    size_t off = (size_t)b << 16;
    ns_body8(A + off, B + off, O + off, scale, diag, tile, threadIdx.x,
             Ap[0], Ap[1], Bp[0], Bp[1]);
}

// grid: 512 blocks 1D.  xcd = id&7; k = id>>3 (0..63); z = k>>5;
// rem = k&31; b = 2*xcd + (rem>>4); tile = rem&15.
__global__ __launch_bounds__(512) void ns_gemm_pair(const float* __restrict__ Y,
                                                    const float* __restrict__ Mm,
                                                    const float* __restrict__ Z,
                                                    float* __restrict__ Yn,
                                                    float* __restrict__ Zn) {
    __shared__ unsigned short Ap[2][8192], Bp[2][8192];
    const int id  = blockIdx.x;
    const int xcd = id & 7;
    const int k   = id >> 3;
    const int z   = k >> 5;
    const int rem = k & 31;
    const int b   = 2 * xcd + (rem >> 4);
    const int tile = rem & 15;
    size_t off = (size_t)b << 16;
    if (z == 0)
        ns_body8(Y + off, Mm + off, Yn + off, 0.5f, 0.f, tile, threadIdx.x,
                 Ap[0], Ap[1], Bp[0], Bp[1]);
    else
        ns_body8(Mm + off, Z + off, Zn + off, 0.5f, 0.f, tile, threadIdx.x,
                 Ap[0], Ap[1], Bp[0], Bp[1]);
}

// ---------------------------------------------------------------------------
// FC: outpre[b,o] += sum_k sqrt(trace[b])*Yf[b,k] * Wfc[o,k]
// ---------------------------------------------------------------------------
__global__ __launch_bounds__(256) void fc_ker(const float* __restrict__ Yf,
                                              const float* __restrict__ trace,
                                              const float* __restrict__ Wfc,
                                              float* __restrict__ outpre) {
    int kc = blockIdx.x;
    int ot = blockIdx.y;
    int t = threadIdx.x;
    __shared__ float Wl[64][129];
    __shared__ float Vl[16][129];
#pragma unroll
    for (int i = 0; i < 32; ++i) {
        int l = i * 256 + t;
        int o = l >> 7, k = l & 127;
        Wl[o][k] = Wfc[(size_t)(ot * 64 + o) * 65536 + kc * 128 + k];
    }
#pragma unroll
    for (int i = 0; i < 8; ++i) {
        int l = i * 256 + t;
        int bb = l >> 7, k = l & 127;
        Vl[bb][k] = sqrtf(trace[bb]) * Yf[((size_t)bb << 16) + kc * 128 + k];
    }
    __syncthreads();
    int ol = t & 63, bg = t >> 6;
    float a0 = 0.f, a1 = 0.f, a2 = 0.f, a3 = 0.f;
    for (int k = 0; k < 128; ++k) {
        float w = Wl[ol][k];
        a0 = fmaf(w, Vl[bg * 4 + 0][k], a0);
        a1 = fmaf(w, Vl[bg * 4 + 1][k], a1);
        a2 = fmaf(w, Vl[bg * 4 + 2][k], a2);
        a3 = fmaf(w, Vl[bg * 4 + 3][k], a3);
    }
    int o = ot * 64 + ol;
    atomicAdd(&outpre[(bg * 4 + 0) * 256 + o], a0);
    atomicAdd(&outpre[(bg * 4 + 1) * 256 + o], a1);
    atomicAdd(&outpre[(bg * 4 + 2) * 256 + o], a2);
    atomicAdd(&outpre[(bg * 4 + 3) * 256 + o], a3);
}

__global__ void norm_ker(const float* __restrict__ outpre, const float* __restrict__ bfc,
                         float* __restrict__ dout) {
    int b = blockIdx.x, t = threadIdx.x;
    float v = outpre[b * 256 + t] + bfc[t];
    float q = v * v;
    for (int off = 32; off; off >>= 1) q += __shfl_xor(q, off);
    __shared__ float lq[4];
    __shared__ float snorm;
    if ((t & 63) == 0) lq[t >> 6] = q;
    __syncthreads();
    if (t == 0) snorm = fmaxf(sqrtf(lq[0] + lq[1] + lq[2] + lq[3]), 1e-12f);
    __syncthreads();
    dout[b * 256 + t] = v / snorm;
}

// ---------------------------------------------------------------------------
extern "C" void kernel_launch(void* const* d_in, const int* in_sizes, int n_in,
                              void* d_out, int out_size, void* d_ws, size_t ws_size,
                              hipStream_t stream) {
    (void)in_sizes; (void)n_in; (void)out_size; (void)ws_size;
    const float* pts = (const float*)d_in[0];
    const float* Wm[5]; const float* gm[5]; const float* bm[5];
    for (int i = 0; i < 5; ++i) {
        Wm[i] = (const float*)d_in[1 + 3 * i];
        gm[i] = (const float*)d_in[2 + 3 * i];
        bm[i] = (const float*)d_in[3 + 3 * i];
    }
    const float* Wfc = (const float*)d_in[16];
    const float* bfc = (const float*)d_in[17];

    float* ws     = (float*)d_ws;
    float* stats  = ws;                  // 2560
    float* fsumb  = ws + 2560;           // 4096
    float* trace  = ws + 6656;           // 16
    float* outpre = ws + 6672;           // 4096
    float* ss     = ws + 10768;          // 2560
    float* R      = ws + 16384;          // 256ch fp32: 40,960,000 floats (y4)
    float* P      = R;                   // 64ch view (L0/L2 out)
    float* Q      = R + (size_t)NB * 256 * NPTS;   // 128ch: 20,480,000 floats
    // cov partials alias the (then-dead) Q region:
    // 20 chunks * 16 b * 3 tiles * 16384 = 15,728,640 floats < 20.48M
    float* covP   = Q;
    // NS buffers alias the (then-dead) R region (R dead after cov_all):
    float* Y0     = R;
    float* Y1     = Y0 + 1048576;
    float* Z0     = Y1 + 1048576;
    float* Z1     = Z0 + 1048576;
    float* Mb     = Z1 + 1048576;        // 5.24M floats << 40.96M of R

    hipMemsetAsync(ws, 0, 16384 * sizeof(float), stream);

    // Layer 0 (3 -> 64)
    conv0_ker<<<dim3(NBN / 256), dim3(256), 0, stream>>>(pts, Wm[0], P);
    chan_stats<<<dim3(64, NB), dim3(256), 0, stream>>>(P, 64, stats);
    bn_finalize<<<dim3(1), dim3(256), 0, stream>>>(stats, gm[0], bm[0], 64, ss);
    // Layer 1 (64 -> 64), stats fused
    conv_mfma<64, 64, 64><<<dim3(79, 1, NB), dim3(256), 0, stream>>>(P, ss, Wm[1], Q, stats + 512);
    bn_finalize<<<dim3(1), dim3(256), 0, stream>>>(stats + 512, gm[1], bm[1], 64, ss + 512);
    // Layer 2 (64 -> 64)
    conv_mfma<64, 64, 64><<<dim3(79, 1, NB), dim3(256), 0, stream>>>(Q, ss + 512, Wm[2], P, stats + 1024);
    bn_finalize<<<dim3(1), dim3(256), 0, stream>>>(stats + 1024, gm[2], bm[2], 64, ss + 1024);
    // Layer 3 (64 -> 128)
    conv_mfma<64, 128, 128><<<dim3(79, 1, NB), dim3(256), 0, stream>>>(P, ss + 1024, Wm[3], Q, stats + 1536);
    bn_finalize<<<dim3(1), dim3(256), 0, stream>>>(stats + 1536, gm[3], bm[3], 128, ss + 1536);
    // Layer 4 (128 -> 256); writes R (P is dead now)
    conv_mfma<128, 256, 128><<<dim3(79, 2, NB), dim3(256), 0, stream>>>(Q, ss + 1536, Wm[4], R, stats + 2048);
    bn_finalize<<<dim3(1), dim3(256), 0, stream>>>(stats + 2048, gm[4], bm[4], 256, ss + 2048);

    // Covariance path: single merged dispatch, trio-XCD co-scheduled
    cov_all<<<dim3(960), dim3(256), 0, stream>>>(R, ss + 2048, covP, fsumb);
    covfin_ker<<<dim3(256, NB), dim3(256), 0, stream>>>(covP, fsumb, Y0, trace);
    ns_init<<<dim3(4096), dim3(256), 0, stream>>>(Y0, Z0, trace);

    // Newton–Schulz iterations (stable coupled form, 8-wave K=128 bodies,
    // XCD-pinned batches for L2 residency)
    float* Yc = Y0; float* Zc = Z0; float* Yn = Y1; float* Zn = Z1;
    for (int it = 0; it < NS_ITERS; ++it) {
        ns_gemm<<<dim3(256), dim3(512), 0, stream>>>(Zc, Yc, Mb, -1.f, 3.f);
        ns_gemm_pair<<<dim3(512), dim3(512), 0, stream>>>(Yc, Mb, Zc, Yn, Zn);
        float* ty = Yc; Yc = Yn; Yn = ty;
        float* tz = Zc; Zc = Zn; Zn = tz;
    }

    fc_ker<<<dim3(512, 4), dim3(256), 0, stream>>>(Yc, trace, Wfc, outpre);
    norm_ker<<<dim3(NB), dim3(256), 0, stream>>>(outpre, bfc, (float*)d_out);
}